// Round 9
// baseline (1961.729 us; speedup 1.0000x reference)
//
#include <hip/hip_runtime.h>

// Decoder_48378511622552 — CSR-sorted, bf16, K=128 MFMA fused GNN decoder (gfx950)
// Round 9: EDGE T14 register-prefetch pipeline (idx 2 tiles ahead, rows 1 tile ahead);
// DEC1+DEC2 fused into one 3-GEMM kernel (eac never leaves LDS).

#define HD   128
#define NC   50000
#define NF   150000
#define ECNT 400000
#define OUTD 3
#define SCB  512
#define NB_SCAN ((NF + SCB - 1) / SCB)   // 293

typedef unsigned short u16;
typedef unsigned int   u32;
typedef short bf16x8 __attribute__((ext_vector_type(8)));
typedef float f32x4  __attribute__((ext_vector_type(4)));

__device__ __forceinline__ float bf2f(u32 u){ return __uint_as_float(u << 16); }
__device__ __forceinline__ u32 cvtpk(float a, float b){   // lo = bf16(a), hi = bf16(b)
  u32 r; asm("v_cvt_pk_bf16_f32 %0, %1, %2" : "=v"(r) : "v"(a), "v"(b)); return r;
}
__device__ __forceinline__ u16 f2bf(float f){ return (u16)cvtpk(f, f); }
__device__ __forceinline__ u32 addpk(u32 a, u32 b){
  return cvtpk(bf2f(a & 0xffffu) + bf2f(b & 0xffffu),
               __uint_as_float(a & 0xffff0000u) + __uint_as_float(b & 0xffff0000u));
}
__device__ __forceinline__ float eluf(float x){ return x > 0.f ? x : __expf(x) - 1.f; }
// swizzle for bf16 [32][256B] tiles
__device__ __forceinline__ int SW(int row, int byte){ return row * 256 + (byte ^ ((row & 7) << 4)); }

// ---------------- prep kernels ----------------

__global__ void prep_all_kernel(const float* __restrict__ eW0, const float* __restrict__ eW1,
                                const float* __restrict__ nW0, const float* __restrict__ nW1,
                                const float* __restrict__ uW0, const float* __restrict__ uW1,
                                const float* __restrict__ dW1,
                                u16* c_eW0, u16* c_eW1, u16* c_nW0, u16* c_nW1,
                                u16* c_uW0, u16* c_uW1, u16* c_dW1)
{
  int b = blockIdx.x;
  const float* src; u16* dst; int kb;
  if      (b <  384){ src = eW0; dst = c_eW0; kb = b * 2; }          // K=768 (2 mats)
  else if (b <  512){ src = eW1; dst = c_eW1; kb = (b - 384) * 2; }  // K=256
  else if (b <  768){ src = nW0; dst = c_nW0; kb = (b - 512) * 2; }  // K=512
  else if (b <  896){ src = nW1; dst = c_nW1; kb = (b - 768) * 2; }  // K=256
  else if (b < 1024){ src = uW0; dst = c_uW0; kb = (b - 896) * 2; }  // K=256
  else if (b < 1088){ src = uW1; dst = c_uW1; kb = (b - 1024) * 2; } // K=128
  else              { src = dW1; dst = c_dW1; kb = (b - 1088) * 2; } // K=128
  int t = threadIdx.x;
  int k = kb + (t >> 7), j = t & 127;
  dst[(((k >> 3) * HD + j) << 3) + (k & 7)] = f2bf(src[k * HD + j]);
}

__global__ void f32_to_bf16_vec(const float* __restrict__ in, u16* __restrict__ out, int n8){
  int i = blockIdx.x * blockDim.x + threadIdx.x;
  if (i >= n8) return;
  float4 f0 = ((const float4*)in)[i * 2];
  float4 f1 = ((const float4*)in)[i * 2 + 1];
  ((uint4*)out)[i] = make_uint4(cvtpk(f0.x,f0.y), cvtpk(f0.z,f0.w), cvtpk(f1.x,f1.y), cvtpk(f1.z,f1.w));
}

__global__ void deg_kernel(const int* __restrict__ ei, int* __restrict__ deg){
  int e = blockIdx.x * blockDim.x + threadIdx.x;
  if (e < ECNT) atomicAdd(&deg[ei[ECNT + e]], 1);
}

__global__ void scanA_kernel(const int* __restrict__ deg, int* __restrict__ part){
  __shared__ int s[SCB];
  int t = threadIdx.x, i = blockIdx.x * SCB + t;
  s[t] = (i < NF) ? deg[i] : 0;
  __syncthreads();
  for (int off = SCB/2; off; off >>= 1){ if (t < off) s[t] += s[t + off]; __syncthreads(); }
  if (t == 0) part[blockIdx.x] = s[0];
}

__global__ void scanB_kernel(int* __restrict__ part){
  __shared__ int s[SCB];
  int t = threadIdx.x;
  int v = (t < NB_SCAN) ? part[t] : 0;
  s[t] = v; __syncthreads();
  for (int off = 1; off < SCB; off <<= 1){
    int x = (t >= off) ? s[t - off] : 0;
    __syncthreads(); s[t] += x; __syncthreads();
  }
  if (t < NB_SCAN) part[t] = s[t] - v;   // exclusive
}

__global__ void scanC_kernel(const int* __restrict__ deg, const int* __restrict__ part,
                             int* __restrict__ rowptr){
  __shared__ int s[SCB];
  int t = threadIdx.x, i = blockIdx.x * SCB + t;
  int v = (i < NF) ? deg[i] : 0;
  s[t] = v; __syncthreads();
  for (int off = 1; off < SCB; off <<= 1){
    int x = (t >= off) ? s[t - off] : 0;
    __syncthreads(); s[t] += x; __syncthreads();
  }
  int excl = part[blockIdx.x] + s[t] - v;
  if (i < NF) rowptr[i] = excl;
  if (i == NF - 1) rowptr[NF] = excl + v;
}

__global__ void build_perm_kernel(const int* __restrict__ ei, int* __restrict__ cursor,
                                  int* __restrict__ perm, int* __restrict__ esrc,
                                  int* __restrict__ edst){
  int e = blockIdx.x * blockDim.x + threadIdx.x;
  if (e >= ECNT) return;
  int sI = ei[e], d = ei[ECNT + e];
  int p = atomicAdd(&cursor[d], 1);
  perm[p] = e; esrc[p] = sI; edst[p] = d;
}

__global__ void permute_ea_kernel(const float* __restrict__ ea_in, const int* __restrict__ perm,
                                  u16* __restrict__ ea_s){
  int i = blockIdx.x * blockDim.x + threadIdx.x;
  if (i >= ECNT * 16) return;
  int p = i >> 4, c = i & 15;
  int e = perm[p];
  const float4* src = (const float4*)(ea_in + (size_t)e * HD + c * 8);
  float4 f0 = src[0], f1 = src[1];
  ((uint4*)ea_s)[(size_t)p * 16 + c] =
      make_uint4(cvtpk(f0.x,f0.y), cvtpk(f0.z,f0.w), cvtpk(f1.x,f1.y), cvtpk(f1.z,f1.w));
}

// ---------------- fused LIN (1 or 3 outputs): o[w] = x @ W[w], bf16 out ----------------
template<int NOUT>
__global__ __launch_bounds__(256, 4)
void lin_kernel(const u16* __restrict__ Wa, const u16* __restrict__ Wb, const u16* __restrict__ Wc,
                const u16* __restrict__ x, u16* __restrict__ oA, u16* __restrict__ oB,
                u16* __restrict__ oC, int nA, int nB, int nC, int n_rows)
{
  __shared__ __align__(16) char ldsA[32 * 256];
  const int tid = threadIdx.x, lane = tid & 63, wid = tid >> 6;
  const int ln = lane & 15, kq = lane >> 4, ncol = wid * 32;
  const int tiles = (n_rows + 31) >> 5;

  for (int tile = blockIdx.x; tile < tiles; tile += gridDim.x){
    const int row0 = tile << 5;
    #pragma unroll
    for (int c = 0; c < 2; ++c){
      int i = tid + c * 256, row = i >> 4, kk = i & 15, rg = row0 + row;
      if (rg < n_rows)
        *(uint4*)(ldsA + SW(row, kk * 16)) = *(const uint4*)(x + (((size_t)rg) << 7) + (kk << 3));
    }
    __syncthreads();
    bf16x8 af[4][2];
    #pragma unroll
    for (int k0 = 0; k0 < 4; ++k0){
      af[k0][0] = *(const bf16x8*)(ldsA + SW(ln,      k0 * 64 + (kq << 4)));
      af[k0][1] = *(const bf16x8*)(ldsA + SW(16 + ln, k0 * 64 + (kq << 4)));
    }
    __syncthreads();   // all frag reads done -> next tile may overwrite

    const u16* Ws[3] = {Wa, Wb, Wc};
    u16*       Os[3] = {oA, oB, oC};
    const int  Ns[3] = {nA, nB, nC};
    const f32x4 zz = {0.f, 0.f, 0.f, 0.f};
    #pragma unroll
    for (int w = 0; w < NOUT; ++w){
      if (row0 < Ns[w]){   // block-uniform guard
        const u16* wp = Ws[w];
        asm volatile("" : "+v"(wp));
        uint4 bfr[4][2];
        #pragma unroll
        for (int k0 = 0; k0 < 4; ++k0)
          #pragma unroll
          for (int nt = 0; nt < 2; ++nt)
            bfr[k0][nt] = *(const uint4*)(wp + (((size_t)((k0*4 + kq)*HD + ncol + nt*16 + ln)) << 3));
        f32x4 cc[2][2] = {{zz, zz}, {zz, zz}};
        #pragma unroll
        for (int k0 = 0; k0 < 4; ++k0){
          bf16x8 w0 = __builtin_bit_cast(bf16x8, bfr[k0][0]);
          bf16x8 w1 = __builtin_bit_cast(bf16x8, bfr[k0][1]);
          cc[0][0] = __builtin_amdgcn_mfma_f32_16x16x32_bf16(af[k0][0], w0, cc[0][0], 0, 0, 0);
          cc[0][1] = __builtin_amdgcn_mfma_f32_16x16x32_bf16(af[k0][0], w1, cc[0][1], 0, 0, 0);
          cc[1][0] = __builtin_amdgcn_mfma_f32_16x16x32_bf16(af[k0][1], w0, cc[1][0], 0, 0, 0);
          cc[1][1] = __builtin_amdgcn_mfma_f32_16x16x32_bf16(af[k0][1], w1, cc[1][1], 0, 0, 0);
        }
        u16* op = Os[w];
        #pragma unroll
        for (int mi = 0; mi < 2; ++mi)
          #pragma unroll
          for (int nt = 0; nt < 2; ++nt)
            #pragma unroll
            for (int r = 0; r < 4; ++r){
              int rg = row0 + mi * 16 + kq * 4 + r;
              if (rg < Ns[w]) op[(size_t)rg * HD + ncol + nt * 16 + ln] = f2bf(cc[mi][nt][r]);
            }
      }
    }
  }
}

// ---------------- unified fused K=128 MFMA MLP (16 KB LDS) ----------------
enum { M_EDGE = 0, M_NODE = 1, M_DEC12 = 2 };

// EDGE : A = ea (prefetched); h = elu(A@W0 + P[src]+Q[dst] + b0); o = h@W1 + b1; out = LN(A + o)
// NODE : A = CSR-mean(ea); h = elu(A@W0 + T[row] + b0); o = h@W1 + b1;          out = LN(x + o)
// DEC12: h1 = elu(delta@dW0+db0); eac = elu(h1@W0 + b0); h = elu(eac@W1 + XU[clus] + b1);
//        o = elu(h@W2 + b2); out = LN(eac + o)     [eac lives in ldsA, never hits global]
template<int MODE>
__global__ __launch_bounds__(256, 4)
void mlp_kernel(const u16* __restrict__ W0c, const u16* __restrict__ W1c,
                const u16* __restrict__ W2c,
                const float* __restrict__ b0, const float* __restrict__ b1,
                const float* __restrict__ b2,
                const float* __restrict__ gw, const float* __restrict__ bw,
                const u16* __restrict__ tabA, const u16* __restrict__ addP,
                const u16* __restrict__ addQ, const u16* __restrict__ resid,
                const int* __restrict__ esrc, const int* __restrict__ edst,
                const int* __restrict__ rowptr, const u16* __restrict__ eatab,
                const int* __restrict__ clus,
                u16* __restrict__ outp, int n_rows,
                const float* __restrict__ dW0, const float* __restrict__ db0,
                const float* __restrict__ pos_c, const float* __restrict__ pos_f)
{
  constexpr bool RESLDS = (MODE == M_EDGE || MODE == M_DEC12);

  __shared__ __align__(16) char ldsA [32 * 256];          // A tile / eac (residual)
  __shared__ __align__(16) char ldsPQ[32 * 256];          // addend -> h -> r

  const int tid  = threadIdx.x;
  const int lane = tid & 63;
  const int wid  = tid >> 6;
  const int ln   = lane & 15, kq = lane >> 4;
  const int ncol = wid * 32;

  bf16x8 b1f[4][2];
  #pragma unroll
  for (int k0 = 0; k0 < 4; ++k0)
    #pragma unroll
    for (int nt = 0; nt < 2; ++nt)
      b1f[k0][nt] = *(const bf16x8*)(W0c + (((size_t)((k0*4 + kq)*HD + ncol + nt*16 + ln)) << 3));

  float b0v[2], b1v[2], b2v[2] = {0.f, 0.f};
  #pragma unroll
  for (int nt = 0; nt < 2; ++nt){ b0v[nt] = b0[ncol + nt*16 + ln]; b1v[nt] = b1[ncol + nt*16 + ln]; }
  if constexpr (MODE == M_DEC12){
    #pragma unroll
    for (int nt = 0; nt < 2; ++nt) b2v[nt] = b2[ncol + nt*16 + ln];
  }
  float gl0 = gw[lane], gl1 = gw[64 + lane], bt0 = bw[lane], bt1 = bw[64 + lane];

  const int tiles = (n_rows + 31) >> 5;
  const int g = gridDim.x;

  // ---- EDGE prefetch state: indices 2 tiles ahead, rows 1 tile ahead ----
  const int rowA = tid >> 4, rowB = rowA + 16, kkA = tid & 15;
  int nsi0, ndi0, nsi1, ndi1;
  uint4 pea0, pea1, pp0, pp1, pq0, pq1;
  if constexpr (MODE == M_EDGE){
    int t0 = blockIdx.x;
    int rg0 = (t0 << 5) + rowA, rg1 = (t0 << 5) + rowB;
    nsi0 = esrc[rg0]; ndi0 = edst[rg0];
    nsi1 = esrc[rg1]; ndi1 = edst[rg1];
    pea0 = *(const uint4*)(tabA + (((size_t)rg0) << 7) + (kkA << 3));
    pea1 = *(const uint4*)(tabA + (((size_t)rg1) << 7) + (kkA << 3));
    pp0  = *(const uint4*)(addP + (((size_t)nsi0) << 7) + (kkA << 3));
    pq0  = *(const uint4*)(addQ + (((size_t)ndi0) << 7) + (kkA << 3));
    pp1  = *(const uint4*)(addP + (((size_t)nsi1) << 7) + (kkA << 3));
    pq1  = *(const uint4*)(addQ + (((size_t)ndi1) << 7) + (kkA << 3));
    int tn = t0 + g; if (tn >= tiles) tn = t0;
    int rg0n = (tn << 5) + rowA, rg1n = (tn << 5) + rowB;
    nsi0 = esrc[rg0n]; ndi0 = edst[rg0n];
    nsi1 = esrc[rg1n]; ndi1 = edst[rg1n];
  }

  for (int tile = blockIdx.x; tile < tiles; tile += g){
    const int row0 = tile << 5;

    // ---------------- stage ----------------
    if constexpr (MODE == M_EDGE){
      // write prefetched rows (loads issued a full iteration ago)
      *(uint4*)(ldsA + SW(rowA, kkA * 16)) = pea0;
      *(uint4*)(ldsA + SW(rowB, kkA * 16)) = pea1;
      *(uint4*)(ldsPQ + SW(rowA, kkA * 16)) =
          make_uint4(addpk(pp0.x,pq0.x), addpk(pp0.y,pq0.y), addpk(pp0.z,pq0.z), addpk(pp0.w,pq0.w));
      *(uint4*)(ldsPQ + SW(rowB, kkA * 16)) =
          make_uint4(addpk(pp1.x,pq1.x), addpk(pp1.y,pq1.y), addpk(pp1.z,pq1.z), addpk(pp1.w,pq1.w));
    } else if constexpr (MODE == M_NODE){
      #pragma unroll
      for (int c = 0; c < 2; ++c){           // T[row] addend, bf16
        int i = tid + c * 256, row = i >> 4, kk = i & 15, rg = row0 + row;
        if (rg < n_rows)
          *(uint4*)(ldsPQ + SW(row, kk * 16)) =
              *(const uint4*)(addP + (((size_t)rg) << 7) + (kk << 3));
      }
      // CSR mean of ea -> ldsA
      for (int s = 0; s < 8; ++s){
        int nd = wid * 8 + s, rg = row0 + nd;
        if (rg < n_rows){
          int rp0 = rowptr[rg], rp1 = rowptr[rg + 1];
          float s0 = 0.f, s1 = 0.f;
          int i2 = rp0;
          for (; i2 + 1 < rp1; i2 += 2){
            u32 ua = *(const u32*)(eatab + (((size_t)i2) << 7) + (lane << 1));
            u32 ub = *(const u32*)(eatab + (((size_t)(i2+1)) << 7) + (lane << 1));
            s0 += bf2f(ua & 0xffffu) + bf2f(ub & 0xffffu);
            s1 += bf2f(ua >> 16)     + bf2f(ub >> 16);
          }
          if (i2 < rp1){
            u32 ua = *(const u32*)(eatab + (((size_t)i2) << 7) + (lane << 1));
            s0 += bf2f(ua & 0xffffu); s1 += bf2f(ua >> 16);
          }
          int dg = rp1 - rp0;
          float rd = 1.f / (float)(dg > 0 ? dg : 1);
          *(u32*)(ldsA + SW(nd, lane << 2)) = cvtpk(s0 * rd, s1 * rd);
        }
      }
    } else { // M_DEC12: h1 = elu(delta @ dW0 + db0) -> ldsA ; XU[clus] -> ldsPQ
      #pragma unroll
      for (int c = 0; c < 2; ++c){
        int i = tid + c * 256, row = i >> 4, c8 = i & 15, rg = row0 + row;
        if (rg < n_rows){
          int cl = clus[rg];
          *(uint4*)(ldsPQ + SW(row, c8 * 16)) =
              *(const uint4*)(addP + (((size_t)cl) << 7) + (c8 << 3));
          float d0 = pos_c[cl * 2]     - pos_f[rg * 2];
          float d1 = pos_c[cl * 2 + 1] - pos_f[rg * 2 + 1];
          u32 wq[4];
          #pragma unroll
          for (int q = 0; q < 4; ++q){
            int cc = c8 * 8 + q * 2;
            float va = eluf(fmaf(d0, dW0[cc],     fmaf(d1, dW0[HD + cc],     db0[cc])));
            float vb = eluf(fmaf(d0, dW0[cc + 1], fmaf(d1, dW0[HD + cc + 1], db0[cc + 1])));
            wq[q] = cvtpk(va, vb);
          }
          *(uint4*)(ldsA + SW(row, c8 * 16)) = make_uint4(wq[0], wq[1], wq[2], wq[3]);
        }
      }
    }
    __syncthreads();   // A: stage visible

    if constexpr (MODE == M_EDGE){
      // issue next tile's row loads (using indices prefetched last iter) + next-next indices
      int tn1 = tile + g;  if (tn1 >= tiles) tn1 = tile;
      int tn2 = tn1 + g;   if (tn2 >= tiles) tn2 = tn1;
      int rg0 = (tn1 << 5) + rowA, rg1 = (tn1 << 5) + rowB;
      pea0 = *(const uint4*)(tabA + (((size_t)rg0) << 7) + (kkA << 3));
      pea1 = *(const uint4*)(tabA + (((size_t)rg1) << 7) + (kkA << 3));
      pp0  = *(const uint4*)(addP + (((size_t)nsi0) << 7) + (kkA << 3));
      pq0  = *(const uint4*)(addQ + (((size_t)ndi0) << 7) + (kkA << 3));
      pp1  = *(const uint4*)(addP + (((size_t)nsi1) << 7) + (kkA << 3));
      pq1  = *(const uint4*)(addQ + (((size_t)ndi1) << 7) + (kkA << 3));
      int rg0n = (tn2 << 5) + rowA, rg1n = (tn2 << 5) + rowB;
      nsi0 = esrc[rg0n]; ndi0 = edst[rg0n];
      nsi1 = esrc[rg1n]; ndi1 = edst[rg1n];
    }

    // ---------------- layer 1 (K=128) ----------------
    const f32x4 zz = {0.f, 0.f, 0.f, 0.f};
    f32x4 c1[2][2] = {{zz, zz}, {zz, zz}};
    #pragma unroll
    for (int k0 = 0; k0 < 4; ++k0){
      bf16x8 a0 = *(const bf16x8*)(ldsA + SW(ln,      k0 * 64 + (kq << 4)));
      bf16x8 a1 = *(const bf16x8*)(ldsA + SW(16 + ln, k0 * 64 + (kq << 4)));
      c1[0][0] = __builtin_amdgcn_mfma_f32_16x16x32_bf16(a0, b1f[k0][0], c1[0][0], 0, 0, 0);
      c1[0][1] = __builtin_amdgcn_mfma_f32_16x16x32_bf16(a0, b1f[k0][1], c1[0][1], 0, 0, 0);
      c1[1][0] = __builtin_amdgcn_mfma_f32_16x16x32_bf16(a1, b1f[k0][0], c1[1][0], 0, 0, 0);
      c1[1][1] = __builtin_amdgcn_mfma_f32_16x16x32_bf16(a1, b1f[k0][1], c1[1][1], 0, 0, 0);
    }

    if constexpr (MODE == M_DEC12){
      __syncthreads();  // ldsA (h1) reads done
      // eac = elu(c1 + b0) -> ldsA (residual + GEMM2 input)
      #pragma unroll
      for (int mi = 0; mi < 2; ++mi)
        #pragma unroll
        for (int nt = 0; nt < 2; ++nt)
          #pragma unroll
          for (int r = 0; r < 4; ++r){
            int row = mi * 16 + kq * 4 + r, col = ncol + nt * 16 + ln;
            *(u16*)(ldsA + SW(row, col * 2)) = f2bf(eluf(c1[mi][nt][r] + b0v[nt]));
          }
      __syncthreads();  // eac visible

      // GEMM2: eac @ uW0a
      {
        const u16* w1p = W1c;
        asm volatile("" : "+v"(w1p));
        uint4 b2r[4][2];
        #pragma unroll
        for (int k0 = 0; k0 < 4; ++k0)
          #pragma unroll
          for (int nt = 0; nt < 2; ++nt)
            b2r[k0][nt] = *(const uint4*)(w1p + (((size_t)((k0*4 + kq)*HD + ncol + nt*16 + ln)) << 3));
        f32x4 c2[2][2] = {{zz, zz}, {zz, zz}};
        #pragma unroll
        for (int k0 = 0; k0 < 4; ++k0){
          bf16x8 a0 = *(const bf16x8*)(ldsA + SW(ln,      k0 * 64 + (kq << 4)));
          bf16x8 a1 = *(const bf16x8*)(ldsA + SW(16 + ln, k0 * 64 + (kq << 4)));
          bf16x8 w0 = __builtin_bit_cast(bf16x8, b2r[k0][0]);
          bf16x8 w1 = __builtin_bit_cast(bf16x8, b2r[k0][1]);
          c2[0][0] = __builtin_amdgcn_mfma_f32_16x16x32_bf16(a0, w0, c2[0][0], 0, 0, 0);
          c2[0][1] = __builtin_amdgcn_mfma_f32_16x16x32_bf16(a0, w1, c2[0][1], 0, 0, 0);
          c2[1][0] = __builtin_amdgcn_mfma_f32_16x16x32_bf16(a1, w0, c2[1][0], 0, 0, 0);
          c2[1][1] = __builtin_amdgcn_mfma_f32_16x16x32_bf16(a1, w1, c2[1][1], 0, 0, 0);
        }
        // h = elu(c2 + XU + b1) -> ldsPQ in place (same-thread RMW)
        #pragma unroll
        for (int mi = 0; mi < 2; ++mi)
          #pragma unroll
          for (int nt = 0; nt < 2; ++nt)
            #pragma unroll
            for (int r = 0; r < 4; ++r){
              int row = mi * 16 + kq * 4 + r, col = ncol + nt * 16 + ln;
              u16* pp = (u16*)(ldsPQ + SW(row, col * 2));
              float pq = bf2f(*pp);
              *pp = f2bf(eluf(c2[mi][nt][r] + pq + b1v[nt]));
            }
      }
      __syncthreads();  // h complete

      // GEMM3: h @ uW1 ; o = elu(c3 + b2) -> ldsPQ
      {
        const u16* w2p = W2c;
        asm volatile("" : "+v"(w2p));
        uint4 b3r[4][2];
        #pragma unroll
        for (int k0 = 0; k0 < 4; ++k0)
          #pragma unroll
          for (int nt = 0; nt < 2; ++nt)
            b3r[k0][nt] = *(const uint4*)(w2p + (((size_t)((k0*4 + kq)*HD + ncol + nt*16 + ln)) << 3));
        f32x4 c3[2][2] = {{zz, zz}, {zz, zz}};
        #pragma unroll
        for (int k0 = 0; k0 < 4; ++k0){
          bf16x8 a0 = *(const bf16x8*)(ldsPQ + SW(ln,      k0 * 64 + (kq << 4)));
          bf16x8 a1 = *(const bf16x8*)(ldsPQ + SW(16 + ln, k0 * 64 + (kq << 4)));
          bf16x8 w0 = __builtin_bit_cast(bf16x8, b3r[k0][0]);
          bf16x8 w1 = __builtin_bit_cast(bf16x8, b3r[k0][1]);
          c3[0][0] = __builtin_amdgcn_mfma_f32_16x16x32_bf16(a0, w0, c3[0][0], 0, 0, 0);
          c3[0][1] = __builtin_amdgcn_mfma_f32_16x16x32_bf16(a0, w1, c3[0][1], 0, 0, 0);
          c3[1][0] = __builtin_amdgcn_mfma_f32_16x16x32_bf16(a1, w0, c3[1][0], 0, 0, 0);
          c3[1][1] = __builtin_amdgcn_mfma_f32_16x16x32_bf16(a1, w1, c3[1][1], 0, 0, 0);
        }
        __syncthreads();  // h reads done
        #pragma unroll
        for (int mi = 0; mi < 2; ++mi)
          #pragma unroll
          for (int nt = 0; nt < 2; ++nt)
            #pragma unroll
            for (int r = 0; r < 4; ++r){
              int row = mi * 16 + kq * 4 + r, col = ncol + nt * 16 + ln;
              *(u16*)(ldsPQ + SW(row, col * 2)) = f2bf(eluf(c3[mi][nt][r] + b2v[nt]));
            }
      }
      __syncthreads();  // r complete
    } else {
      // EDGE/NODE: layer-2 weight frags (transient), h in-place, layer 2, r
      const u16* w1p = W1c;
      asm volatile("" : "+v"(w1p));
      uint4 b2r[4][2];
      #pragma unroll
      for (int k0 = 0; k0 < 4; ++k0)
        #pragma unroll
        for (int nt = 0; nt < 2; ++nt)
          b2r[k0][nt] = *(const uint4*)(w1p + (((size_t)((k0*4 + kq)*HD + ncol + nt*16 + ln)) << 3));

      #pragma unroll
      for (int mi = 0; mi < 2; ++mi)
        #pragma unroll
        for (int nt = 0; nt < 2; ++nt)
          #pragma unroll
          for (int r = 0; r < 4; ++r){
            int row = mi * 16 + kq * 4 + r, col = ncol + nt * 16 + ln;
            u16* pp = (u16*)(ldsPQ + SW(row, col * 2));
            float pq = bf2f(*pp);
            *pp = f2bf(eluf(c1[mi][nt][r] + pq + b0v[nt]));
          }
      __syncthreads();  // B: h complete

      f32x4 c2[2][2] = {{zz, zz}, {zz, zz}};
      #pragma unroll
      for (int k0 = 0; k0 < 4; ++k0){
        bf16x8 a0 = *(const bf16x8*)(ldsPQ + SW(ln,      k0 * 64 + (kq << 4)));
        bf16x8 a1 = *(const bf16x8*)(ldsPQ + SW(16 + ln, k0 * 64 + (kq << 4)));
        bf16x8 w0 = __builtin_bit_cast(bf16x8, b2r[k0][0]);
        bf16x8 w1 = __builtin_bit_cast(bf16x8, b2r[k0][1]);
        c2[0][0] = __builtin_amdgcn_mfma_f32_16x16x32_bf16(a0, w0, c2[0][0], 0, 0, 0);
        c2[0][1] = __builtin_amdgcn_mfma_f32_16x16x32_bf16(a0, w1, c2[0][1], 0, 0, 0);
        c2[1][0] = __builtin_amdgcn_mfma_f32_16x16x32_bf16(a1, w0, c2[1][0], 0, 0, 0);
        c2[1][1] = __builtin_amdgcn_mfma_f32_16x16x32_bf16(a1, w1, c2[1][1], 0, 0, 0);
      }
      __syncthreads();  // B2: all h reads done

      #pragma unroll
      for (int mi = 0; mi < 2; ++mi)
        #pragma unroll
        for (int nt = 0; nt < 2; ++nt)
          #pragma unroll
          for (int r = 0; r < 4; ++r){
            int row = mi * 16 + kq * 4 + r, col = ncol + nt * 16 + ln;
            *(u16*)(ldsPQ + SW(row, col * 2)) = f2bf(c2[mi][nt][r] + b1v[nt]);
          }
      __syncthreads();  // C: r complete
    }

    // ---------------- LN (+ residual) + direct u16 stores ----------------
    #pragma unroll
    for (int rr = 0; rr < 8; ++rr){
      int e = wid * 8 + rr, rg = row0 + e;
      float v0 = bf2f(*(const u16*)(ldsPQ + SW(e, lane * 2)));
      float v1 = bf2f(*(const u16*)(ldsPQ + SW(e, (64 + lane) * 2)));
      if constexpr (RESLDS){
        v0 += bf2f(*(const u16*)(ldsA + SW(e, lane * 2)));
        v1 += bf2f(*(const u16*)(ldsA + SW(e, (64 + lane) * 2)));
      } else if (rg < n_rows){
        v0 += bf2f(resid[(((size_t)rg) << 7) + lane]);
        v1 += bf2f(resid[(((size_t)rg) << 7) + 64 + lane]);
      }
      float s = v0 + v1, q = v0 * v0 + v1 * v1;
      #pragma unroll
      for (int o = 32; o; o >>= 1){ s += __shfl_xor(s, o); q += __shfl_xor(q, o); }
      float mu  = s * (1.f / 128.f);
      float var = q * (1.f / 128.f) - mu * mu;
      float rs  = rsqrtf(var + 1e-5f);
      float y0 = (v0 - mu) * rs * gl0 + bt0;
      float y1 = (v1 - mu) * rs * gl1 + bt1;
      if (rg < n_rows){
        outp[(((size_t)rg) << 7) + lane]      = f2bf(y0);
        outp[(((size_t)rg) << 7) + 64 + lane] = f2bf(y1);
      }
    }
    __syncthreads();  // D: LN reads done before next stage overwrites ldsA/ldsPQ
  }
}

// out0 = elu(x @ oW + ob)
__global__ void outhead_kernel(const u16* __restrict__ x, const float* __restrict__ oW,
                               const float* __restrict__ ob, float* __restrict__ out){
  int row  = (blockIdx.x * blockDim.x + threadIdx.x) >> 6;
  int lane = threadIdx.x & 63;
  if (row >= NF) return;
  float x0 = bf2f(x[((size_t)row << 7) + lane]);
  float x1 = bf2f(x[((size_t)row << 7) + 64 + lane]);
  float s0 = x0 * oW[lane * 3 + 0] + x1 * oW[(64 + lane) * 3 + 0];
  float s1 = x0 * oW[lane * 3 + 1] + x1 * oW[(64 + lane) * 3 + 1];
  float s2 = x0 * oW[lane * 3 + 2] + x1 * oW[(64 + lane) * 3 + 2];
  #pragma unroll
  for (int o = 32; o; o >>= 1){
    s0 += __shfl_xor(s0, o); s1 += __shfl_xor(s1, o); s2 += __shfl_xor(s2, o);
  }
  if (lane == 0){
    out[row * 3 + 0] = eluf(s0 + ob[0]);
    out[row * 3 + 1] = eluf(s1 + ob[1]);
    out[row * 3 + 2] = eluf(s2 + ob[2]);
  }
}

__global__ void idxcopy_kernel(const int* __restrict__ ei, float* __restrict__ out){
  int i = blockIdx.x * blockDim.x + threadIdx.x;
  if (i < 2 * ECNT) out[i] = (float)ei[i];
}

extern "C" void kernel_launch(void* const* d_in, const int* in_sizes, int n_in,
                              void* d_out, int out_size, void* d_ws, size_t ws_size,
                              hipStream_t stream)
{
  const float* x_in  = (const float*)d_in[0];
  const float* ea_in = (const float*)d_in[1];
  const float* pos_c = (const float*)d_in[2];
  const float* pos_f = (const float*)d_in[3];
  const int*   ei    = (const int*)d_in[4];
  const int*   clus  = (const int*)d_in[5];
  const float* eW0 = (const float*)d_in[7];
  const float* eb0 = (const float*)d_in[8];
  const float* eW1 = (const float*)d_in[9];
  const float* eb1 = (const float*)d_in[10];
  const float* eg  = (const float*)d_in[11];
  const float* ebt = (const float*)d_in[12];
  const float* nW0 = (const float*)d_in[13];
  const float* nb0 = (const float*)d_in[14];
  const float* nW1 = (const float*)d_in[15];
  const float* nb1 = (const float*)d_in[16];
  const float* ng  = (const float*)d_in[17];
  const float* nbt = (const float*)d_in[18];
  const float* dW0 = (const float*)d_in[19];
  const float* db0 = (const float*)d_in[20];
  const float* dW1 = (const float*)d_in[21];
  const float* db1 = (const float*)d_in[22];
  const float* uW0 = (const float*)d_in[23];
  const float* ub0 = (const float*)d_in[24];
  const float* uW1 = (const float*)d_in[25];
  const float* ub1 = (const float*)d_in[26];
  const float* ug  = (const float*)d_in[27];
  const float* ubt = (const float*)d_in[28];
  const float* oW  = (const float*)d_in[29];
  const float* ob  = (const float*)d_in[30];

  char* w = (char*)d_ws;
  auto alloc = [&](size_t bytes) -> char* {
    char* p = w; w += (bytes + 255) & ~(size_t)255; return p;
  };
  u16*   ea_s   = (u16*)alloc((size_t)ECNT * HD * 2);
  u16*   xa     = (u16*)alloc((size_t)NC * HD * 2);
  u16*   xb     = (u16*)alloc((size_t)NF * HD * 2);
  u16*   P      = (u16*)alloc((size_t)NF * HD * 2);
  u16*   Q      = (u16*)alloc((size_t)NF * HD * 2);
  u16*   T      = (u16*)alloc((size_t)NF * HD * 2);
  u16*   XU     = (u16*)alloc((size_t)NC * HD * 2);
  int*   deg    = (int*)alloc((size_t)NF * 4);
  int*   rowptr = (int*)alloc((size_t)(NF + 1) * 4);
  int*   cursor = (int*)alloc((size_t)NF * 4);
  int*   perm   = (int*)alloc((size_t)ECNT * 4);
  int*   esrc   = (int*)alloc((size_t)ECNT * 4);
  int*   edst   = (int*)alloc((size_t)ECNT * 4);
  int*   part   = (int*)alloc((size_t)SCB * 4);
  u16*   c_eW0  = (u16*)alloc((size_t)2 * 384 * HD * 2);
  u16*   c_eW1  = (u16*)alloc((size_t)2 * HD * HD * 2);
  u16*   c_nW0  = (u16*)alloc((size_t)2 * 256 * HD * 2);
  u16*   c_nW1  = (u16*)alloc((size_t)2 * HD * HD * 2);
  u16*   c_uW0  = (u16*)alloc((size_t)256 * HD * 2);
  u16*   c_uW1  = (u16*)alloc((size_t)HD * HD * 2);
  u16*   c_dW1  = (u16*)alloc((size_t)HD * HD * 2);

  prep_all_kernel<<<1152, 256, 0, stream>>>(eW0, eW1, nW0, nW1, uW0, uW1, dW1,
                                            c_eW0, c_eW1, c_nW0, c_nW1, c_uW0, c_uW1, c_dW1);
  f32_to_bf16_vec<<<(NC * HD / 8 + 255) / 256, 256, 0, stream>>>(x_in, xa, NC * HD / 8);

  hipMemsetAsync(deg, 0, (size_t)NF * 4, stream);
  deg_kernel<<<(ECNT + 255) / 256, 256, 0, stream>>>(ei, deg);
  scanA_kernel<<<NB_SCAN, SCB, 0, stream>>>(deg, part);
  scanB_kernel<<<1, SCB, 0, stream>>>(part);
  scanC_kernel<<<NB_SCAN, SCB, 0, stream>>>(deg, part, rowptr);
  hipMemcpyAsync(cursor, rowptr, (size_t)NF * 4, hipMemcpyDeviceToDevice, stream);
  build_perm_kernel<<<(ECNT + 255) / 256, 256, 0, stream>>>(ei, cursor, perm, esrc, edst);
  permute_ea_kernel<<<(ECNT * 16 + 255) / 256, 256, 0, stream>>>(ea_in, perm, ea_s);

  auto grd = [](int rows){ int t = (rows + 31) / 32; return t < 2048 ? t : 2048; };
  const int KS = 16 * HD * 8;   // u16 offset of one 128-K slice in chunked layout

  auto mp_iter = [&](u16* x, int n, int i){
    int npq = n < NC ? n : NC;   // edge endpoints always < NC
    lin_kernel<3><<<grd(n), 256, 0, stream>>>(
      c_eW0 + (size_t)i*384*HD, c_eW0 + (size_t)i*384*HD + KS, c_nW0 + (size_t)i*256*HD,
      x, P, Q, T, npq, npq, n, n);
    mlp_kernel<M_EDGE><<<grd(ECNT), 256, 0, stream>>>(
      c_eW0 + (size_t)i*384*HD + 2*KS, c_eW1 + (size_t)i*HD*HD, nullptr,
      eb0 + i*HD, eb1 + i*HD, nullptr, eg + i*HD, ebt + i*HD,
      ea_s, P, Q, nullptr, esrc, edst, nullptr, nullptr, nullptr,
      ea_s, ECNT, nullptr, nullptr, nullptr, nullptr);
    mlp_kernel<M_NODE><<<grd(n), 256, 0, stream>>>(
      c_nW0 + (size_t)i*256*HD + KS, c_nW1 + (size_t)i*HD*HD, nullptr,
      nb0 + i*HD, nb1 + i*HD, nullptr, ng + i*HD, nbt + i*HD,
      nullptr, T, nullptr, x, nullptr, nullptr, rowptr, ea_s, nullptr,
      x, n, nullptr, nullptr, nullptr, nullptr);
  };

  // ---- pass 1 on xa ----
  mp_iter(xa, NC, 0);
  mp_iter(xa, NC, 1);

  // ---- decoder (fused DEC1+DEC2; seg_mean over arange(NF) is identity) ----
  lin_kernel<1><<<grd(NC), 256, 0, stream>>>(
    c_uW0 + KS, nullptr, nullptr, xa, XU, nullptr, nullptr, NC, 0, 0, NC);
  mlp_kernel<M_DEC12><<<grd(NF), 256, 0, stream>>>(
    c_dW1, c_uW0, c_uW1,
    db1, ub0, ub1, ug, ubt,
    nullptr, XU, nullptr, nullptr,
    nullptr, nullptr, nullptr, nullptr, clus,
    xb, NF, dW0, db0, pos_c, pos_f);

  // ---- pass 2 on xb ----
  mp_iter(xb, NF, 0);
  mp_iter(xb, NF, 1);

  float* out = (float*)d_out;
  outhead_kernel<<<(NF + 3) / 4, 256, 0, stream>>>(xb, oW, ob, out);
  idxcopy_kernel<<<(2 * ECNT + 255) / 256, 256, 0, stream>>>(ei, out + (size_t)NF * OUTD);
}

// Round 10
// 983.004 us; speedup vs baseline: 1.9956x; 1.9956x over previous
//
#include <hip/hip_runtime.h>

// Decoder_48378511622552 — CSR-sorted, bf16, K=128 MFMA fused GNN decoder (gfx950)
// Round 10: revert EDGE reg-prefetch (R9 spilled to scratch: +300MB); non-persistent
// grids (grid == tile count, scheduler backfill); NODE CSR unroll x4; keep DEC12 fusion.

#define HD   128
#define NC   50000
#define NF   150000
#define ECNT 400000
#define OUTD 3
#define SCB  512
#define NB_SCAN ((NF + SCB - 1) / SCB)   // 293

typedef unsigned short u16;
typedef unsigned int   u32;
typedef short bf16x8 __attribute__((ext_vector_type(8)));
typedef float f32x4  __attribute__((ext_vector_type(4)));

__device__ __forceinline__ float bf2f(u32 u){ return __uint_as_float(u << 16); }
__device__ __forceinline__ u32 cvtpk(float a, float b){   // lo = bf16(a), hi = bf16(b)
  u32 r; asm("v_cvt_pk_bf16_f32 %0, %1, %2" : "=v"(r) : "v"(a), "v"(b)); return r;
}
__device__ __forceinline__ u16 f2bf(float f){ return (u16)cvtpk(f, f); }
__device__ __forceinline__ u32 addpk(u32 a, u32 b){
  return cvtpk(bf2f(a & 0xffffu) + bf2f(b & 0xffffu),
               __uint_as_float(a & 0xffff0000u) + __uint_as_float(b & 0xffff0000u));
}
__device__ __forceinline__ float eluf(float x){ return x > 0.f ? x : __expf(x) - 1.f; }
// swizzle for bf16 [32][256B] tiles
__device__ __forceinline__ int SW(int row, int byte){ return row * 256 + (byte ^ ((row & 7) << 4)); }

// ---------------- prep kernels ----------------

__global__ void prep_all_kernel(const float* __restrict__ eW0, const float* __restrict__ eW1,
                                const float* __restrict__ nW0, const float* __restrict__ nW1,
                                const float* __restrict__ uW0, const float* __restrict__ uW1,
                                const float* __restrict__ dW1,
                                u16* c_eW0, u16* c_eW1, u16* c_nW0, u16* c_nW1,
                                u16* c_uW0, u16* c_uW1, u16* c_dW1)
{
  int b = blockIdx.x;
  const float* src; u16* dst; int kb;
  if      (b <  384){ src = eW0; dst = c_eW0; kb = b * 2; }          // K=768 (2 mats)
  else if (b <  512){ src = eW1; dst = c_eW1; kb = (b - 384) * 2; }  // K=256
  else if (b <  768){ src = nW0; dst = c_nW0; kb = (b - 512) * 2; }  // K=512
  else if (b <  896){ src = nW1; dst = c_nW1; kb = (b - 768) * 2; }  // K=256
  else if (b < 1024){ src = uW0; dst = c_uW0; kb = (b - 896) * 2; }  // K=256
  else if (b < 1088){ src = uW1; dst = c_uW1; kb = (b - 1024) * 2; } // K=128
  else              { src = dW1; dst = c_dW1; kb = (b - 1088) * 2; } // K=128
  int t = threadIdx.x;
  int k = kb + (t >> 7), j = t & 127;
  dst[(((k >> 3) * HD + j) << 3) + (k & 7)] = f2bf(src[k * HD + j]);
}

__global__ void f32_to_bf16_vec(const float* __restrict__ in, u16* __restrict__ out, int n8){
  int i = blockIdx.x * blockDim.x + threadIdx.x;
  if (i >= n8) return;
  float4 f0 = ((const float4*)in)[i * 2];
  float4 f1 = ((const float4*)in)[i * 2 + 1];
  ((uint4*)out)[i] = make_uint4(cvtpk(f0.x,f0.y), cvtpk(f0.z,f0.w), cvtpk(f1.x,f1.y), cvtpk(f1.z,f1.w));
}

__global__ void deg_kernel(const int* __restrict__ ei, int* __restrict__ deg){
  int e = blockIdx.x * blockDim.x + threadIdx.x;
  if (e < ECNT) atomicAdd(&deg[ei[ECNT + e]], 1);
}

__global__ void scanA_kernel(const int* __restrict__ deg, int* __restrict__ part){
  __shared__ int s[SCB];
  int t = threadIdx.x, i = blockIdx.x * SCB + t;
  s[t] = (i < NF) ? deg[i] : 0;
  __syncthreads();
  for (int off = SCB/2; off; off >>= 1){ if (t < off) s[t] += s[t + off]; __syncthreads(); }
  if (t == 0) part[blockIdx.x] = s[0];
}

__global__ void scanB_kernel(int* __restrict__ part){
  __shared__ int s[SCB];
  int t = threadIdx.x;
  int v = (t < NB_SCAN) ? part[t] : 0;
  s[t] = v; __syncthreads();
  for (int off = 1; off < SCB; off <<= 1){
    int x = (t >= off) ? s[t - off] : 0;
    __syncthreads(); s[t] += x; __syncthreads();
  }
  if (t < NB_SCAN) part[t] = s[t] - v;   // exclusive
}

__global__ void scanC_kernel(const int* __restrict__ deg, const int* __restrict__ part,
                             int* __restrict__ rowptr){
  __shared__ int s[SCB];
  int t = threadIdx.x, i = blockIdx.x * SCB + t;
  int v = (i < NF) ? deg[i] : 0;
  s[t] = v; __syncthreads();
  for (int off = 1; off < SCB; off <<= 1){
    int x = (t >= off) ? s[t - off] : 0;
    __syncthreads(); s[t] += x; __syncthreads();
  }
  int excl = part[blockIdx.x] + s[t] - v;
  if (i < NF) rowptr[i] = excl;
  if (i == NF - 1) rowptr[NF] = excl + v;
}

__global__ void build_perm_kernel(const int* __restrict__ ei, int* __restrict__ cursor,
                                  int* __restrict__ perm, int* __restrict__ esrc,
                                  int* __restrict__ edst){
  int e = blockIdx.x * blockDim.x + threadIdx.x;
  if (e >= ECNT) return;
  int sI = ei[e], d = ei[ECNT + e];
  int p = atomicAdd(&cursor[d], 1);
  perm[p] = e; esrc[p] = sI; edst[p] = d;
}

__global__ void permute_ea_kernel(const float* __restrict__ ea_in, const int* __restrict__ perm,
                                  u16* __restrict__ ea_s){
  int i = blockIdx.x * blockDim.x + threadIdx.x;
  if (i >= ECNT * 16) return;
  int p = i >> 4, c = i & 15;
  int e = perm[p];
  const float4* src = (const float4*)(ea_in + (size_t)e * HD + c * 8);
  float4 f0 = src[0], f1 = src[1];
  ((uint4*)ea_s)[(size_t)p * 16 + c] =
      make_uint4(cvtpk(f0.x,f0.y), cvtpk(f0.z,f0.w), cvtpk(f1.x,f1.y), cvtpk(f1.z,f1.w));
}

// ---------------- fused LIN (1 or 3 outputs): o[w] = x @ W[w], bf16 out ----------------
template<int NOUT>
__global__ __launch_bounds__(256, 4)
void lin_kernel(const u16* __restrict__ Wa, const u16* __restrict__ Wb, const u16* __restrict__ Wc,
                const u16* __restrict__ x, u16* __restrict__ oA, u16* __restrict__ oB,
                u16* __restrict__ oC, int nA, int nB, int nC, int n_rows)
{
  __shared__ __align__(16) char ldsA[32 * 256];
  const int tid = threadIdx.x, lane = tid & 63, wid = tid >> 6;
  const int ln = lane & 15, kq = lane >> 4, ncol = wid * 32;

  const int row0 = blockIdx.x << 5;
  #pragma unroll
  for (int c = 0; c < 2; ++c){
    int i = tid + c * 256, row = i >> 4, kk = i & 15, rg = row0 + row;
    if (rg < n_rows)
      *(uint4*)(ldsA + SW(row, kk * 16)) = *(const uint4*)(x + (((size_t)rg) << 7) + (kk << 3));
  }
  __syncthreads();
  bf16x8 af[4][2];
  #pragma unroll
  for (int k0 = 0; k0 < 4; ++k0){
    af[k0][0] = *(const bf16x8*)(ldsA + SW(ln,      k0 * 64 + (kq << 4)));
    af[k0][1] = *(const bf16x8*)(ldsA + SW(16 + ln, k0 * 64 + (kq << 4)));
  }

  const u16* Ws[3] = {Wa, Wb, Wc};
  u16*       Os[3] = {oA, oB, oC};
  const int  Ns[3] = {nA, nB, nC};
  const f32x4 zz = {0.f, 0.f, 0.f, 0.f};
  #pragma unroll
  for (int w = 0; w < NOUT; ++w){
    if (row0 < Ns[w]){   // block-uniform guard
      const u16* wp = Ws[w];
      asm volatile("" : "+v"(wp));
      uint4 bfr[4][2];
      #pragma unroll
      for (int k0 = 0; k0 < 4; ++k0)
        #pragma unroll
        for (int nt = 0; nt < 2; ++nt)
          bfr[k0][nt] = *(const uint4*)(wp + (((size_t)((k0*4 + kq)*HD + ncol + nt*16 + ln)) << 3));
      f32x4 cc[2][2] = {{zz, zz}, {zz, zz}};
      #pragma unroll
      for (int k0 = 0; k0 < 4; ++k0){
        bf16x8 w0 = __builtin_bit_cast(bf16x8, bfr[k0][0]);
        bf16x8 w1 = __builtin_bit_cast(bf16x8, bfr[k0][1]);
        cc[0][0] = __builtin_amdgcn_mfma_f32_16x16x32_bf16(af[k0][0], w0, cc[0][0], 0, 0, 0);
        cc[0][1] = __builtin_amdgcn_mfma_f32_16x16x32_bf16(af[k0][0], w1, cc[0][1], 0, 0, 0);
        cc[1][0] = __builtin_amdgcn_mfma_f32_16x16x32_bf16(af[k0][1], w0, cc[1][0], 0, 0, 0);
        cc[1][1] = __builtin_amdgcn_mfma_f32_16x16x32_bf16(af[k0][1], w1, cc[1][1], 0, 0, 0);
      }
      u16* op = Os[w];
      #pragma unroll
      for (int mi = 0; mi < 2; ++mi)
        #pragma unroll
        for (int nt = 0; nt < 2; ++nt)
          #pragma unroll
          for (int r = 0; r < 4; ++r){
            int rg = row0 + mi * 16 + kq * 4 + r;
            if (rg < Ns[w]) op[(size_t)rg * HD + ncol + nt * 16 + ln] = f2bf(cc[mi][nt][r]);
          }
    }
  }
}

// ---------------- unified fused K=128 MFMA MLP (16 KB LDS, non-persistent) ----------------
enum { M_EDGE = 0, M_NODE = 1, M_DEC12 = 2 };

// EDGE : A = ea; h = elu(A@W0 + P[src]+Q[dst] + b0); o = h@W1 + b1;            out = LN(A + o)
// NODE : A = CSR-mean(ea); h = elu(A@W0 + T[row] + b0); o = h@W1 + b1;         out = LN(x + o)
// DEC12: h1 = elu(delta@dW0+db0); eac = elu(h1@W0 + b0); h = elu(eac@W1 + XU[clus] + b1);
//        o = elu(h@W2 + b2); out = LN(eac + o)     [eac lives in ldsA, never hits global]
template<int MODE>
__global__ __launch_bounds__(256, 4)
void mlp_kernel(const u16* __restrict__ W0c, const u16* __restrict__ W1c,
                const u16* __restrict__ W2c,
                const float* __restrict__ b0, const float* __restrict__ b1,
                const float* __restrict__ b2,
                const float* __restrict__ gw, const float* __restrict__ bw,
                const u16* __restrict__ tabA, const u16* __restrict__ addP,
                const u16* __restrict__ addQ, const u16* __restrict__ resid,
                const int* __restrict__ esrc, const int* __restrict__ edst,
                const int* __restrict__ rowptr, const u16* __restrict__ eatab,
                const int* __restrict__ clus,
                u16* __restrict__ outp, int n_rows,
                const float* __restrict__ dW0, const float* __restrict__ db0,
                const float* __restrict__ pos_c, const float* __restrict__ pos_f)
{
  constexpr bool RESLDS = (MODE == M_EDGE || MODE == M_DEC12);

  __shared__ __align__(16) char ldsA [32 * 256];          // A tile / eac (residual)
  __shared__ __align__(16) char ldsPQ[32 * 256];          // addend -> h -> r

  const int tid  = threadIdx.x;
  const int lane = tid & 63;
  const int wid  = tid >> 6;
  const int ln   = lane & 15, kq = lane >> 4;
  const int ncol = wid * 32;

  bf16x8 b1f[4][2];
  #pragma unroll
  for (int k0 = 0; k0 < 4; ++k0)
    #pragma unroll
    for (int nt = 0; nt < 2; ++nt)
      b1f[k0][nt] = *(const bf16x8*)(W0c + (((size_t)((k0*4 + kq)*HD + ncol + nt*16 + ln)) << 3));

  float b0v[2], b1v[2], b2v[2] = {0.f, 0.f};
  #pragma unroll
  for (int nt = 0; nt < 2; ++nt){ b0v[nt] = b0[ncol + nt*16 + ln]; b1v[nt] = b1[ncol + nt*16 + ln]; }
  if constexpr (MODE == M_DEC12){
    #pragma unroll
    for (int nt = 0; nt < 2; ++nt) b2v[nt] = b2[ncol + nt*16 + ln];
  }
  float gl0 = gw[lane], gl1 = gw[64 + lane], bt0 = bw[lane], bt1 = bw[64 + lane];

  const int row0 = blockIdx.x << 5;

  // ---------------- stage ----------------
  if constexpr (MODE == M_EDGE){
    #pragma unroll
    for (int c = 0; c < 2; ++c){           // ea tile + (P[src]+Q[dst]) addend, both bf16
      int i = tid + c * 256, row = i >> 4, kk = i & 15, rg = row0 + row;   // ECNT%32==0
      *(uint4*)(ldsA + SW(row, kk * 16)) =
          *(const uint4*)(tabA + (((size_t)rg) << 7) + (kk << 3));
      int sI = esrc[rg], dI = edst[rg];
      uint4 p = *(const uint4*)(addP + (((size_t)sI) << 7) + (kk << 3));
      uint4 q = *(const uint4*)(addQ + (((size_t)dI) << 7) + (kk << 3));
      *(uint4*)(ldsPQ + SW(row, kk * 16)) =
          make_uint4(addpk(p.x,q.x), addpk(p.y,q.y), addpk(p.z,q.z), addpk(p.w,q.w));
    }
  } else if constexpr (MODE == M_NODE){
    #pragma unroll
    for (int c = 0; c < 2; ++c){           // T[row] addend, bf16
      int i = tid + c * 256, row = i >> 4, kk = i & 15, rg = row0 + row;
      if (rg < n_rows)
        *(uint4*)(ldsPQ + SW(row, kk * 16)) =
            *(const uint4*)(addP + (((size_t)rg) << 7) + (kk << 3));
    }
    // CSR mean of ea -> ldsA; unroll x4 with two independent accumulator pairs
    for (int s = 0; s < 8; ++s){
      int nd = wid * 8 + s, rg = row0 + nd;
      if (rg < n_rows){
        int rp0 = rowptr[rg], rp1 = rowptr[rg + 1];
        float s0 = 0.f, s1 = 0.f, t0 = 0.f, t1 = 0.f;
        int i2 = rp0;
        for (; i2 + 3 < rp1; i2 += 4){
          u32 ua = *(const u32*)(eatab + (((size_t) i2     ) << 7) + (lane << 1));
          u32 ub = *(const u32*)(eatab + (((size_t)(i2 + 1)) << 7) + (lane << 1));
          u32 uc = *(const u32*)(eatab + (((size_t)(i2 + 2)) << 7) + (lane << 1));
          u32 ud = *(const u32*)(eatab + (((size_t)(i2 + 3)) << 7) + (lane << 1));
          s0 += bf2f(ua & 0xffffu) + bf2f(ub & 0xffffu);
          s1 += bf2f(ua >> 16)     + bf2f(ub >> 16);
          t0 += bf2f(uc & 0xffffu) + bf2f(ud & 0xffffu);
          t1 += bf2f(uc >> 16)     + bf2f(ud >> 16);
        }
        for (; i2 < rp1; ++i2){
          u32 ua = *(const u32*)(eatab + (((size_t)i2) << 7) + (lane << 1));
          s0 += bf2f(ua & 0xffffu); s1 += bf2f(ua >> 16);
        }
        s0 += t0; s1 += t1;
        int dg = rp1 - rp0;
        float rd = 1.f / (float)(dg > 0 ? dg : 1);
        *(u32*)(ldsA + SW(nd, lane << 2)) = cvtpk(s0 * rd, s1 * rd);
      }
    }
  } else { // M_DEC12: h1 = elu(delta @ dW0 + db0) -> ldsA ; XU[clus] -> ldsPQ
    #pragma unroll
    for (int c = 0; c < 2; ++c){
      int i = tid + c * 256, row = i >> 4, c8 = i & 15, rg = row0 + row;
      if (rg < n_rows){
        int cl = clus[rg];
        *(uint4*)(ldsPQ + SW(row, c8 * 16)) =
            *(const uint4*)(addP + (((size_t)cl) << 7) + (c8 << 3));
        float d0 = pos_c[cl * 2]     - pos_f[rg * 2];
        float d1 = pos_c[cl * 2 + 1] - pos_f[rg * 2 + 1];
        u32 wq[4];
        #pragma unroll
        for (int q = 0; q < 4; ++q){
          int cc = c8 * 8 + q * 2;
          float va = eluf(fmaf(d0, dW0[cc],     fmaf(d1, dW0[HD + cc],     db0[cc])));
          float vb = eluf(fmaf(d0, dW0[cc + 1], fmaf(d1, dW0[HD + cc + 1], db0[cc + 1])));
          wq[q] = cvtpk(va, vb);
        }
        *(uint4*)(ldsA + SW(row, c8 * 16)) = make_uint4(wq[0], wq[1], wq[2], wq[3]);
      }
    }
  }
  __syncthreads();   // A: stage visible

  // ---------------- layer 1 (K=128) ----------------
  const f32x4 zz = {0.f, 0.f, 0.f, 0.f};
  f32x4 c1[2][2] = {{zz, zz}, {zz, zz}};
  #pragma unroll
  for (int k0 = 0; k0 < 4; ++k0){
    bf16x8 a0 = *(const bf16x8*)(ldsA + SW(ln,      k0 * 64 + (kq << 4)));
    bf16x8 a1 = *(const bf16x8*)(ldsA + SW(16 + ln, k0 * 64 + (kq << 4)));
    c1[0][0] = __builtin_amdgcn_mfma_f32_16x16x32_bf16(a0, b1f[k0][0], c1[0][0], 0, 0, 0);
    c1[0][1] = __builtin_amdgcn_mfma_f32_16x16x32_bf16(a0, b1f[k0][1], c1[0][1], 0, 0, 0);
    c1[1][0] = __builtin_amdgcn_mfma_f32_16x16x32_bf16(a1, b1f[k0][0], c1[1][0], 0, 0, 0);
    c1[1][1] = __builtin_amdgcn_mfma_f32_16x16x32_bf16(a1, b1f[k0][1], c1[1][1], 0, 0, 0);
  }

  if constexpr (MODE == M_DEC12){
    __syncthreads();  // ldsA (h1) reads done
    // eac = elu(c1 + b0) -> ldsA (residual + GEMM2 input)
    #pragma unroll
    for (int mi = 0; mi < 2; ++mi)
      #pragma unroll
      for (int nt = 0; nt < 2; ++nt)
        #pragma unroll
        for (int r = 0; r < 4; ++r){
          int row = mi * 16 + kq * 4 + r, col = ncol + nt * 16 + ln;
          *(u16*)(ldsA + SW(row, col * 2)) = f2bf(eluf(c1[mi][nt][r] + b0v[nt]));
        }
    __syncthreads();  // eac visible

    // GEMM2: eac @ uW0a ; h = elu(c2 + XU + b1) -> ldsPQ in place
    {
      const u16* w1p = W1c;
      asm volatile("" : "+v"(w1p));
      uint4 b2r[4][2];
      #pragma unroll
      for (int k0 = 0; k0 < 4; ++k0)
        #pragma unroll
        for (int nt = 0; nt < 2; ++nt)
          b2r[k0][nt] = *(const uint4*)(w1p + (((size_t)((k0*4 + kq)*HD + ncol + nt*16 + ln)) << 3));
      f32x4 c2[2][2] = {{zz, zz}, {zz, zz}};
      #pragma unroll
      for (int k0 = 0; k0 < 4; ++k0){
        bf16x8 a0 = *(const bf16x8*)(ldsA + SW(ln,      k0 * 64 + (kq << 4)));
        bf16x8 a1 = *(const bf16x8*)(ldsA + SW(16 + ln, k0 * 64 + (kq << 4)));
        bf16x8 w0 = __builtin_bit_cast(bf16x8, b2r[k0][0]);
        bf16x8 w1 = __builtin_bit_cast(bf16x8, b2r[k0][1]);
        c2[0][0] = __builtin_amdgcn_mfma_f32_16x16x32_bf16(a0, w0, c2[0][0], 0, 0, 0);
        c2[0][1] = __builtin_amdgcn_mfma_f32_16x16x32_bf16(a0, w1, c2[0][1], 0, 0, 0);
        c2[1][0] = __builtin_amdgcn_mfma_f32_16x16x32_bf16(a1, w0, c2[1][0], 0, 0, 0);
        c2[1][1] = __builtin_amdgcn_mfma_f32_16x16x32_bf16(a1, w1, c2[1][1], 0, 0, 0);
      }
      #pragma unroll
      for (int mi = 0; mi < 2; ++mi)
        #pragma unroll
        for (int nt = 0; nt < 2; ++nt)
          #pragma unroll
          for (int r = 0; r < 4; ++r){
            int row = mi * 16 + kq * 4 + r, col = ncol + nt * 16 + ln;
            u16* pp = (u16*)(ldsPQ + SW(row, col * 2));
            float pq = bf2f(*pp);
            *pp = f2bf(eluf(c2[mi][nt][r] + pq + b1v[nt]));
          }
    }
    __syncthreads();  // h complete

    // GEMM3: h @ uW1 ; o = elu(c3 + b2) -> ldsPQ
    {
      const u16* w2p = W2c;
      asm volatile("" : "+v"(w2p));
      uint4 b3r[4][2];
      #pragma unroll
      for (int k0 = 0; k0 < 4; ++k0)
        #pragma unroll
        for (int nt = 0; nt < 2; ++nt)
          b3r[k0][nt] = *(const uint4*)(w2p + (((size_t)((k0*4 + kq)*HD + ncol + nt*16 + ln)) << 3));
      f32x4 c3[2][2] = {{zz, zz}, {zz, zz}};
      #pragma unroll
      for (int k0 = 0; k0 < 4; ++k0){
        bf16x8 a0 = *(const bf16x8*)(ldsPQ + SW(ln,      k0 * 64 + (kq << 4)));
        bf16x8 a1 = *(const bf16x8*)(ldsPQ + SW(16 + ln, k0 * 64 + (kq << 4)));
        bf16x8 w0 = __builtin_bit_cast(bf16x8, b3r[k0][0]);
        bf16x8 w1 = __builtin_bit_cast(bf16x8, b3r[k0][1]);
        c3[0][0] = __builtin_amdgcn_mfma_f32_16x16x32_bf16(a0, w0, c3[0][0], 0, 0, 0);
        c3[0][1] = __builtin_amdgcn_mfma_f32_16x16x32_bf16(a0, w1, c3[0][1], 0, 0, 0);
        c3[1][0] = __builtin_amdgcn_mfma_f32_16x16x32_bf16(a1, w0, c3[1][0], 0, 0, 0);
        c3[1][1] = __builtin_amdgcn_mfma_f32_16x16x32_bf16(a1, w1, c3[1][1], 0, 0, 0);
      }
      __syncthreads();  // h reads done
      #pragma unroll
      for (int mi = 0; mi < 2; ++mi)
        #pragma unroll
        for (int nt = 0; nt < 2; ++nt)
          #pragma unroll
          for (int r = 0; r < 4; ++r){
            int row = mi * 16 + kq * 4 + r, col = ncol + nt * 16 + ln;
            *(u16*)(ldsPQ + SW(row, col * 2)) = f2bf(eluf(c3[mi][nt][r] + b2v[nt]));
          }
    }
    __syncthreads();  // r complete
  } else {
    // EDGE/NODE: layer-2 weight frags (transient), h in-place, layer 2, r
    const u16* w1p = W1c;
    asm volatile("" : "+v"(w1p));
    uint4 b2r[4][2];
    #pragma unroll
    for (int k0 = 0; k0 < 4; ++k0)
      #pragma unroll
      for (int nt = 0; nt < 2; ++nt)
        b2r[k0][nt] = *(const uint4*)(w1p + (((size_t)((k0*4 + kq)*HD + ncol + nt*16 + ln)) << 3));

    #pragma unroll
    for (int mi = 0; mi < 2; ++mi)
      #pragma unroll
      for (int nt = 0; nt < 2; ++nt)
        #pragma unroll
        for (int r = 0; r < 4; ++r){
          int row = mi * 16 + kq * 4 + r, col = ncol + nt * 16 + ln;
          u16* pp = (u16*)(ldsPQ + SW(row, col * 2));
          float pq = bf2f(*pp);
          *pp = f2bf(eluf(c1[mi][nt][r] + pq + b0v[nt]));
        }
    __syncthreads();  // B: h complete

    f32x4 c2[2][2] = {{zz, zz}, {zz, zz}};
    #pragma unroll
    for (int k0 = 0; k0 < 4; ++k0){
      bf16x8 a0 = *(const bf16x8*)(ldsPQ + SW(ln,      k0 * 64 + (kq << 4)));
      bf16x8 a1 = *(const bf16x8*)(ldsPQ + SW(16 + ln, k0 * 64 + (kq << 4)));
      bf16x8 w0 = __builtin_bit_cast(bf16x8, b2r[k0][0]);
      bf16x8 w1 = __builtin_bit_cast(bf16x8, b2r[k0][1]);
      c2[0][0] = __builtin_amdgcn_mfma_f32_16x16x32_bf16(a0, w0, c2[0][0], 0, 0, 0);
      c2[0][1] = __builtin_amdgcn_mfma_f32_16x16x32_bf16(a0, w1, c2[0][1], 0, 0, 0);
      c2[1][0] = __builtin_amdgcn_mfma_f32_16x16x32_bf16(a1, w0, c2[1][0], 0, 0, 0);
      c2[1][1] = __builtin_amdgcn_mfma_f32_16x16x32_bf16(a1, w1, c2[1][1], 0, 0, 0);
    }
    __syncthreads();  // B2: all h reads done

    #pragma unroll
    for (int mi = 0; mi < 2; ++mi)
      #pragma unroll
      for (int nt = 0; nt < 2; ++nt)
        #pragma unroll
        for (int r = 0; r < 4; ++r){
          int row = mi * 16 + kq * 4 + r, col = ncol + nt * 16 + ln;
          *(u16*)(ldsPQ + SW(row, col * 2)) = f2bf(c2[mi][nt][r] + b1v[nt]);
        }
    __syncthreads();  // C: r complete
  }

  // ---------------- LN (+ residual) + direct u16 stores ----------------
  #pragma unroll
  for (int rr = 0; rr < 8; ++rr){
    int e = wid * 8 + rr, rg = row0 + e;
    float v0 = bf2f(*(const u16*)(ldsPQ + SW(e, lane * 2)));
    float v1 = bf2f(*(const u16*)(ldsPQ + SW(e, (64 + lane) * 2)));
    if constexpr (RESLDS){
      v0 += bf2f(*(const u16*)(ldsA + SW(e, lane * 2)));
      v1 += bf2f(*(const u16*)(ldsA + SW(e, (64 + lane) * 2)));
    } else if (rg < n_rows){
      v0 += bf2f(resid[(((size_t)rg) << 7) + lane]);
      v1 += bf2f(resid[(((size_t)rg) << 7) + 64 + lane]);
    }
    float s = v0 + v1, q = v0 * v0 + v1 * v1;
    #pragma unroll
    for (int o = 32; o; o >>= 1){ s += __shfl_xor(s, o); q += __shfl_xor(q, o); }
    float mu  = s * (1.f / 128.f);
    float var = q * (1.f / 128.f) - mu * mu;
    float rs  = rsqrtf(var + 1e-5f);
    float y0 = (v0 - mu) * rs * gl0 + bt0;
    float y1 = (v1 - mu) * rs * gl1 + bt1;
    if (rg < n_rows){
      outp[(((size_t)rg) << 7) + lane]      = f2bf(y0);
      outp[(((size_t)rg) << 7) + 64 + lane] = f2bf(y1);
    }
  }
}

// out0 = elu(x @ oW + ob)
__global__ void outhead_kernel(const u16* __restrict__ x, const float* __restrict__ oW,
                               const float* __restrict__ ob, float* __restrict__ out){
  int row  = (blockIdx.x * blockDim.x + threadIdx.x) >> 6;
  int lane = threadIdx.x & 63;
  if (row >= NF) return;
  float x0 = bf2f(x[((size_t)row << 7) + lane]);
  float x1 = bf2f(x[((size_t)row << 7) + 64 + lane]);
  float s0 = x0 * oW[lane * 3 + 0] + x1 * oW[(64 + lane) * 3 + 0];
  float s1 = x0 * oW[lane * 3 + 1] + x1 * oW[(64 + lane) * 3 + 1];
  float s2 = x0 * oW[lane * 3 + 2] + x1 * oW[(64 + lane) * 3 + 2];
  #pragma unroll
  for (int o = 32; o; o >>= 1){
    s0 += __shfl_xor(s0, o); s1 += __shfl_xor(s1, o); s2 += __shfl_xor(s2, o);
  }
  if (lane == 0){
    out[row * 3 + 0] = eluf(s0 + ob[0]);
    out[row * 3 + 1] = eluf(s1 + ob[1]);
    out[row * 3 + 2] = eluf(s2 + ob[2]);
  }
}

__global__ void idxcopy_kernel(const int* __restrict__ ei, float* __restrict__ out){
  int i = blockIdx.x * blockDim.x + threadIdx.x;
  if (i < 2 * ECNT) out[i] = (float)ei[i];
}

extern "C" void kernel_launch(void* const* d_in, const int* in_sizes, int n_in,
                              void* d_out, int out_size, void* d_ws, size_t ws_size,
                              hipStream_t stream)
{
  const float* x_in  = (const float*)d_in[0];
  const float* ea_in = (const float*)d_in[1];
  const float* pos_c = (const float*)d_in[2];
  const float* pos_f = (const float*)d_in[3];
  const int*   ei    = (const int*)d_in[4];
  const int*   clus  = (const int*)d_in[5];
  const float* eW0 = (const float*)d_in[7];
  const float* eb0 = (const float*)d_in[8];
  const float* eW1 = (const float*)d_in[9];
  const float* eb1 = (const float*)d_in[10];
  const float* eg  = (const float*)d_in[11];
  const float* ebt = (const float*)d_in[12];
  const float* nW0 = (const float*)d_in[13];
  const float* nb0 = (const float*)d_in[14];
  const float* nW1 = (const float*)d_in[15];
  const float* nb1 = (const float*)d_in[16];
  const float* ng  = (const float*)d_in[17];
  const float* nbt = (const float*)d_in[18];
  const float* dW0 = (const float*)d_in[19];
  const float* db0 = (const float*)d_in[20];
  const float* dW1 = (const float*)d_in[21];
  const float* db1 = (const float*)d_in[22];
  const float* uW0 = (const float*)d_in[23];
  const float* ub0 = (const float*)d_in[24];
  const float* uW1 = (const float*)d_in[25];
  const float* ub1 = (const float*)d_in[26];
  const float* ug  = (const float*)d_in[27];
  const float* ubt = (const float*)d_in[28];
  const float* oW  = (const float*)d_in[29];
  const float* ob  = (const float*)d_in[30];

  char* w = (char*)d_ws;
  auto alloc = [&](size_t bytes) -> char* {
    char* p = w; w += (bytes + 255) & ~(size_t)255; return p;
  };
  u16*   ea_s   = (u16*)alloc((size_t)ECNT * HD * 2);
  u16*   xa     = (u16*)alloc((size_t)NC * HD * 2);
  u16*   xb     = (u16*)alloc((size_t)NF * HD * 2);
  u16*   P      = (u16*)alloc((size_t)NF * HD * 2);
  u16*   Q      = (u16*)alloc((size_t)NF * HD * 2);
  u16*   T      = (u16*)alloc((size_t)NF * HD * 2);
  u16*   XU     = (u16*)alloc((size_t)NC * HD * 2);
  int*   deg    = (int*)alloc((size_t)NF * 4);
  int*   rowptr = (int*)alloc((size_t)(NF + 1) * 4);
  int*   cursor = (int*)alloc((size_t)NF * 4);
  int*   perm   = (int*)alloc((size_t)ECNT * 4);
  int*   esrc   = (int*)alloc((size_t)ECNT * 4);
  int*   edst   = (int*)alloc((size_t)ECNT * 4);
  int*   part   = (int*)alloc((size_t)SCB * 4);
  u16*   c_eW0  = (u16*)alloc((size_t)2 * 384 * HD * 2);
  u16*   c_eW1  = (u16*)alloc((size_t)2 * HD * HD * 2);
  u16*   c_nW0  = (u16*)alloc((size_t)2 * 256 * HD * 2);
  u16*   c_nW1  = (u16*)alloc((size_t)2 * HD * HD * 2);
  u16*   c_uW0  = (u16*)alloc((size_t)256 * HD * 2);
  u16*   c_uW1  = (u16*)alloc((size_t)HD * HD * 2);
  u16*   c_dW1  = (u16*)alloc((size_t)HD * HD * 2);

  prep_all_kernel<<<1152, 256, 0, stream>>>(eW0, eW1, nW0, nW1, uW0, uW1, dW1,
                                            c_eW0, c_eW1, c_nW0, c_nW1, c_uW0, c_uW1, c_dW1);
  f32_to_bf16_vec<<<(NC * HD / 8 + 255) / 256, 256, 0, stream>>>(x_in, xa, NC * HD / 8);

  hipMemsetAsync(deg, 0, (size_t)NF * 4, stream);
  deg_kernel<<<(ECNT + 255) / 256, 256, 0, stream>>>(ei, deg);
  scanA_kernel<<<NB_SCAN, SCB, 0, stream>>>(deg, part);
  scanB_kernel<<<1, SCB, 0, stream>>>(part);
  scanC_kernel<<<NB_SCAN, SCB, 0, stream>>>(deg, part, rowptr);
  hipMemcpyAsync(cursor, rowptr, (size_t)NF * 4, hipMemcpyDeviceToDevice, stream);
  build_perm_kernel<<<(ECNT + 255) / 256, 256, 0, stream>>>(ei, cursor, perm, esrc, edst);
  permute_ea_kernel<<<(ECNT * 16 + 255) / 256, 256, 0, stream>>>(ea_in, perm, ea_s);

  auto grd = [](int rows){ return (rows + 31) / 32; };   // non-persistent: grid == tiles
  const int KS = 16 * HD * 8;   // u16 offset of one 128-K slice in chunked layout

  auto mp_iter = [&](u16* x, int n, int i){
    int npq = n < NC ? n : NC;   // edge endpoints always < NC
    lin_kernel<3><<<grd(n), 256, 0, stream>>>(
      c_eW0 + (size_t)i*384*HD, c_eW0 + (size_t)i*384*HD + KS, c_nW0 + (size_t)i*256*HD,
      x, P, Q, T, npq, npq, n, n);
    mlp_kernel<M_EDGE><<<grd(ECNT), 256, 0, stream>>>(
      c_eW0 + (size_t)i*384*HD + 2*KS, c_eW1 + (size_t)i*HD*HD, nullptr,
      eb0 + i*HD, eb1 + i*HD, nullptr, eg + i*HD, ebt + i*HD,
      ea_s, P, Q, nullptr, esrc, edst, nullptr, nullptr, nullptr,
      ea_s, ECNT, nullptr, nullptr, nullptr, nullptr);
    mlp_kernel<M_NODE><<<grd(n), 256, 0, stream>>>(
      c_nW0 + (size_t)i*256*HD + KS, c_nW1 + (size_t)i*HD*HD, nullptr,
      nb0 + i*HD, nb1 + i*HD, nullptr, ng + i*HD, nbt + i*HD,
      nullptr, T, nullptr, x, nullptr, nullptr, rowptr, ea_s, nullptr,
      x, n, nullptr, nullptr, nullptr, nullptr);
  };

  // ---- pass 1 on xa ----
  mp_iter(xa, NC, 0);
  mp_iter(xa, NC, 1);

  // ---- decoder (fused DEC1+DEC2; seg_mean over arange(NF) is identity) ----
  lin_kernel<1><<<grd(NC), 256, 0, stream>>>(
    c_uW0 + KS, nullptr, nullptr, xa, XU, nullptr, nullptr, NC, 0, 0, NC);
  mlp_kernel<M_DEC12><<<grd(NF), 256, 0, stream>>>(
    c_dW1, c_uW0, c_uW1,
    db1, ub0, ub1, ug, ubt,
    nullptr, XU, nullptr, nullptr,
    nullptr, nullptr, nullptr, nullptr, clus,
    xb, NF, dW0, db0, pos_c, pos_f);

  // ---- pass 2 on xb ----
  mp_iter(xb, NF, 0);
  mp_iter(xb, NF, 1);

  float* out = (float*)d_out;
  outhead_kernel<<<(NF + 3) / 4, 256, 0, stream>>>(xb, oW, ob, out);
  idxcopy_kernel<<<(2 * ECNT + 255) / 256, 256, 0, stream>>>(ei, out + (size_t)NF * OUTD);
}

// Round 11
// 888.274 us; speedup vs baseline: 2.2085x; 1.1066x over previous
//
#include <hip/hip_runtime.h>

// Decoder_48378511622552 — CSR-sorted, bf16, K=128 MFMA fused GNN decoder (gfx950)
// Round 11: R10 base + NODE computes T=x@nW0a inline (MFMA-accumulated), LIN3->LIN2
// (P,Q over NC rows only), NODE skips CSR+aggGEMM for block-uniform row0>=NC (deg==0).

#define HD   128
#define NC   50000
#define NF   150000
#define ECNT 400000
#define OUTD 3
#define SCB  512
#define NB_SCAN ((NF + SCB - 1) / SCB)   // 293

typedef unsigned short u16;
typedef unsigned int   u32;
typedef short bf16x8 __attribute__((ext_vector_type(8)));
typedef float f32x4  __attribute__((ext_vector_type(4)));

__device__ __forceinline__ float bf2f(u32 u){ return __uint_as_float(u << 16); }
__device__ __forceinline__ u32 cvtpk(float a, float b){   // lo = bf16(a), hi = bf16(b)
  u32 r; asm("v_cvt_pk_bf16_f32 %0, %1, %2" : "=v"(r) : "v"(a), "v"(b)); return r;
}
__device__ __forceinline__ u16 f2bf(float f){ return (u16)cvtpk(f, f); }
__device__ __forceinline__ u32 addpk(u32 a, u32 b){
  return cvtpk(bf2f(a & 0xffffu) + bf2f(b & 0xffffu),
               __uint_as_float(a & 0xffff0000u) + __uint_as_float(b & 0xffff0000u));
}
__device__ __forceinline__ float eluf(float x){ return x > 0.f ? x : __expf(x) - 1.f; }
// swizzle for bf16 [32][256B] tiles
__device__ __forceinline__ int SW(int row, int byte){ return row * 256 + (byte ^ ((row & 7) << 4)); }

// ---------------- prep kernels ----------------

__global__ void prep_all_kernel(const float* __restrict__ eW0, const float* __restrict__ eW1,
                                const float* __restrict__ nW0, const float* __restrict__ nW1,
                                const float* __restrict__ uW0, const float* __restrict__ uW1,
                                const float* __restrict__ dW1,
                                u16* c_eW0, u16* c_eW1, u16* c_nW0, u16* c_nW1,
                                u16* c_uW0, u16* c_uW1, u16* c_dW1)
{
  int b = blockIdx.x;
  const float* src; u16* dst; int kb;
  if      (b <  384){ src = eW0; dst = c_eW0; kb = b * 2; }          // K=768 (2 mats)
  else if (b <  512){ src = eW1; dst = c_eW1; kb = (b - 384) * 2; }  // K=256
  else if (b <  768){ src = nW0; dst = c_nW0; kb = (b - 512) * 2; }  // K=512
  else if (b <  896){ src = nW1; dst = c_nW1; kb = (b - 768) * 2; }  // K=256
  else if (b < 1024){ src = uW0; dst = c_uW0; kb = (b - 896) * 2; }  // K=256
  else if (b < 1088){ src = uW1; dst = c_uW1; kb = (b - 1024) * 2; } // K=128
  else              { src = dW1; dst = c_dW1; kb = (b - 1088) * 2; } // K=128
  int t = threadIdx.x;
  int k = kb + (t >> 7), j = t & 127;
  dst[(((k >> 3) * HD + j) << 3) + (k & 7)] = f2bf(src[k * HD + j]);
}

__global__ void f32_to_bf16_vec(const float* __restrict__ in, u16* __restrict__ out, int n8){
  int i = blockIdx.x * blockDim.x + threadIdx.x;
  if (i >= n8) return;
  float4 f0 = ((const float4*)in)[i * 2];
  float4 f1 = ((const float4*)in)[i * 2 + 1];
  ((uint4*)out)[i] = make_uint4(cvtpk(f0.x,f0.y), cvtpk(f0.z,f0.w), cvtpk(f1.x,f1.y), cvtpk(f1.z,f1.w));
}

__global__ void deg_kernel(const int* __restrict__ ei, int* __restrict__ deg){
  int e = blockIdx.x * blockDim.x + threadIdx.x;
  if (e < ECNT) atomicAdd(&deg[ei[ECNT + e]], 1);
}

__global__ void scanA_kernel(const int* __restrict__ deg, int* __restrict__ part){
  __shared__ int s[SCB];
  int t = threadIdx.x, i = blockIdx.x * SCB + t;
  s[t] = (i < NF) ? deg[i] : 0;
  __syncthreads();
  for (int off = SCB/2; off; off >>= 1){ if (t < off) s[t] += s[t + off]; __syncthreads(); }
  if (t == 0) part[blockIdx.x] = s[0];
}

__global__ void scanB_kernel(int* __restrict__ part){
  __shared__ int s[SCB];
  int t = threadIdx.x;
  int v = (t < NB_SCAN) ? part[t] : 0;
  s[t] = v; __syncthreads();
  for (int off = 1; off < SCB; off <<= 1){
    int x = (t >= off) ? s[t - off] : 0;
    __syncthreads(); s[t] += x; __syncthreads();
  }
  if (t < NB_SCAN) part[t] = s[t] - v;   // exclusive
}

__global__ void scanC_kernel(const int* __restrict__ deg, const int* __restrict__ part,
                             int* __restrict__ rowptr){
  __shared__ int s[SCB];
  int t = threadIdx.x, i = blockIdx.x * SCB + t;
  int v = (i < NF) ? deg[i] : 0;
  s[t] = v; __syncthreads();
  for (int off = 1; off < SCB; off <<= 1){
    int x = (t >= off) ? s[t - off] : 0;
    __syncthreads(); s[t] += x; __syncthreads();
  }
  int excl = part[blockIdx.x] + s[t] - v;
  if (i < NF) rowptr[i] = excl;
  if (i == NF - 1) rowptr[NF] = excl + v;
}

__global__ void build_perm_kernel(const int* __restrict__ ei, int* __restrict__ cursor,
                                  int* __restrict__ perm, int* __restrict__ esrc,
                                  int* __restrict__ edst){
  int e = blockIdx.x * blockDim.x + threadIdx.x;
  if (e >= ECNT) return;
  int sI = ei[e], d = ei[ECNT + e];
  int p = atomicAdd(&cursor[d], 1);
  perm[p] = e; esrc[p] = sI; edst[p] = d;
}

__global__ void permute_ea_kernel(const float* __restrict__ ea_in, const int* __restrict__ perm,
                                  u16* __restrict__ ea_s){
  int i = blockIdx.x * blockDim.x + threadIdx.x;
  if (i >= ECNT * 16) return;
  int p = i >> 4, c = i & 15;
  int e = perm[p];
  const float4* src = (const float4*)(ea_in + (size_t)e * HD + c * 8);
  float4 f0 = src[0], f1 = src[1];
  ((uint4*)ea_s)[(size_t)p * 16 + c] =
      make_uint4(cvtpk(f0.x,f0.y), cvtpk(f0.z,f0.w), cvtpk(f1.x,f1.y), cvtpk(f1.z,f1.w));
}

// ---------------- fused LIN (1 or 2 outputs): o[w] = x @ W[w], bf16 out ----------------
template<int NOUT>
__global__ __launch_bounds__(256, 4)
void lin_kernel(const u16* __restrict__ Wa, const u16* __restrict__ Wb,
                const u16* __restrict__ x, u16* __restrict__ oA, u16* __restrict__ oB,
                int n_rows)
{
  __shared__ __align__(16) char ldsA[32 * 256];
  const int tid = threadIdx.x, lane = tid & 63, wid = tid >> 6;
  const int ln = lane & 15, kq = lane >> 4, ncol = wid * 32;

  const int row0 = blockIdx.x << 5;
  #pragma unroll
  for (int c = 0; c < 2; ++c){
    int i = tid + c * 256, row = i >> 4, kk = i & 15, rg = row0 + row;
    if (rg < n_rows)
      *(uint4*)(ldsA + SW(row, kk * 16)) = *(const uint4*)(x + (((size_t)rg) << 7) + (kk << 3));
  }
  __syncthreads();
  bf16x8 af[4][2];
  #pragma unroll
  for (int k0 = 0; k0 < 4; ++k0){
    af[k0][0] = *(const bf16x8*)(ldsA + SW(ln,      k0 * 64 + (kq << 4)));
    af[k0][1] = *(const bf16x8*)(ldsA + SW(16 + ln, k0 * 64 + (kq << 4)));
  }

  const u16* Ws[2] = {Wa, Wb};
  u16*       Os[2] = {oA, oB};
  const f32x4 zz = {0.f, 0.f, 0.f, 0.f};
  #pragma unroll
  for (int w = 0; w < NOUT; ++w){
    const u16* wp = Ws[w];
    asm volatile("" : "+v"(wp));
    uint4 bfr[4][2];
    #pragma unroll
    for (int k0 = 0; k0 < 4; ++k0)
      #pragma unroll
      for (int nt = 0; nt < 2; ++nt)
        bfr[k0][nt] = *(const uint4*)(wp + (((size_t)((k0*4 + kq)*HD + ncol + nt*16 + ln)) << 3));
    f32x4 cc[2][2] = {{zz, zz}, {zz, zz}};
    #pragma unroll
    for (int k0 = 0; k0 < 4; ++k0){
      bf16x8 w0 = __builtin_bit_cast(bf16x8, bfr[k0][0]);
      bf16x8 w1 = __builtin_bit_cast(bf16x8, bfr[k0][1]);
      cc[0][0] = __builtin_amdgcn_mfma_f32_16x16x32_bf16(af[k0][0], w0, cc[0][0], 0, 0, 0);
      cc[0][1] = __builtin_amdgcn_mfma_f32_16x16x32_bf16(af[k0][0], w1, cc[0][1], 0, 0, 0);
      cc[1][0] = __builtin_amdgcn_mfma_f32_16x16x32_bf16(af[k0][1], w0, cc[1][0], 0, 0, 0);
      cc[1][1] = __builtin_amdgcn_mfma_f32_16x16x32_bf16(af[k0][1], w1, cc[1][1], 0, 0, 0);
    }
    u16* op = Os[w];
    #pragma unroll
    for (int mi = 0; mi < 2; ++mi)
      #pragma unroll
      for (int nt = 0; nt < 2; ++nt)
        #pragma unroll
        for (int r = 0; r < 4; ++r){
          int rg = row0 + mi * 16 + kq * 4 + r;
          if (rg < n_rows) op[(size_t)rg * HD + ncol + nt * 16 + ln] = f2bf(cc[mi][nt][r]);
        }
  }
}

// ---------------- unified fused K=128 MFMA MLP (16 KB LDS, non-persistent) ----------------
enum { M_EDGE = 0, M_NODE = 1, M_DEC12 = 2 };

// EDGE : A = ea; h = elu(A@W0 + P[src]+Q[dst] + b0); o = h@W1 + b1;            out = LN(A + o)
// NODE : cT = x@W0c(nW0a); if(row0<NC){A=CSR-mean(ea); cT += A@W1c(nW0b)};
//        h = elu(cT + b0); o = h@W2c(nW1) + b1;                                out = LN(x + o)
// DEC12: h1 = elu(delta@dW0+db0); eac = elu(h1@W0 + b0); h = elu(eac@W1 + XU[clus] + b1);
//        o = elu(h@W2 + b2); out = LN(eac + o)     [eac lives in ldsA, never hits global]
template<int MODE>
__global__ __launch_bounds__(256, 4)
void mlp_kernel(const u16* __restrict__ W0c, const u16* __restrict__ W1c,
                const u16* __restrict__ W2c,
                const float* __restrict__ b0, const float* __restrict__ b1,
                const float* __restrict__ b2,
                const float* __restrict__ gw, const float* __restrict__ bw,
                const u16* __restrict__ tabA, const u16* __restrict__ addP,
                const u16* __restrict__ addQ, const u16* __restrict__ resid,
                const int* __restrict__ esrc, const int* __restrict__ edst,
                const int* __restrict__ rowptr, const u16* __restrict__ eatab,
                const int* __restrict__ clus,
                u16* __restrict__ outp, int n_rows,
                const float* __restrict__ dW0, const float* __restrict__ db0,
                const float* __restrict__ pos_c, const float* __restrict__ pos_f)
{
  constexpr bool RESLDS = (MODE == M_EDGE || MODE == M_DEC12);

  __shared__ __align__(16) char ldsA [32 * 256];          // A tile / x / eac (residual)
  __shared__ __align__(16) char ldsPQ[32 * 256];          // addend -> h -> r

  const int tid  = threadIdx.x;
  const int lane = tid & 63;
  const int wid  = tid >> 6;
  const int ln   = lane & 15, kq = lane >> 4;
  const int ncol = wid * 32;

  bf16x8 b1f[4][2];
  #pragma unroll
  for (int k0 = 0; k0 < 4; ++k0)
    #pragma unroll
    for (int nt = 0; nt < 2; ++nt)
      b1f[k0][nt] = *(const bf16x8*)(W0c + (((size_t)((k0*4 + kq)*HD + ncol + nt*16 + ln)) << 3));

  float b0v[2], b1v[2], b2v[2] = {0.f, 0.f};
  #pragma unroll
  for (int nt = 0; nt < 2; ++nt){ b0v[nt] = b0[ncol + nt*16 + ln]; b1v[nt] = b1[ncol + nt*16 + ln]; }
  if constexpr (MODE == M_DEC12){
    #pragma unroll
    for (int nt = 0; nt < 2; ++nt) b2v[nt] = b2[ncol + nt*16 + ln];
  }
  float gl0 = gw[lane], gl1 = gw[64 + lane], bt0 = bw[lane], bt1 = bw[64 + lane];

  const int row0 = blockIdx.x << 5;

  // ---------------- stage ----------------
  if constexpr (MODE == M_EDGE){
    #pragma unroll
    for (int c = 0; c < 2; ++c){           // ea tile + (P[src]+Q[dst]) addend, both bf16
      int i = tid + c * 256, row = i >> 4, kk = i & 15, rg = row0 + row;   // ECNT%32==0
      *(uint4*)(ldsA + SW(row, kk * 16)) =
          *(const uint4*)(tabA + (((size_t)rg) << 7) + (kk << 3));
      int sI = esrc[rg], dI = edst[rg];
      uint4 p = *(const uint4*)(addP + (((size_t)sI) << 7) + (kk << 3));
      uint4 q = *(const uint4*)(addQ + (((size_t)dI) << 7) + (kk << 3));
      *(uint4*)(ldsPQ + SW(row, kk * 16)) =
          make_uint4(addpk(p.x,q.x), addpk(p.y,q.y), addpk(p.z,q.z), addpk(p.w,q.w));
    }
  } else if constexpr (MODE == M_NODE){
    #pragma unroll
    for (int c = 0; c < 2; ++c){           // x tile -> ldsA (for cT = x @ nW0a)
      int i = tid + c * 256, row = i >> 4, kk = i & 15, rg = row0 + row;
      if (rg < n_rows)
        *(uint4*)(ldsA + SW(row, kk * 16)) =
            *(const uint4*)(tabA + (((size_t)rg) << 7) + (kk << 3));
    }
  } else { // M_DEC12: h1 = elu(delta @ dW0 + db0) -> ldsA ; XU[clus] -> ldsPQ
    #pragma unroll
    for (int c = 0; c < 2; ++c){
      int i = tid + c * 256, row = i >> 4, c8 = i & 15, rg = row0 + row;
      if (rg < n_rows){
        int cl = clus[rg];
        *(uint4*)(ldsPQ + SW(row, c8 * 16)) =
            *(const uint4*)(addP + (((size_t)cl) << 7) + (c8 << 3));
        float d0 = pos_c[cl * 2]     - pos_f[rg * 2];
        float d1 = pos_c[cl * 2 + 1] - pos_f[rg * 2 + 1];
        u32 wq[4];
        #pragma unroll
        for (int q = 0; q < 4; ++q){
          int cc = c8 * 8 + q * 2;
          float va = eluf(fmaf(d0, dW0[cc],     fmaf(d1, dW0[HD + cc],     db0[cc])));
          float vb = eluf(fmaf(d0, dW0[cc + 1], fmaf(d1, dW0[HD + cc + 1], db0[cc + 1])));
          wq[q] = cvtpk(va, vb);
        }
        *(uint4*)(ldsA + SW(row, c8 * 16)) = make_uint4(wq[0], wq[1], wq[2], wq[3]);
      }
    }
  }
  __syncthreads();   // A: stage visible

  // ---------------- layer 1 (K=128): c1 = ldsA @ b1f ----------------
  const f32x4 zz = {0.f, 0.f, 0.f, 0.f};
  f32x4 c1[2][2] = {{zz, zz}, {zz, zz}};
  #pragma unroll
  for (int k0 = 0; k0 < 4; ++k0){
    bf16x8 a0 = *(const bf16x8*)(ldsA + SW(ln,      k0 * 64 + (kq << 4)));
    bf16x8 a1 = *(const bf16x8*)(ldsA + SW(16 + ln, k0 * 64 + (kq << 4)));
    c1[0][0] = __builtin_amdgcn_mfma_f32_16x16x32_bf16(a0, b1f[k0][0], c1[0][0], 0, 0, 0);
    c1[0][1] = __builtin_amdgcn_mfma_f32_16x16x32_bf16(a0, b1f[k0][1], c1[0][1], 0, 0, 0);
    c1[1][0] = __builtin_amdgcn_mfma_f32_16x16x32_bf16(a1, b1f[k0][0], c1[1][0], 0, 0, 0);
    c1[1][1] = __builtin_amdgcn_mfma_f32_16x16x32_bf16(a1, b1f[k0][1], c1[1][1], 0, 0, 0);
  }

  if constexpr (MODE == M_DEC12){
    __syncthreads();  // ldsA (h1) reads done
    // eac = elu(c1 + b0) -> ldsA (residual + GEMM2 input)
    #pragma unroll
    for (int mi = 0; mi < 2; ++mi)
      #pragma unroll
      for (int nt = 0; nt < 2; ++nt)
        #pragma unroll
        for (int r = 0; r < 4; ++r){
          int row = mi * 16 + kq * 4 + r, col = ncol + nt * 16 + ln;
          *(u16*)(ldsA + SW(row, col * 2)) = f2bf(eluf(c1[mi][nt][r] + b0v[nt]));
        }
    __syncthreads();  // eac visible

    // GEMM2: eac @ uW0a ; h = elu(c2 + XU + b1) -> ldsPQ in place
    {
      const u16* w1p = W1c;
      asm volatile("" : "+v"(w1p));
      uint4 b2r[4][2];
      #pragma unroll
      for (int k0 = 0; k0 < 4; ++k0)
        #pragma unroll
        for (int nt = 0; nt < 2; ++nt)
          b2r[k0][nt] = *(const uint4*)(w1p + (((size_t)((k0*4 + kq)*HD + ncol + nt*16 + ln)) << 3));
      f32x4 c2[2][2] = {{zz, zz}, {zz, zz}};
      #pragma unroll
      for (int k0 = 0; k0 < 4; ++k0){
        bf16x8 a0 = *(const bf16x8*)(ldsA + SW(ln,      k0 * 64 + (kq << 4)));
        bf16x8 a1 = *(const bf16x8*)(ldsA + SW(16 + ln, k0 * 64 + (kq << 4)));
        bf16x8 w0 = __builtin_bit_cast(bf16x8, b2r[k0][0]);
        bf16x8 w1 = __builtin_bit_cast(bf16x8, b2r[k0][1]);
        c2[0][0] = __builtin_amdgcn_mfma_f32_16x16x32_bf16(a0, w0, c2[0][0], 0, 0, 0);
        c2[0][1] = __builtin_amdgcn_mfma_f32_16x16x32_bf16(a0, w1, c2[0][1], 0, 0, 0);
        c2[1][0] = __builtin_amdgcn_mfma_f32_16x16x32_bf16(a1, w0, c2[1][0], 0, 0, 0);
        c2[1][1] = __builtin_amdgcn_mfma_f32_16x16x32_bf16(a1, w1, c2[1][1], 0, 0, 0);
      }
      #pragma unroll
      for (int mi = 0; mi < 2; ++mi)
        #pragma unroll
        for (int nt = 0; nt < 2; ++nt)
          #pragma unroll
          for (int r = 0; r < 4; ++r){
            int row = mi * 16 + kq * 4 + r, col = ncol + nt * 16 + ln;
            u16* pp = (u16*)(ldsPQ + SW(row, col * 2));
            float pq = bf2f(*pp);
            *pp = f2bf(eluf(c2[mi][nt][r] + pq + b1v[nt]));
          }
    }
    __syncthreads();  // h complete

    // GEMM3: h @ uW1 ; o = elu(c3 + b2) -> ldsPQ
    {
      const u16* w2p = W2c;
      asm volatile("" : "+v"(w2p));
      uint4 b3r[4][2];
      #pragma unroll
      for (int k0 = 0; k0 < 4; ++k0)
        #pragma unroll
        for (int nt = 0; nt < 2; ++nt)
          b3r[k0][nt] = *(const uint4*)(w2p + (((size_t)((k0*4 + kq)*HD + ncol + nt*16 + ln)) << 3));
      f32x4 c3[2][2] = {{zz, zz}, {zz, zz}};
      #pragma unroll
      for (int k0 = 0; k0 < 4; ++k0){
        bf16x8 a0 = *(const bf16x8*)(ldsPQ + SW(ln,      k0 * 64 + (kq << 4)));
        bf16x8 a1 = *(const bf16x8*)(ldsPQ + SW(16 + ln, k0 * 64 + (kq << 4)));
        bf16x8 w0 = __builtin_bit_cast(bf16x8, b3r[k0][0]);
        bf16x8 w1 = __builtin_bit_cast(bf16x8, b3r[k0][1]);
        c3[0][0] = __builtin_amdgcn_mfma_f32_16x16x32_bf16(a0, w0, c3[0][0], 0, 0, 0);
        c3[0][1] = __builtin_amdgcn_mfma_f32_16x16x32_bf16(a0, w1, c3[0][1], 0, 0, 0);
        c3[1][0] = __builtin_amdgcn_mfma_f32_16x16x32_bf16(a1, w0, c3[1][0], 0, 0, 0);
        c3[1][1] = __builtin_amdgcn_mfma_f32_16x16x32_bf16(a1, w1, c3[1][1], 0, 0, 0);
      }
      __syncthreads();  // h reads done
      #pragma unroll
      for (int mi = 0; mi < 2; ++mi)
        #pragma unroll
        for (int nt = 0; nt < 2; ++nt)
          #pragma unroll
          for (int r = 0; r < 4; ++r){
            int row = mi * 16 + kq * 4 + r, col = ncol + nt * 16 + ln;
            *(u16*)(ldsPQ + SW(row, col * 2)) = f2bf(eluf(c3[mi][nt][r] + b2v[nt]));
          }
    }
    __syncthreads();  // r complete
  } else if constexpr (MODE == M_NODE){
    __syncthreads();  // x frag reads done (before CSR overwrites ldsA)
    const bool act = (row0 < NC);   // rows >= NC have degree 0 -> A = 0 (block-uniform)
    if (act){
      // CSR mean of ea -> ldsA; unroll x4, two independent accumulator pairs
      for (int s = 0; s < 8; ++s){
        int nd = wid * 8 + s, rg = row0 + nd;
        if (rg < n_rows){
          int rp0 = rowptr[rg], rp1 = rowptr[rg + 1];
          float s0 = 0.f, s1 = 0.f, t0 = 0.f, t1 = 0.f;
          int i2 = rp0;
          for (; i2 + 3 < rp1; i2 += 4){
            u32 ua = *(const u32*)(eatab + (((size_t) i2     ) << 7) + (lane << 1));
            u32 ub = *(const u32*)(eatab + (((size_t)(i2 + 1)) << 7) + (lane << 1));
            u32 uc = *(const u32*)(eatab + (((size_t)(i2 + 2)) << 7) + (lane << 1));
            u32 ud = *(const u32*)(eatab + (((size_t)(i2 + 3)) << 7) + (lane << 1));
            s0 += bf2f(ua & 0xffffu) + bf2f(ub & 0xffffu);
            s1 += bf2f(ua >> 16)     + bf2f(ub >> 16);
            t0 += bf2f(uc & 0xffffu) + bf2f(ud & 0xffffu);
            t1 += bf2f(uc >> 16)     + bf2f(ud >> 16);
          }
          for (; i2 < rp1; ++i2){
            u32 ua = *(const u32*)(eatab + (((size_t)i2) << 7) + (lane << 1));
            s0 += bf2f(ua & 0xffffu); s1 += bf2f(ua >> 16);
          }
          s0 += t0; s1 += t1;
          int dg = rp1 - rp0;
          float rd = 1.f / (float)(dg > 0 ? dg : 1);
          *(u32*)(ldsA + SW(nd, lane << 2)) = cvtpk(s0 * rd, s1 * rd);
        }
      }
    }
    __syncthreads();  // A(mean) visible
    if (act){
      // c1 += A @ nW0b (accumulate into cT)
      const u16* wbp = W1c;
      asm volatile("" : "+v"(wbp));
      uint4 bbr[4][2];
      #pragma unroll
      for (int k0 = 0; k0 < 4; ++k0)
        #pragma unroll
        for (int nt = 0; nt < 2; ++nt)
          bbr[k0][nt] = *(const uint4*)(wbp + (((size_t)((k0*4 + kq)*HD + ncol + nt*16 + ln)) << 3));
      #pragma unroll
      for (int k0 = 0; k0 < 4; ++k0){
        bf16x8 a0 = *(const bf16x8*)(ldsA + SW(ln,      k0 * 64 + (kq << 4)));
        bf16x8 a1 = *(const bf16x8*)(ldsA + SW(16 + ln, k0 * 64 + (kq << 4)));
        bf16x8 w0 = __builtin_bit_cast(bf16x8, bbr[k0][0]);
        bf16x8 w1 = __builtin_bit_cast(bf16x8, bbr[k0][1]);
        c1[0][0] = __builtin_amdgcn_mfma_f32_16x16x32_bf16(a0, w0, c1[0][0], 0, 0, 0);
        c1[0][1] = __builtin_amdgcn_mfma_f32_16x16x32_bf16(a0, w1, c1[0][1], 0, 0, 0);
        c1[1][0] = __builtin_amdgcn_mfma_f32_16x16x32_bf16(a1, w0, c1[1][0], 0, 0, 0);
        c1[1][1] = __builtin_amdgcn_mfma_f32_16x16x32_bf16(a1, w1, c1[1][1], 0, 0, 0);
      }
    }
    // h = elu(c1 + b0) -> ldsPQ
    #pragma unroll
    for (int mi = 0; mi < 2; ++mi)
      #pragma unroll
      for (int nt = 0; nt < 2; ++nt)
        #pragma unroll
        for (int r = 0; r < 4; ++r){
          int row = mi * 16 + kq * 4 + r, col = ncol + nt * 16 + ln;
          *(u16*)(ldsPQ + SW(row, col * 2)) = f2bf(eluf(c1[mi][nt][r] + b0v[nt]));
        }
    __syncthreads();  // h complete

    // layer 2: c2 = h @ nW1 ; r = c2 + b1 -> ldsPQ
    {
      const u16* w2p = W2c;
      asm volatile("" : "+v"(w2p));
      uint4 b3r[4][2];
      #pragma unroll
      for (int k0 = 0; k0 < 4; ++k0)
        #pragma unroll
        for (int nt = 0; nt < 2; ++nt)
          b3r[k0][nt] = *(const uint4*)(w2p + (((size_t)((k0*4 + kq)*HD + ncol + nt*16 + ln)) << 3));
      f32x4 c2[2][2] = {{zz, zz}, {zz, zz}};
      #pragma unroll
      for (int k0 = 0; k0 < 4; ++k0){
        bf16x8 a0 = *(const bf16x8*)(ldsPQ + SW(ln,      k0 * 64 + (kq << 4)));
        bf16x8 a1 = *(const bf16x8*)(ldsPQ + SW(16 + ln, k0 * 64 + (kq << 4)));
        bf16x8 w0 = __builtin_bit_cast(bf16x8, b3r[k0][0]);
        bf16x8 w1 = __builtin_bit_cast(bf16x8, b3r[k0][1]);
        c2[0][0] = __builtin_amdgcn_mfma_f32_16x16x32_bf16(a0, w0, c2[0][0], 0, 0, 0);
        c2[0][1] = __builtin_amdgcn_mfma_f32_16x16x32_bf16(a0, w1, c2[0][1], 0, 0, 0);
        c2[1][0] = __builtin_amdgcn_mfma_f32_16x16x32_bf16(a1, w0, c2[1][0], 0, 0, 0);
        c2[1][1] = __builtin_amdgcn_mfma_f32_16x16x32_bf16(a1, w1, c2[1][1], 0, 0, 0);
      }
      __syncthreads();  // h reads done
      #pragma unroll
      for (int mi = 0; mi < 2; ++mi)
        #pragma unroll
        for (int nt = 0; nt < 2; ++nt)
          #pragma unroll
          for (int r = 0; r < 4; ++r){
            int row = mi * 16 + kq * 4 + r, col = ncol + nt * 16 + ln;
            *(u16*)(ldsPQ + SW(row, col * 2)) = f2bf(c2[mi][nt][r] + b1v[nt]);
          }
    }
    __syncthreads();  // r complete
  } else {
    // EDGE: layer-2 weight frags (transient), h in-place, layer 2, r
    const u16* w1p = W1c;
    asm volatile("" : "+v"(w1p));
    uint4 b2r[4][2];
    #pragma unroll
    for (int k0 = 0; k0 < 4; ++k0)
      #pragma unroll
      for (int nt = 0; nt < 2; ++nt)
        b2r[k0][nt] = *(const uint4*)(w1p + (((size_t)((k0*4 + kq)*HD + ncol + nt*16 + ln)) << 3));

    #pragma unroll
    for (int mi = 0; mi < 2; ++mi)
      #pragma unroll
      for (int nt = 0; nt < 2; ++nt)
        #pragma unroll
        for (int r = 0; r < 4; ++r){
          int row = mi * 16 + kq * 4 + r, col = ncol + nt * 16 + ln;
          u16* pp = (u16*)(ldsPQ + SW(row, col * 2));
          float pq = bf2f(*pp);
          *pp = f2bf(eluf(c1[mi][nt][r] + pq + b0v[nt]));
        }
    __syncthreads();  // B: h complete

    f32x4 c2[2][2] = {{zz, zz}, {zz, zz}};
    #pragma unroll
    for (int k0 = 0; k0 < 4; ++k0){
      bf16x8 a0 = *(const bf16x8*)(ldsPQ + SW(ln,      k0 * 64 + (kq << 4)));
      bf16x8 a1 = *(const bf16x8*)(ldsPQ + SW(16 + ln, k0 * 64 + (kq << 4)));
      bf16x8 w0 = __builtin_bit_cast(bf16x8, b2r[k0][0]);
      bf16x8 w1 = __builtin_bit_cast(bf16x8, b2r[k0][1]);
      c2[0][0] = __builtin_amdgcn_mfma_f32_16x16x32_bf16(a0, w0, c2[0][0], 0, 0, 0);
      c2[0][1] = __builtin_amdgcn_mfma_f32_16x16x32_bf16(a0, w1, c2[0][1], 0, 0, 0);
      c2[1][0] = __builtin_amdgcn_mfma_f32_16x16x32_bf16(a1, w0, c2[1][0], 0, 0, 0);
      c2[1][1] = __builtin_amdgcn_mfma_f32_16x16x32_bf16(a1, w1, c2[1][1], 0, 0, 0);
    }
    __syncthreads();  // B2: all h reads done

    #pragma unroll
    for (int mi = 0; mi < 2; ++mi)
      #pragma unroll
      for (int nt = 0; nt < 2; ++nt)
        #pragma unroll
        for (int r = 0; r < 4; ++r){
          int row = mi * 16 + kq * 4 + r, col = ncol + nt * 16 + ln;
          *(u16*)(ldsPQ + SW(row, col * 2)) = f2bf(c2[mi][nt][r] + b1v[nt]);
        }
    __syncthreads();  // C: r complete
  }

  // ---------------- LN (+ residual) + direct u16 stores ----------------
  #pragma unroll
  for (int rr = 0; rr < 8; ++rr){
    int e = wid * 8 + rr, rg = row0 + e;
    float v0 = bf2f(*(const u16*)(ldsPQ + SW(e, lane * 2)));
    float v1 = bf2f(*(const u16*)(ldsPQ + SW(e, (64 + lane) * 2)));
    if constexpr (RESLDS){
      v0 += bf2f(*(const u16*)(ldsA + SW(e, lane * 2)));
      v1 += bf2f(*(const u16*)(ldsA + SW(e, (64 + lane) * 2)));
    } else if (rg < n_rows){
      v0 += bf2f(resid[(((size_t)rg) << 7) + lane]);
      v1 += bf2f(resid[(((size_t)rg) << 7) + 64 + lane]);
    }
    float s = v0 + v1, q = v0 * v0 + v1 * v1;
    #pragma unroll
    for (int o = 32; o; o >>= 1){ s += __shfl_xor(s, o); q += __shfl_xor(q, o); }
    float mu  = s * (1.f / 128.f);
    float var = q * (1.f / 128.f) - mu * mu;
    float rs  = rsqrtf(var + 1e-5f);
    float y0 = (v0 - mu) * rs * gl0 + bt0;
    float y1 = (v1 - mu) * rs * gl1 + bt1;
    if (rg < n_rows){
      outp[(((size_t)rg) << 7) + lane]      = f2bf(y0);
      outp[(((size_t)rg) << 7) + 64 + lane] = f2bf(y1);
    }
  }
}

// out0 = elu(x @ oW + ob)
__global__ void outhead_kernel(const u16* __restrict__ x, const float* __restrict__ oW,
                               const float* __restrict__ ob, float* __restrict__ out){
  int row  = (blockIdx.x * blockDim.x + threadIdx.x) >> 6;
  int lane = threadIdx.x & 63;
  if (row >= NF) return;
  float x0 = bf2f(x[((size_t)row << 7) + lane]);
  float x1 = bf2f(x[((size_t)row << 7) + 64 + lane]);
  float s0 = x0 * oW[lane * 3 + 0] + x1 * oW[(64 + lane) * 3 + 0];
  float s1 = x0 * oW[lane * 3 + 1] + x1 * oW[(64 + lane) * 3 + 1];
  float s2 = x0 * oW[lane * 3 + 2] + x1 * oW[(64 + lane) * 3 + 2];
  #pragma unroll
  for (int o = 32; o; o >>= 1){
    s0 += __shfl_xor(s0, o); s1 += __shfl_xor(s1, o); s2 += __shfl_xor(s2, o);
  }
  if (lane == 0){
    out[row * 3 + 0] = eluf(s0 + ob[0]);
    out[row * 3 + 1] = eluf(s1 + ob[1]);
    out[row * 3 + 2] = eluf(s2 + ob[2]);
  }
}

__global__ void idxcopy_kernel(const int* __restrict__ ei, float* __restrict__ out){
  int i = blockIdx.x * blockDim.x + threadIdx.x;
  if (i < 2 * ECNT) out[i] = (float)ei[i];
}

extern "C" void kernel_launch(void* const* d_in, const int* in_sizes, int n_in,
                              void* d_out, int out_size, void* d_ws, size_t ws_size,
                              hipStream_t stream)
{
  const float* x_in  = (const float*)d_in[0];
  const float* ea_in = (const float*)d_in[1];
  const float* pos_c = (const float*)d_in[2];
  const float* pos_f = (const float*)d_in[3];
  const int*   ei    = (const int*)d_in[4];
  const int*   clus  = (const int*)d_in[5];
  const float* eW0 = (const float*)d_in[7];
  const float* eb0 = (const float*)d_in[8];
  const float* eW1 = (const float*)d_in[9];
  const float* eb1 = (const float*)d_in[10];
  const float* eg  = (const float*)d_in[11];
  const float* ebt = (const float*)d_in[12];
  const float* nW0 = (const float*)d_in[13];
  const float* nb0 = (const float*)d_in[14];
  const float* nW1 = (const float*)d_in[15];
  const float* nb1 = (const float*)d_in[16];
  const float* ng  = (const float*)d_in[17];
  const float* nbt = (const float*)d_in[18];
  const float* dW0 = (const float*)d_in[19];
  const float* db0 = (const float*)d_in[20];
  const float* dW1 = (const float*)d_in[21];
  const float* db1 = (const float*)d_in[22];
  const float* uW0 = (const float*)d_in[23];
  const float* ub0 = (const float*)d_in[24];
  const float* uW1 = (const float*)d_in[25];
  const float* ub1 = (const float*)d_in[26];
  const float* ug  = (const float*)d_in[27];
  const float* ubt = (const float*)d_in[28];
  const float* oW  = (const float*)d_in[29];
  const float* ob  = (const float*)d_in[30];

  char* w = (char*)d_ws;
  auto alloc = [&](size_t bytes) -> char* {
    char* p = w; w += (bytes + 255) & ~(size_t)255; return p;
  };
  u16*   ea_s   = (u16*)alloc((size_t)ECNT * HD * 2);
  u16*   xa     = (u16*)alloc((size_t)NC * HD * 2);
  u16*   xb     = (u16*)alloc((size_t)NF * HD * 2);
  u16*   P      = (u16*)alloc((size_t)NC * HD * 2);
  u16*   Q      = (u16*)alloc((size_t)NC * HD * 2);
  u16*   XU     = (u16*)alloc((size_t)NC * HD * 2);
  int*   deg    = (int*)alloc((size_t)NF * 4);
  int*   rowptr = (int*)alloc((size_t)(NF + 1) * 4);
  int*   cursor = (int*)alloc((size_t)NF * 4);
  int*   perm   = (int*)alloc((size_t)ECNT * 4);
  int*   esrc   = (int*)alloc((size_t)ECNT * 4);
  int*   edst   = (int*)alloc((size_t)ECNT * 4);
  int*   part   = (int*)alloc((size_t)SCB * 4);
  u16*   c_eW0  = (u16*)alloc((size_t)2 * 384 * HD * 2);
  u16*   c_eW1  = (u16*)alloc((size_t)2 * HD * HD * 2);
  u16*   c_nW0  = (u16*)alloc((size_t)2 * 256 * HD * 2);
  u16*   c_nW1  = (u16*)alloc((size_t)2 * HD * HD * 2);
  u16*   c_uW0  = (u16*)alloc((size_t)256 * HD * 2);
  u16*   c_uW1  = (u16*)alloc((size_t)HD * HD * 2);
  u16*   c_dW1  = (u16*)alloc((size_t)HD * HD * 2);

  prep_all_kernel<<<1152, 256, 0, stream>>>(eW0, eW1, nW0, nW1, uW0, uW1, dW1,
                                            c_eW0, c_eW1, c_nW0, c_nW1, c_uW0, c_uW1, c_dW1);
  f32_to_bf16_vec<<<(NC * HD / 8 + 255) / 256, 256, 0, stream>>>(x_in, xa, NC * HD / 8);

  hipMemsetAsync(deg, 0, (size_t)NF * 4, stream);
  deg_kernel<<<(ECNT + 255) / 256, 256, 0, stream>>>(ei, deg);
  scanA_kernel<<<NB_SCAN, SCB, 0, stream>>>(deg, part);
  scanB_kernel<<<1, SCB, 0, stream>>>(part);
  scanC_kernel<<<NB_SCAN, SCB, 0, stream>>>(deg, part, rowptr);
  hipMemcpyAsync(cursor, rowptr, (size_t)NF * 4, hipMemcpyDeviceToDevice, stream);
  build_perm_kernel<<<(ECNT + 255) / 256, 256, 0, stream>>>(ei, cursor, perm, esrc, edst);
  permute_ea_kernel<<<(ECNT * 16 + 255) / 256, 256, 0, stream>>>(ea_in, perm, ea_s);

  auto grd = [](int rows){ return (rows + 31) / 32; };   // non-persistent: grid == tiles
  const int KS = 16 * HD * 8;   // u16 offset of one 128-K slice in chunked layout

  auto mp_iter = [&](u16* x, int n, int i){
    int npq = n < NC ? n : NC;   // edge endpoints always < NC
    lin_kernel<2><<<grd(npq), 256, 0, stream>>>(
      c_eW0 + (size_t)i*384*HD, c_eW0 + (size_t)i*384*HD + KS, x, P, Q, npq);
    mlp_kernel<M_EDGE><<<grd(ECNT), 256, 0, stream>>>(
      c_eW0 + (size_t)i*384*HD + 2*KS, c_eW1 + (size_t)i*HD*HD, nullptr,
      eb0 + i*HD, eb1 + i*HD, nullptr, eg + i*HD, ebt + i*HD,
      ea_s, P, Q, nullptr, esrc, edst, nullptr, nullptr, nullptr,
      ea_s, ECNT, nullptr, nullptr, nullptr, nullptr);
    mlp_kernel<M_NODE><<<grd(n), 256, 0, stream>>>(
      c_nW0 + (size_t)i*256*HD, c_nW0 + (size_t)i*256*HD + KS, c_nW1 + (size_t)i*HD*HD,
      nb0 + i*HD, nb1 + i*HD, nullptr, ng + i*HD, nbt + i*HD,
      x, nullptr, nullptr, x, nullptr, nullptr, rowptr, ea_s, nullptr,
      x, n, nullptr, nullptr, nullptr, nullptr);
  };

  // ---- pass 1 on xa ----
  mp_iter(xa, NC, 0);
  mp_iter(xa, NC, 1);

  // ---- decoder (fused DEC1+DEC2; seg_mean over arange(NF) is identity) ----
  lin_kernel<1><<<grd(NC), 256, 0, stream>>>(
    c_uW0 + KS, nullptr, xa, XU, nullptr, NC);
  mlp_kernel<M_DEC12><<<grd(NF), 256, 0, stream>>>(
    c_dW1, c_uW0, c_uW1,
    db1, ub0, ub1, ug, ubt,
    nullptr, XU, nullptr, nullptr,
    nullptr, nullptr, nullptr, nullptr, clus,
    xb, NF, dW0, db0, pos_c, pos_f);

  // ---- pass 2 on xb ----
  mp_iter(xb, NF, 0);
  mp_iter(xb, NF, 1);

  float* out = (float*)d_out;
  outhead_kernel<<<(NF + 3) / 4, 256, 0, stream>>>(xb, oW, ob, out);
  idxcopy_kernel<<<(2 * ECNT + 255) / 256, 256, 0, stream>>>(ei, out + (size_t)NF * OUTD);
}

// Round 12
// 850.872 us; speedup vs baseline: 2.3055x; 1.0440x over previous
//
#include <hip/hip_runtime.h>

// Decoder_48378511622552 — CSR-sorted, bf16, K=128 MFMA fused GNN decoder (gfx950)
// Round 12: register-direct LN epilogue (no r->LDS round-trip, 64-shfl partial reduce),
// LIN fused into NODE/DEC12 epilogues (only first LIN standalone), coalesced permute_ea.

#define HD   128
#define NC   50000
#define NF   150000
#define ECNT 400000
#define OUTD 3
#define SCB  512
#define NB_SCAN ((NF + SCB - 1) / SCB)   // 293

typedef unsigned short u16;
typedef unsigned int   u32;
typedef short bf16x8 __attribute__((ext_vector_type(8)));
typedef float f32x4  __attribute__((ext_vector_type(4)));

__device__ __forceinline__ float bf2f(u32 u){ return __uint_as_float(u << 16); }
__device__ __forceinline__ u32 cvtpk(float a, float b){   // lo = bf16(a), hi = bf16(b)
  u32 r; asm("v_cvt_pk_bf16_f32 %0, %1, %2" : "=v"(r) : "v"(a), "v"(b)); return r;
}
__device__ __forceinline__ u16 f2bf(float f){ return (u16)cvtpk(f, f); }
__device__ __forceinline__ u32 addpk(u32 a, u32 b){
  return cvtpk(bf2f(a & 0xffffu) + bf2f(b & 0xffffu),
               __uint_as_float(a & 0xffff0000u) + __uint_as_float(b & 0xffff0000u));
}
__device__ __forceinline__ float eluf(float x){ return x > 0.f ? x : __expf(x) - 1.f; }
// swizzle for bf16 [32][256B] tiles
__device__ __forceinline__ int SW(int row, int byte){ return row * 256 + (byte ^ ((row & 7) << 4)); }

// ---------------- prep kernels ----------------

__global__ void prep_all_kernel(const float* __restrict__ eW0, const float* __restrict__ eW1,
                                const float* __restrict__ nW0, const float* __restrict__ nW1,
                                const float* __restrict__ uW0, const float* __restrict__ uW1,
                                const float* __restrict__ dW1,
                                u16* c_eW0, u16* c_eW1, u16* c_nW0, u16* c_nW1,
                                u16* c_uW0, u16* c_uW1, u16* c_dW1)
{
  int b = blockIdx.x;
  const float* src; u16* dst; int kb;
  if      (b <  384){ src = eW0; dst = c_eW0; kb = b * 2; }          // K=768 (2 mats)
  else if (b <  512){ src = eW1; dst = c_eW1; kb = (b - 384) * 2; }  // K=256
  else if (b <  768){ src = nW0; dst = c_nW0; kb = (b - 512) * 2; }  // K=512
  else if (b <  896){ src = nW1; dst = c_nW1; kb = (b - 768) * 2; }  // K=256
  else if (b < 1024){ src = uW0; dst = c_uW0; kb = (b - 896) * 2; }  // K=256
  else if (b < 1088){ src = uW1; dst = c_uW1; kb = (b - 1024) * 2; } // K=128
  else              { src = dW1; dst = c_dW1; kb = (b - 1088) * 2; } // K=128
  int t = threadIdx.x;
  int k = kb + (t >> 7), j = t & 127;
  dst[(((k >> 3) * HD + j) << 3) + (k & 7)] = f2bf(src[k * HD + j]);
}

__global__ void f32_to_bf16_vec(const float* __restrict__ in, u16* __restrict__ out, int n8){
  int i = blockIdx.x * blockDim.x + threadIdx.x;
  if (i >= n8) return;
  float4 f0 = ((const float4*)in)[i * 2];
  float4 f1 = ((const float4*)in)[i * 2 + 1];
  ((uint4*)out)[i] = make_uint4(cvtpk(f0.x,f0.y), cvtpk(f0.z,f0.w), cvtpk(f1.x,f1.y), cvtpk(f1.z,f1.w));
}

__global__ void deg_kernel(const int* __restrict__ ei, int* __restrict__ deg){
  int e = blockIdx.x * blockDim.x + threadIdx.x;
  if (e < ECNT) atomicAdd(&deg[ei[ECNT + e]], 1);
}

__global__ void scanA_kernel(const int* __restrict__ deg, int* __restrict__ part){
  __shared__ int s[SCB];
  int t = threadIdx.x, i = blockIdx.x * SCB + t;
  s[t] = (i < NF) ? deg[i] : 0;
  __syncthreads();
  for (int off = SCB/2; off; off >>= 1){ if (t < off) s[t] += s[t + off]; __syncthreads(); }
  if (t == 0) part[blockIdx.x] = s[0];
}

__global__ void scanB_kernel(int* __restrict__ part){
  __shared__ int s[SCB];
  int t = threadIdx.x;
  int v = (t < NB_SCAN) ? part[t] : 0;
  s[t] = v; __syncthreads();
  for (int off = 1; off < SCB; off <<= 1){
    int x = (t >= off) ? s[t - off] : 0;
    __syncthreads(); s[t] += x; __syncthreads();
  }
  if (t < NB_SCAN) part[t] = s[t] - v;   // exclusive
}

__global__ void scanC_kernel(const int* __restrict__ deg, const int* __restrict__ part,
                             int* __restrict__ rowptr){
  __shared__ int s[SCB];
  int t = threadIdx.x, i = blockIdx.x * SCB + t;
  int v = (i < NF) ? deg[i] : 0;
  s[t] = v; __syncthreads();
  for (int off = 1; off < SCB; off <<= 1){
    int x = (t >= off) ? s[t - off] : 0;
    __syncthreads(); s[t] += x; __syncthreads();
  }
  int excl = part[blockIdx.x] + s[t] - v;
  if (i < NF) rowptr[i] = excl;
  if (i == NF - 1) rowptr[NF] = excl + v;
}

__global__ void build_perm_kernel(const int* __restrict__ ei, int* __restrict__ cursor,
                                  int* __restrict__ perm, int* __restrict__ esrc,
                                  int* __restrict__ edst){
  int e = blockIdx.x * blockDim.x + threadIdx.x;
  if (e >= ECNT) return;
  int sI = ei[e], d = ei[ECNT + e];
  int p = atomicAdd(&cursor[d], 1);
  perm[p] = e; esrc[p] = sI; edst[p] = d;
}

// wave-per-row: 512B contiguous f32 read, 256B bf16 write
__global__ void permute_ea_kernel(const float* __restrict__ ea_in, const int* __restrict__ perm,
                                  u16* __restrict__ ea_s){
  int p = (blockIdx.x << 2) + (threadIdx.x >> 6);
  int lane = threadIdx.x & 63;
  if (p >= ECNT) return;
  int e = perm[p];
  float2 f = *(const float2*)(ea_in + (((size_t)e) << 7) + (lane << 1));
  *(u32*)(ea_s + (((size_t)p) << 7) + (lane << 1)) = cvtpk(f.x, f.y);
}

// ---------------- standalone LIN2: oA = x@Wa, oB = x@Wb ----------------
__global__ __launch_bounds__(256, 4)
void lin2_kernel(const u16* __restrict__ Wa, const u16* __restrict__ Wb,
                 const u16* __restrict__ x, u16* __restrict__ oA, u16* __restrict__ oB,
                 int n_rows)
{
  __shared__ __align__(16) char ldsA[32 * 256];
  const int tid = threadIdx.x, lane = tid & 63, wid = tid >> 6;
  const int ln = lane & 15, kq = lane >> 4, ncol = wid * 32;

  const int row0 = blockIdx.x << 5;
  #pragma unroll
  for (int c = 0; c < 2; ++c){
    int i = tid + c * 256, row = i >> 4, kk = i & 15, rg = row0 + row;
    if (rg < n_rows)
      *(uint4*)(ldsA + SW(row, kk * 16)) = *(const uint4*)(x + (((size_t)rg) << 7) + (kk << 3));
  }
  __syncthreads();
  bf16x8 af[4][2];
  #pragma unroll
  for (int k0 = 0; k0 < 4; ++k0){
    af[k0][0] = *(const bf16x8*)(ldsA + SW(ln,      k0 * 64 + (kq << 4)));
    af[k0][1] = *(const bf16x8*)(ldsA + SW(16 + ln, k0 * 64 + (kq << 4)));
  }
  const u16* Ws[2] = {Wa, Wb};
  u16*       Os[2] = {oA, oB};
  const f32x4 zz = {0.f, 0.f, 0.f, 0.f};
  #pragma unroll
  for (int w = 0; w < 2; ++w){
    const u16* wp = Ws[w];
    asm volatile("" : "+v"(wp));
    uint4 bfr[4][2];
    #pragma unroll
    for (int k0 = 0; k0 < 4; ++k0)
      #pragma unroll
      for (int nt = 0; nt < 2; ++nt)
        bfr[k0][nt] = *(const uint4*)(wp + (((size_t)((k0*4 + kq)*HD + ncol + nt*16 + ln)) << 3));
    f32x4 cc[2][2] = {{zz, zz}, {zz, zz}};
    #pragma unroll
    for (int k0 = 0; k0 < 4; ++k0){
      bf16x8 w0 = __builtin_bit_cast(bf16x8, bfr[k0][0]);
      bf16x8 w1 = __builtin_bit_cast(bf16x8, bfr[k0][1]);
      cc[0][0] = __builtin_amdgcn_mfma_f32_16x16x32_bf16(af[k0][0], w0, cc[0][0], 0, 0, 0);
      cc[0][1] = __builtin_amdgcn_mfma_f32_16x16x32_bf16(af[k0][0], w1, cc[0][1], 0, 0, 0);
      cc[1][0] = __builtin_amdgcn_mfma_f32_16x16x32_bf16(af[k0][1], w0, cc[1][0], 0, 0, 0);
      cc[1][1] = __builtin_amdgcn_mfma_f32_16x16x32_bf16(af[k0][1], w1, cc[1][1], 0, 0, 0);
    }
    u16* op = Os[w];
    #pragma unroll
    for (int mi = 0; mi < 2; ++mi)
      #pragma unroll
      for (int nt = 0; nt < 2; ++nt)
        #pragma unroll
        for (int r = 0; r < 4; ++r){
          int rg = row0 + mi * 16 + kq * 4 + r;
          if (rg < n_rows) op[(size_t)rg * HD + ncol + nt * 16 + ln] = f2bf(cc[mi][nt][r]);
        }
  }
}

// ---------------- unified fused K=128 MFMA MLP ----------------
enum { M_EDGE = 0, M_NODE = 1, M_DEC12 = 2 };

// EDGE : A=ea; h=elu(A@W0 + P[src]+Q[dst] + b0); cf=h@W1;      out = LN(cf+b1 + A)
// NODE : cf1=x@W0 (+ act: CSR-mean(ea)@W1); h=elu(cf1+b0); cf=h@W2; out = LN(cf+b1 + x)
// DEC12: h1=elu(delta@dW0+db0); eac=elu(h1@W0+b0); h=elu(eac@W1 + XU[clus] + b1);
//        cf=h@W2;                                              out = LN(elu(cf+b2) + eac)
// FUSE>0: after LN store, compute oF[w] = out_tile @ Wf[w] for blocks row0 < fuse_n.
template<int MODE, int FUSE>
__global__ __launch_bounds__(256, 4)
void mlp_kernel(const u16* __restrict__ W0c, const u16* __restrict__ W1c,
                const u16* __restrict__ W2c,
                const float* __restrict__ b0, const float* __restrict__ b1,
                const float* __restrict__ b2,
                const float* __restrict__ gw, const float* __restrict__ bw,
                const u16* __restrict__ tabA, const u16* __restrict__ addP,
                const u16* __restrict__ addQ,
                const int* __restrict__ esrc, const int* __restrict__ edst,
                const int* __restrict__ rowptr, const u16* __restrict__ eatab,
                const int* __restrict__ clus,
                u16* __restrict__ outp, int n_rows,
                const float* __restrict__ dW0, const float* __restrict__ db0,
                const float* __restrict__ pos_c, const float* __restrict__ pos_f,
                const u16* __restrict__ Wf0, const u16* __restrict__ Wf1,
                u16* __restrict__ oF0, u16* __restrict__ oF1, int fuse_n)
{
  constexpr bool ELU2 = (MODE == M_DEC12);

  __shared__ __align__(16) char  ldsA [32 * 256];   // A/x/eac tile (residual source)
  __shared__ __align__(16) char  ldsPQ[32 * 256];   // addend/mean -> h
  __shared__ float ldsSQ[32 * 8];                   // per-row wave partials {s,q} x4
  __shared__ float ldsM [32 * 2];                   // per-row {mu, rs}

  const int tid  = threadIdx.x;
  const int lane = tid & 63;
  const int wid  = tid >> 6;
  const int ln   = lane & 15, kq = lane >> 4;
  const int ncol = wid * 32;

  bf16x8 b1f[4][2];
  #pragma unroll
  for (int k0 = 0; k0 < 4; ++k0)
    #pragma unroll
    for (int nt = 0; nt < 2; ++nt)
      b1f[k0][nt] = *(const bf16x8*)(W0c + (((size_t)((k0*4 + kq)*HD + ncol + nt*16 + ln)) << 3));

  float b0v[2], b1v[2], bfin[2], gv[2], btv[2];
  #pragma unroll
  for (int nt = 0; nt < 2; ++nt){
    int col = ncol + nt*16 + ln;
    b0v[nt] = b0[col]; b1v[nt] = b1[col];
    bfin[nt] = (MODE == M_DEC12) ? b2[col] : b1v[nt];
    gv[nt] = gw[col]; btv[nt] = bw[col];
  }

  const int row0 = blockIdx.x << 5;
  const f32x4 zz = {0.f, 0.f, 0.f, 0.f};
  f32x4 cf[2][2];

  if constexpr (MODE == M_EDGE){
    // ---- stage: ea -> ldsA, P[src]+Q[dst] -> ldsPQ ----
    #pragma unroll
    for (int c = 0; c < 2; ++c){
      int i = tid + c * 256, row = i >> 4, kk = i & 15, rg = row0 + row;   // ECNT%32==0
      *(uint4*)(ldsA + SW(row, kk * 16)) =
          *(const uint4*)(tabA + (((size_t)rg) << 7) + (kk << 3));
      int sI = esrc[rg], dI = edst[rg];
      uint4 p = *(const uint4*)(addP + (((size_t)sI) << 7) + (kk << 3));
      uint4 q = *(const uint4*)(addQ + (((size_t)dI) << 7) + (kk << 3));
      *(uint4*)(ldsPQ + SW(row, kk * 16)) =
          make_uint4(addpk(p.x,q.x), addpk(p.y,q.y), addpk(p.z,q.z), addpk(p.w,q.w));
    }
    __syncthreads();   // A
    // GEMM1
    cf[0][0]=zz; cf[0][1]=zz; cf[1][0]=zz; cf[1][1]=zz;
    #pragma unroll
    for (int k0 = 0; k0 < 4; ++k0){
      bf16x8 a0 = *(const bf16x8*)(ldsA + SW(ln,      k0 * 64 + (kq << 4)));
      bf16x8 a1 = *(const bf16x8*)(ldsA + SW(16 + ln, k0 * 64 + (kq << 4)));
      cf[0][0] = __builtin_amdgcn_mfma_f32_16x16x32_bf16(a0, b1f[k0][0], cf[0][0], 0, 0, 0);
      cf[0][1] = __builtin_amdgcn_mfma_f32_16x16x32_bf16(a0, b1f[k0][1], cf[0][1], 0, 0, 0);
      cf[1][0] = __builtin_amdgcn_mfma_f32_16x16x32_bf16(a1, b1f[k0][0], cf[1][0], 0, 0, 0);
      cf[1][1] = __builtin_amdgcn_mfma_f32_16x16x32_bf16(a1, b1f[k0][1], cf[1][1], 0, 0, 0);
    }
    // h = elu(cf + pq + b0) -> ldsPQ in place (same-thread RMW at C positions)
    #pragma unroll
    for (int mi = 0; mi < 2; ++mi)
      #pragma unroll
      for (int nt = 0; nt < 2; ++nt)
        #pragma unroll
        for (int r = 0; r < 4; ++r){
          int row = mi * 16 + kq * 4 + r, col = ncol + nt * 16 + ln;
          u16* pp = (u16*)(ldsPQ + SW(row, col * 2));
          *pp = f2bf(eluf(cf[mi][nt][r] + bf2f(*pp) + b0v[nt]));
        }
    __syncthreads();   // B
    // GEMM2
    {
      const u16* w1p = W1c;
      asm volatile("" : "+v"(w1p));
      uint4 b2r[4][2];
      #pragma unroll
      for (int k0 = 0; k0 < 4; ++k0)
        #pragma unroll
        for (int nt = 0; nt < 2; ++nt)
          b2r[k0][nt] = *(const uint4*)(w1p + (((size_t)((k0*4 + kq)*HD + ncol + nt*16 + ln)) << 3));
      cf[0][0]=zz; cf[0][1]=zz; cf[1][0]=zz; cf[1][1]=zz;
      #pragma unroll
      for (int k0 = 0; k0 < 4; ++k0){
        bf16x8 a0 = *(const bf16x8*)(ldsPQ + SW(ln,      k0 * 64 + (kq << 4)));
        bf16x8 a1 = *(const bf16x8*)(ldsPQ + SW(16 + ln, k0 * 64 + (kq << 4)));
        bf16x8 w0 = __builtin_bit_cast(bf16x8, b2r[k0][0]);
        bf16x8 w1 = __builtin_bit_cast(bf16x8, b2r[k0][1]);
        cf[0][0] = __builtin_amdgcn_mfma_f32_16x16x32_bf16(a0, w0, cf[0][0], 0, 0, 0);
        cf[0][1] = __builtin_amdgcn_mfma_f32_16x16x32_bf16(a0, w1, cf[0][1], 0, 0, 0);
        cf[1][0] = __builtin_amdgcn_mfma_f32_16x16x32_bf16(a1, w0, cf[1][0], 0, 0, 0);
        cf[1][1] = __builtin_amdgcn_mfma_f32_16x16x32_bf16(a1, w1, cf[1][1], 0, 0, 0);
      }
    }
  } else if constexpr (MODE == M_NODE){
    // ---- stage: x -> ldsA ; act: CSR mean -> ldsPQ ----
    #pragma unroll
    for (int c = 0; c < 2; ++c){
      int i = tid + c * 256, row = i >> 4, kk = i & 15, rg = row0 + row;
      if (rg < n_rows)
        *(uint4*)(ldsA + SW(row, kk * 16)) =
            *(const uint4*)(tabA + (((size_t)rg) << 7) + (kk << 3));
    }
    const bool act = (row0 < NC);   // rows >= NC have degree 0 (block-uniform)
    if (act){
      for (int s = 0; s < 8; ++s){
        int nd = wid * 8 + s, rg = row0 + nd;
        if (rg < n_rows){
          int rp0 = rowptr[rg], rp1 = rowptr[rg + 1];
          float s0 = 0.f, s1 = 0.f, t0 = 0.f, t1 = 0.f;
          int i2 = rp0;
          for (; i2 + 3 < rp1; i2 += 4){
            u32 ua = *(const u32*)(eatab + (((size_t) i2     ) << 7) + (lane << 1));
            u32 ub = *(const u32*)(eatab + (((size_t)(i2 + 1)) << 7) + (lane << 1));
            u32 uc = *(const u32*)(eatab + (((size_t)(i2 + 2)) << 7) + (lane << 1));
            u32 ud = *(const u32*)(eatab + (((size_t)(i2 + 3)) << 7) + (lane << 1));
            s0 += bf2f(ua & 0xffffu) + bf2f(ub & 0xffffu);
            s1 += bf2f(ua >> 16)     + bf2f(ub >> 16);
            t0 += bf2f(uc & 0xffffu) + bf2f(ud & 0xffffu);
            t1 += bf2f(uc >> 16)     + bf2f(ud >> 16);
          }
          for (; i2 < rp1; ++i2){
            u32 ua = *(const u32*)(eatab + (((size_t)i2) << 7) + (lane << 1));
            s0 += bf2f(ua & 0xffffu); s1 += bf2f(ua >> 16);
          }
          s0 += t0; s1 += t1;
          int dg = rp1 - rp0;
          float rd = 1.f / (float)(dg > 0 ? dg : 1);
          *(u32*)(ldsPQ + SW(nd, lane << 2)) = cvtpk(s0 * rd, s1 * rd);
        }
      }
    }
    __syncthreads();   // A
    // GEMM1: cf = x @ nW0a
    cf[0][0]=zz; cf[0][1]=zz; cf[1][0]=zz; cf[1][1]=zz;
    #pragma unroll
    for (int k0 = 0; k0 < 4; ++k0){
      bf16x8 a0 = *(const bf16x8*)(ldsA + SW(ln,      k0 * 64 + (kq << 4)));
      bf16x8 a1 = *(const bf16x8*)(ldsA + SW(16 + ln, k0 * 64 + (kq << 4)));
      cf[0][0] = __builtin_amdgcn_mfma_f32_16x16x32_bf16(a0, b1f[k0][0], cf[0][0], 0, 0, 0);
      cf[0][1] = __builtin_amdgcn_mfma_f32_16x16x32_bf16(a0, b1f[k0][1], cf[0][1], 0, 0, 0);
      cf[1][0] = __builtin_amdgcn_mfma_f32_16x16x32_bf16(a1, b1f[k0][0], cf[1][0], 0, 0, 0);
      cf[1][1] = __builtin_amdgcn_mfma_f32_16x16x32_bf16(a1, b1f[k0][1], cf[1][1], 0, 0, 0);
    }
    if (act){
      // cf += mean @ nW0b
      const u16* wbp = W1c;
      asm volatile("" : "+v"(wbp));
      uint4 bbr[4][2];
      #pragma unroll
      for (int k0 = 0; k0 < 4; ++k0)
        #pragma unroll
        for (int nt = 0; nt < 2; ++nt)
          bbr[k0][nt] = *(const uint4*)(wbp + (((size_t)((k0*4 + kq)*HD + ncol + nt*16 + ln)) << 3));
      #pragma unroll
      for (int k0 = 0; k0 < 4; ++k0){
        bf16x8 a0 = *(const bf16x8*)(ldsPQ + SW(ln,      k0 * 64 + (kq << 4)));
        bf16x8 a1 = *(const bf16x8*)(ldsPQ + SW(16 + ln, k0 * 64 + (kq << 4)));
        bf16x8 w0 = __builtin_bit_cast(bf16x8, bbr[k0][0]);
        bf16x8 w1 = __builtin_bit_cast(bf16x8, bbr[k0][1]);
        cf[0][0] = __builtin_amdgcn_mfma_f32_16x16x32_bf16(a0, w0, cf[0][0], 0, 0, 0);
        cf[0][1] = __builtin_amdgcn_mfma_f32_16x16x32_bf16(a0, w1, cf[0][1], 0, 0, 0);
        cf[1][0] = __builtin_amdgcn_mfma_f32_16x16x32_bf16(a1, w0, cf[1][0], 0, 0, 0);
        cf[1][1] = __builtin_amdgcn_mfma_f32_16x16x32_bf16(a1, w1, cf[1][1], 0, 0, 0);
      }
    }
    __syncthreads();   // B: mean reads done
    // h = elu(cf + b0) -> ldsPQ (C positions)
    #pragma unroll
    for (int mi = 0; mi < 2; ++mi)
      #pragma unroll
      for (int nt = 0; nt < 2; ++nt)
        #pragma unroll
        for (int r = 0; r < 4; ++r){
          int row = mi * 16 + kq * 4 + r, col = ncol + nt * 16 + ln;
          *(u16*)(ldsPQ + SW(row, col * 2)) = f2bf(eluf(cf[mi][nt][r] + b0v[nt]));
        }
    __syncthreads();   // C
    // GEMM2: cf = h @ nW1
    {
      const u16* w2p = W2c;
      asm volatile("" : "+v"(w2p));
      uint4 b3r[4][2];
      #pragma unroll
      for (int k0 = 0; k0 < 4; ++k0)
        #pragma unroll
        for (int nt = 0; nt < 2; ++nt)
          b3r[k0][nt] = *(const uint4*)(w2p + (((size_t)((k0*4 + kq)*HD + ncol + nt*16 + ln)) << 3));
      cf[0][0]=zz; cf[0][1]=zz; cf[1][0]=zz; cf[1][1]=zz;
      #pragma unroll
      for (int k0 = 0; k0 < 4; ++k0){
        bf16x8 a0 = *(const bf16x8*)(ldsPQ + SW(ln,      k0 * 64 + (kq << 4)));
        bf16x8 a1 = *(const bf16x8*)(ldsPQ + SW(16 + ln, k0 * 64 + (kq << 4)));
        bf16x8 w0 = __builtin_bit_cast(bf16x8, b3r[k0][0]);
        bf16x8 w1 = __builtin_bit_cast(bf16x8, b3r[k0][1]);
        cf[0][0] = __builtin_amdgcn_mfma_f32_16x16x32_bf16(a0, w0, cf[0][0], 0, 0, 0);
        cf[0][1] = __builtin_amdgcn_mfma_f32_16x16x32_bf16(a0, w1, cf[0][1], 0, 0, 0);
        cf[1][0] = __builtin_amdgcn_mfma_f32_16x16x32_bf16(a1, w0, cf[1][0], 0, 0, 0);
        cf[1][1] = __builtin_amdgcn_mfma_f32_16x16x32_bf16(a1, w1, cf[1][1], 0, 0, 0);
      }
    }
  } else { // M_DEC12
    // ---- stage: h1 = elu(delta@dW0+db0) -> ldsA ; XU[clus] -> ldsPQ ----
    #pragma unroll
    for (int c = 0; c < 2; ++c){
      int i = tid + c * 256, row = i >> 4, c8 = i & 15, rg = row0 + row;
      if (rg < n_rows){
        int cl = clus[rg];
        *(uint4*)(ldsPQ + SW(row, c8 * 16)) =
            *(const uint4*)(addP + (((size_t)cl) << 7) + (c8 << 3));
        float d0 = pos_c[cl * 2]     - pos_f[rg * 2];
        float d1 = pos_c[cl * 2 + 1] - pos_f[rg * 2 + 1];
        u32 wq[4];
        #pragma unroll
        for (int q = 0; q < 4; ++q){
          int cc = c8 * 8 + q * 2;
          float va = eluf(fmaf(d0, dW0[cc],     fmaf(d1, dW0[HD + cc],     db0[cc])));
          float vb = eluf(fmaf(d0, dW0[cc + 1], fmaf(d1, dW0[HD + cc + 1], db0[cc + 1])));
          wq[q] = cvtpk(va, vb);
        }
        *(uint4*)(ldsA + SW(row, c8 * 16)) = make_uint4(wq[0], wq[1], wq[2], wq[3]);
      }
    }
    __syncthreads();   // A
    // GEMM1: cf = h1 @ dW1
    cf[0][0]=zz; cf[0][1]=zz; cf[1][0]=zz; cf[1][1]=zz;
    #pragma unroll
    for (int k0 = 0; k0 < 4; ++k0){
      bf16x8 a0 = *(const bf16x8*)(ldsA + SW(ln,      k0 * 64 + (kq << 4)));
      bf16x8 a1 = *(const bf16x8*)(ldsA + SW(16 + ln, k0 * 64 + (kq << 4)));
      cf[0][0] = __builtin_amdgcn_mfma_f32_16x16x32_bf16(a0, b1f[k0][0], cf[0][0], 0, 0, 0);
      cf[0][1] = __builtin_amdgcn_mfma_f32_16x16x32_bf16(a0, b1f[k0][1], cf[0][1], 0, 0, 0);
      cf[1][0] = __builtin_amdgcn_mfma_f32_16x16x32_bf16(a1, b1f[k0][0], cf[1][0], 0, 0, 0);
      cf[1][1] = __builtin_amdgcn_mfma_f32_16x16x32_bf16(a1, b1f[k0][1], cf[1][1], 0, 0, 0);
    }
    __syncthreads();   // B: h1 reads done
    // eac = elu(cf + b0) -> ldsA (C positions)
    #pragma unroll
    for (int mi = 0; mi < 2; ++mi)
      #pragma unroll
      for (int nt = 0; nt < 2; ++nt)
        #pragma unroll
        for (int r = 0; r < 4; ++r){
          int row = mi * 16 + kq * 4 + r, col = ncol + nt * 16 + ln;
          *(u16*)(ldsA + SW(row, col * 2)) = f2bf(eluf(cf[mi][nt][r] + b0v[nt]));
        }
    __syncthreads();   // C: eac visible
    // GEMM2: cf = eac @ uW0a ; h = elu(cf + XU + b1) -> ldsPQ in place
    {
      const u16* w1p = W1c;
      asm volatile("" : "+v"(w1p));
      uint4 b2r[4][2];
      #pragma unroll
      for (int k0 = 0; k0 < 4; ++k0)
        #pragma unroll
        for (int nt = 0; nt < 2; ++nt)
          b2r[k0][nt] = *(const uint4*)(w1p + (((size_t)((k0*4 + kq)*HD + ncol + nt*16 + ln)) << 3));
      cf[0][0]=zz; cf[0][1]=zz; cf[1][0]=zz; cf[1][1]=zz;
      #pragma unroll
      for (int k0 = 0; k0 < 4; ++k0){
        bf16x8 a0 = *(const bf16x8*)(ldsA + SW(ln,      k0 * 64 + (kq << 4)));
        bf16x8 a1 = *(const bf16x8*)(ldsA + SW(16 + ln, k0 * 64 + (kq << 4)));
        bf16x8 w0 = __builtin_bit_cast(bf16x8, b2r[k0][0]);
        bf16x8 w1 = __builtin_bit_cast(bf16x8, b2r[k0][1]);
        cf[0][0] = __builtin_amdgcn_mfma_f32_16x16x32_bf16(a0, w0, cf[0][0], 0, 0, 0);
        cf[0][1] = __builtin_amdgcn_mfma_f32_16x16x32_bf16(a0, w1, cf[0][1], 0, 0, 0);
        cf[1][0] = __builtin_amdgcn_mfma_f32_16x16x32_bf16(a1, w0, cf[1][0], 0, 0, 0);
        cf[1][1] = __builtin_amdgcn_mfma_f32_16x16x32_bf16(a1, w1, cf[1][1], 0, 0, 0);
      }
      #pragma unroll
      for (int mi = 0; mi < 2; ++mi)
        #pragma unroll
        for (int nt = 0; nt < 2; ++nt)
          #pragma unroll
          for (int r = 0; r < 4; ++r){
            int row = mi * 16 + kq * 4 + r, col = ncol + nt * 16 + ln;
            u16* pp = (u16*)(ldsPQ + SW(row, col * 2));
            *pp = f2bf(eluf(cf[mi][nt][r] + bf2f(*pp) + b1v[nt]));
          }
    }
    __syncthreads();   // D
    // GEMM3: cf = h @ uW1
    {
      const u16* w2p = W2c;
      asm volatile("" : "+v"(w2p));
      uint4 b3r[4][2];
      #pragma unroll
      for (int k0 = 0; k0 < 4; ++k0)
        #pragma unroll
        for (int nt = 0; nt < 2; ++nt)
          b3r[k0][nt] = *(const uint4*)(w2p + (((size_t)((k0*4 + kq)*HD + ncol + nt*16 + ln)) << 3));
      cf[0][0]=zz; cf[0][1]=zz; cf[1][0]=zz; cf[1][1]=zz;
      #pragma unroll
      for (int k0 = 0; k0 < 4; ++k0){
        bf16x8 a0 = *(const bf16x8*)(ldsPQ + SW(ln,      k0 * 64 + (kq << 4)));
        bf16x8 a1 = *(const bf16x8*)(ldsPQ + SW(16 + ln, k0 * 64 + (kq << 4)));
        bf16x8 w0 = __builtin_bit_cast(bf16x8, b3r[k0][0]);
        bf16x8 w1 = __builtin_bit_cast(bf16x8, b3r[k0][1]);
        cf[0][0] = __builtin_amdgcn_mfma_f32_16x16x32_bf16(a0, w0, cf[0][0], 0, 0, 0);
        cf[0][1] = __builtin_amdgcn_mfma_f32_16x16x32_bf16(a0, w1, cf[0][1], 0, 0, 0);
        cf[1][0] = __builtin_amdgcn_mfma_f32_16x16x32_bf16(a1, w0, cf[1][0], 0, 0, 0);
        cf[1][1] = __builtin_amdgcn_mfma_f32_16x16x32_bf16(a1, w1, cf[1][1], 0, 0, 0);
      }
    }
  }

  // ================= shared register-direct LN epilogue =================
  // rv = (ELU2 ? elu(cf + bfin) : cf + bfin) + resid(ldsA)
  #pragma unroll
  for (int mi = 0; mi < 2; ++mi)
    #pragma unroll
    for (int nt = 0; nt < 2; ++nt)
      #pragma unroll
      for (int r = 0; r < 4; ++r){
        int row = mi * 16 + kq * 4 + r, col = ncol + nt * 16 + ln;
        float v = cf[mi][nt][r] + bfin[nt];
        if constexpr (ELU2) v = eluf(v);
        v += bf2f(*(const u16*)(ldsA + SW(row, col * 2)));
        cf[mi][nt][r] = v;
      }
  // per-row partials + 16-lane xor reduce
  float sp[8], qp[8];
  #pragma unroll
  for (int mi = 0; mi < 2; ++mi)
    #pragma unroll
    for (int r = 0; r < 4; ++r){
      int ri = mi * 4 + r;
      float a = cf[mi][0][r], b = cf[mi][1][r];
      sp[ri] = a + b; qp[ri] = a * a + b * b;
    }
  #pragma unroll
  for (int off = 1; off < 16; off <<= 1)
    #pragma unroll
    for (int ri = 0; ri < 8; ++ri){
      sp[ri] += __shfl_xor(sp[ri], off);
      qp[ri] += __shfl_xor(qp[ri], off);
    }
  if (ln == 0){
    #pragma unroll
    for (int mi = 0; mi < 2; ++mi)
      #pragma unroll
      for (int r = 0; r < 4; ++r){
        int row = mi * 16 + kq * 4 + r;
        ldsSQ[row * 8 + wid * 2]     = sp[mi * 4 + r];
        ldsSQ[row * 8 + wid * 2 + 1] = qp[mi * 4 + r];
      }
  }
  __syncthreads();
  if (tid < 32){
    float s = ldsSQ[tid*8+0] + ldsSQ[tid*8+2] + ldsSQ[tid*8+4] + ldsSQ[tid*8+6];
    float q = ldsSQ[tid*8+1] + ldsSQ[tid*8+3] + ldsSQ[tid*8+5] + ldsSQ[tid*8+7];
    float mu  = s * (1.f / 128.f);
    float var = q * (1.f / 128.f) - mu * mu;
    ldsM[tid * 2]     = mu;
    ldsM[tid * 2 + 1] = rsqrtf(var + 1e-5f);
  }
  __syncthreads();
  // normalize + store (+ stash y into ldsA for fusion)
  #pragma unroll
  for (int mi = 0; mi < 2; ++mi)
    #pragma unroll
    for (int r = 0; r < 4; ++r){
      int row = mi * 16 + kq * 4 + r, rg = row0 + row;
      float mu = ldsM[row * 2], rs = ldsM[row * 2 + 1];
      #pragma unroll
      for (int nt = 0; nt < 2; ++nt){
        int col = ncol + nt * 16 + ln;
        float y = (cf[mi][nt][r] - mu) * rs * gv[nt] + btv[nt];
        u16 yb = f2bf(y);
        if (MODE == M_EDGE || rg < n_rows)
          outp[(((size_t)rg) << 7) + col] = yb;
        if constexpr (FUSE > 0)
          *(u16*)(ldsA + SW(row, col * 2)) = yb;
      }
    }

  // ================= fused next-LIN GEMMs =================
  if constexpr (FUSE > 0){
    __syncthreads();
    if (row0 < fuse_n){   // block-uniform
      bf16x8 af[4][2];
      #pragma unroll
      for (int k0 = 0; k0 < 4; ++k0){
        af[k0][0] = *(const bf16x8*)(ldsA + SW(ln,      k0 * 64 + (kq << 4)));
        af[k0][1] = *(const bf16x8*)(ldsA + SW(16 + ln, k0 * 64 + (kq << 4)));
      }
      const u16* Ws[2] = {Wf0, Wf1};
      u16*       Os[2] = {oF0, oF1};
      #pragma unroll
      for (int w = 0; w < FUSE; ++w){
        const u16* wp = Ws[w];
        asm volatile("" : "+v"(wp));
        uint4 bfr[4][2];
        #pragma unroll
        for (int k0 = 0; k0 < 4; ++k0)
          #pragma unroll
          for (int nt = 0; nt < 2; ++nt)
            bfr[k0][nt] = *(const uint4*)(wp + (((size_t)((k0*4 + kq)*HD + ncol + nt*16 + ln)) << 3));
        f32x4 cc[2][2] = {{zz, zz}, {zz, zz}};
        #pragma unroll
        for (int k0 = 0; k0 < 4; ++k0){
          bf16x8 w0 = __builtin_bit_cast(bf16x8, bfr[k0][0]);
          bf16x8 w1 = __builtin_bit_cast(bf16x8, bfr[k0][1]);
          cc[0][0] = __builtin_amdgcn_mfma_f32_16x16x32_bf16(af[k0][0], w0, cc[0][0], 0, 0, 0);
          cc[0][1] = __builtin_amdgcn_mfma_f32_16x16x32_bf16(af[k0][0], w1, cc[0][1], 0, 0, 0);
          cc[1][0] = __builtin_amdgcn_mfma_f32_16x16x32_bf16(af[k0][1], w0, cc[1][0], 0, 0, 0);
          cc[1][1] = __builtin_amdgcn_mfma_f32_16x16x32_bf16(af[k0][1], w1, cc[1][1], 0, 0, 0);
        }
        u16* op = Os[w];
        #pragma unroll
        for (int mi = 0; mi < 2; ++mi)
          #pragma unroll
          for (int nt = 0; nt < 2; ++nt)
            #pragma unroll
            for (int r = 0; r < 4; ++r){
              int rg = row0 + mi * 16 + kq * 4 + r;
              if (rg < fuse_n)
                op[(size_t)rg * HD + ncol + nt * 16 + ln] = f2bf(cc[mi][nt][r]);
            }
      }
    }
  }
}

// out0 = elu(x @ oW + ob)
__global__ void outhead_kernel(const u16* __restrict__ x, const float* __restrict__ oW,
                               const float* __restrict__ ob, float* __restrict__ out){
  int row  = (blockIdx.x * blockDim.x + threadIdx.x) >> 6;
  int lane = threadIdx.x & 63;
  if (row >= NF) return;
  float x0 = bf2f(x[((size_t)row << 7) + lane]);
  float x1 = bf2f(x[((size_t)row << 7) + 64 + lane]);
  float s0 = x0 * oW[lane * 3 + 0] + x1 * oW[(64 + lane) * 3 + 0];
  float s1 = x0 * oW[lane * 3 + 1] + x1 * oW[(64 + lane) * 3 + 1];
  float s2 = x0 * oW[lane * 3 + 2] + x1 * oW[(64 + lane) * 3 + 2];
  #pragma unroll
  for (int o = 32; o; o >>= 1){
    s0 += __shfl_xor(s0, o); s1 += __shfl_xor(s1, o); s2 += __shfl_xor(s2, o);
  }
  if (lane == 0){
    out[row * 3 + 0] = eluf(s0 + ob[0]);
    out[row * 3 + 1] = eluf(s1 + ob[1]);
    out[row * 3 + 2] = eluf(s2 + ob[2]);
  }
}

__global__ void idxcopy_kernel(const int* __restrict__ ei, float* __restrict__ out){
  int i = blockIdx.x * blockDim.x + threadIdx.x;
  if (i < 2 * ECNT) out[i] = (float)ei[i];
}

extern "C" void kernel_launch(void* const* d_in, const int* in_sizes, int n_in,
                              void* d_out, int out_size, void* d_ws, size_t ws_size,
                              hipStream_t stream)
{
  const float* x_in  = (const float*)d_in[0];
  const float* ea_in = (const float*)d_in[1];
  const float* pos_c = (const float*)d_in[2];
  const float* pos_f = (const float*)d_in[3];
  const int*   ei    = (const int*)d_in[4];
  const int*   clus  = (const int*)d_in[5];
  const float* eW0 = (const float*)d_in[7];
  const float* eb0 = (const float*)d_in[8];
  const float* eW1 = (const float*)d_in[9];
  const float* eb1 = (const float*)d_in[10];
  const float* eg  = (const float*)d_in[11];
  const float* ebt = (const float*)d_in[12];
  const float* nW0 = (const float*)d_in[13];
  const float* nb0 = (const float*)d_in[14];
  const float* nW1 = (const float*)d_in[15];
  const float* nb1 = (const float*)d_in[16];
  const float* ng  = (const float*)d_in[17];
  const float* nbt = (const float*)d_in[18];
  const float* dW0 = (const float*)d_in[19];
  const float* db0 = (const float*)d_in[20];
  const float* dW1 = (const float*)d_in[21];
  const float* db1 = (const float*)d_in[22];
  const float* uW0 = (const float*)d_in[23];
  const float* ub0 = (const float*)d_in[24];
  const float* uW1 = (const float*)d_in[25];
  const float* ub1 = (const float*)d_in[26];
  const float* ug  = (const float*)d_in[27];
  const float* ubt = (const float*)d_in[28];
  const float* oW  = (const float*)d_in[29];
  const float* ob  = (const float*)d_in[30];

  char* w = (char*)d_ws;
  auto alloc = [&](size_t bytes) -> char* {
    char* p = w; w += (bytes + 255) & ~(size_t)255; return p;
  };
  u16*   ea_s   = (u16*)alloc((size_t)ECNT * HD * 2);
  u16*   xa     = (u16*)alloc((size_t)NC * HD * 2);
  u16*   xb     = (u16*)alloc((size_t)NF * HD * 2);
  u16*   P      = (u16*)alloc((size_t)NC * HD * 2);
  u16*   Q      = (u16*)alloc((size_t)NC * HD * 2);
  u16*   XU     = (u16*)alloc((size_t)NC * HD * 2);
  int*   deg    = (int*)alloc((size_t)NF * 4);
  int*   rowptr = (int*)alloc((size_t)(NF + 1) * 4);
  int*   cursor = (int*)alloc((size_t)NF * 4);
  int*   perm   = (int*)alloc((size_t)ECNT * 4);
  int*   esrc   = (int*)alloc((size_t)ECNT * 4);
  int*   edst   = (int*)alloc((size_t)ECNT * 4);
  int*   part   = (int*)alloc((size_t)SCB * 4);
  u16*   c_eW0  = (u16*)alloc((size_t)2 * 384 * HD * 2);
  u16*   c_eW1  = (u16*)alloc((size_t)2 * HD * HD * 2);
  u16*   c_nW0  = (u16*)alloc((size_t)2 * 256 * HD * 2);
  u16*   c_nW1  = (u16*)alloc((size_t)2 * HD * HD * 2);
  u16*   c_uW0  = (u16*)alloc((size_t)256 * HD * 2);
  u16*   c_uW1  = (u16*)alloc((size_t)HD * HD * 2);
  u16*   c_dW1  = (u16*)alloc((size_t)HD * HD * 2);

  prep_all_kernel<<<1152, 256, 0, stream>>>(eW0, eW1, nW0, nW1, uW0, uW1, dW1,
                                            c_eW0, c_eW1, c_nW0, c_nW1, c_uW0, c_uW1, c_dW1);
  f32_to_bf16_vec<<<(NC * HD / 8 + 255) / 256, 256, 0, stream>>>(x_in, xa, NC * HD / 8);

  hipMemsetAsync(deg, 0, (size_t)NF * 4, stream);
  deg_kernel<<<(ECNT + 255) / 256, 256, 0, stream>>>(ei, deg);
  scanA_kernel<<<NB_SCAN, SCB, 0, stream>>>(deg, part);
  scanB_kernel<<<1, SCB, 0, stream>>>(part);
  scanC_kernel<<<NB_SCAN, SCB, 0, stream>>>(deg, part, rowptr);
  hipMemcpyAsync(cursor, rowptr, (size_t)NF * 4, hipMemcpyDeviceToDevice, stream);
  build_perm_kernel<<<(ECNT + 255) / 256, 256, 0, stream>>>(ei, cursor, perm, esrc, edst);
  permute_ea_kernel<<<(ECNT + 3) / 4, 256, 0, stream>>>(ea_in, perm, ea_s);

  auto grd = [](int rows){ return (rows + 31) / 32; };
  const int KS = 16 * HD * 8;   // u16 offset of one 128-K slice in chunked layout

  auto eslice = [&](int i, int s){ return c_eW0 + (size_t)i * 384 * HD + (size_t)s * KS; };

  auto edge = [&](u16* x_unused, int i){
    mlp_kernel<M_EDGE, 0><<<grd(ECNT), 256, 0, stream>>>(
      eslice(i, 2), c_eW1 + (size_t)i*HD*HD, nullptr,
      eb0 + i*HD, eb1 + i*HD, nullptr, eg + i*HD, ebt + i*HD,
      ea_s, P, Q, esrc, edst, nullptr, nullptr, nullptr,
      ea_s, ECNT, nullptr, nullptr, nullptr, nullptr,
      nullptr, nullptr, nullptr, nullptr, 0);
  };
  // NODE with fusion variant F (0,1,2)
  auto node = [&](u16* x, int n, int i, int F,
                  const u16* Wf0, const u16* Wf1, u16* oF0, u16* oF1){
    if (F == 2)
      mlp_kernel<M_NODE, 2><<<grd(n), 256, 0, stream>>>(
        c_nW0 + (size_t)i*256*HD, c_nW0 + (size_t)i*256*HD + KS, c_nW1 + (size_t)i*HD*HD,
        nb0 + i*HD, nb1 + i*HD, nullptr, ng + i*HD, nbt + i*HD,
        x, nullptr, nullptr, nullptr, nullptr, rowptr, ea_s, nullptr,
        x, n, nullptr, nullptr, nullptr, nullptr, Wf0, Wf1, oF0, oF1, NC);
    else if (F == 1)
      mlp_kernel<M_NODE, 1><<<grd(n), 256, 0, stream>>>(
        c_nW0 + (size_t)i*256*HD, c_nW0 + (size_t)i*256*HD + KS, c_nW1 + (size_t)i*HD*HD,
        nb0 + i*HD, nb1 + i*HD, nullptr, ng + i*HD, nbt + i*HD,
        x, nullptr, nullptr, nullptr, nullptr, rowptr, ea_s, nullptr,
        x, n, nullptr, nullptr, nullptr, nullptr, Wf0, nullptr, oF0, nullptr, NC);
    else
      mlp_kernel<M_NODE, 0><<<grd(n), 256, 0, stream>>>(
        c_nW0 + (size_t)i*256*HD, c_nW0 + (size_t)i*256*HD + KS, c_nW1 + (size_t)i*HD*HD,
        nb0 + i*HD, nb1 + i*HD, nullptr, ng + i*HD, nbt + i*HD,
        x, nullptr, nullptr, nullptr, nullptr, rowptr, ea_s, nullptr,
        x, n, nullptr, nullptr, nullptr, nullptr, nullptr, nullptr, nullptr, nullptr, 0);
  };

  // ---- pass 1 on xa ----
  lin2_kernel<<<grd(NC), 256, 0, stream>>>(eslice(0,0), eslice(0,1), xa, P, Q, NC);
  edge(xa, 0);
  node(xa, NC, 0, 2, eslice(1,0), eslice(1,1), P, Q);          // next-iter P,Q
  edge(xa, 1);
  node(xa, NC, 1, 1, c_uW0 + KS, nullptr, XU, nullptr);        // XU = xa @ uW0b

  // ---- decoder (fused DEC1+DEC2), fuses pass-2 first P,Q ----
  mlp_kernel<M_DEC12, 2><<<grd(NF), 256, 0, stream>>>(
    c_dW1, c_uW0, c_uW1,
    db1, ub0, ub1, ug, ubt,
    nullptr, XU, nullptr, nullptr, nullptr, nullptr, nullptr, clus,
    xb, NF, dW0, db0, pos_c, pos_f,
    eslice(0,0), eslice(0,1), P, Q, NC);

  // ---- pass 2 on xb ----
  edge(xb, 0);
  node(xb, NF, 0, 2, eslice(1,0), eslice(1,1), P, Q);
  edge(xb, 1);
  node(xb, NF, 1, 0, nullptr, nullptr, nullptr, nullptr);

  float* out = (float*)d_out;
  outhead_kernel<<<(NF + 3) / 4, 256, 0, stream>>>(xb, oW, ob, out);
  idxcopy_kernel<<<(2 * ECNT + 255) / 256, 256, 0, stream>>>(ei, out + (size_t)NF * OUTD);
}

// Round 13
// 818.384 us; speedup vs baseline: 2.3971x; 1.0397x over previous
//
#include <hip/hip_runtime.h>

// Decoder_48378511622552 — CSR-sorted, bf16, K=128 MFMA fused GNN decoder (gfx950)
// Round 13: permute_ea folded into first EDGE dispatch (perm-gather + inline f32->bf16
// in stage); permute_ea kernel deleted. Everything else identical to R12.

#define HD   128
#define NC   50000
#define NF   150000
#define ECNT 400000
#define OUTD 3
#define SCB  512
#define NB_SCAN ((NF + SCB - 1) / SCB)   // 293

typedef unsigned short u16;
typedef unsigned int   u32;
typedef short bf16x8 __attribute__((ext_vector_type(8)));
typedef float f32x4  __attribute__((ext_vector_type(4)));

__device__ __forceinline__ float bf2f(u32 u){ return __uint_as_float(u << 16); }
__device__ __forceinline__ u32 cvtpk(float a, float b){   // lo = bf16(a), hi = bf16(b)
  u32 r; asm("v_cvt_pk_bf16_f32 %0, %1, %2" : "=v"(r) : "v"(a), "v"(b)); return r;
}
__device__ __forceinline__ u16 f2bf(float f){ return (u16)cvtpk(f, f); }
__device__ __forceinline__ u32 addpk(u32 a, u32 b){
  return cvtpk(bf2f(a & 0xffffu) + bf2f(b & 0xffffu),
               __uint_as_float(a & 0xffff0000u) + __uint_as_float(b & 0xffff0000u));
}
__device__ __forceinline__ float eluf(float x){ return x > 0.f ? x : __expf(x) - 1.f; }
// swizzle for bf16 [32][256B] tiles
__device__ __forceinline__ int SW(int row, int byte){ return row * 256 + (byte ^ ((row & 7) << 4)); }

// ---------------- prep kernels ----------------

__global__ void prep_all_kernel(const float* __restrict__ eW0, const float* __restrict__ eW1,
                                const float* __restrict__ nW0, const float* __restrict__ nW1,
                                const float* __restrict__ uW0, const float* __restrict__ uW1,
                                const float* __restrict__ dW1,
                                u16* c_eW0, u16* c_eW1, u16* c_nW0, u16* c_nW1,
                                u16* c_uW0, u16* c_uW1, u16* c_dW1)
{
  int b = blockIdx.x;
  const float* src; u16* dst; int kb;
  if      (b <  384){ src = eW0; dst = c_eW0; kb = b * 2; }          // K=768 (2 mats)
  else if (b <  512){ src = eW1; dst = c_eW1; kb = (b - 384) * 2; }  // K=256
  else if (b <  768){ src = nW0; dst = c_nW0; kb = (b - 512) * 2; }  // K=512
  else if (b <  896){ src = nW1; dst = c_nW1; kb = (b - 768) * 2; }  // K=256
  else if (b < 1024){ src = uW0; dst = c_uW0; kb = (b - 896) * 2; }  // K=256
  else if (b < 1088){ src = uW1; dst = c_uW1; kb = (b - 1024) * 2; } // K=128
  else              { src = dW1; dst = c_dW1; kb = (b - 1088) * 2; } // K=128
  int t = threadIdx.x;
  int k = kb + (t >> 7), j = t & 127;
  dst[(((k >> 3) * HD + j) << 3) + (k & 7)] = f2bf(src[k * HD + j]);
}

__global__ void f32_to_bf16_vec(const float* __restrict__ in, u16* __restrict__ out, int n8){
  int i = blockIdx.x * blockDim.x + threadIdx.x;
  if (i >= n8) return;
  float4 f0 = ((const float4*)in)[i * 2];
  float4 f1 = ((const float4*)in)[i * 2 + 1];
  ((uint4*)out)[i] = make_uint4(cvtpk(f0.x,f0.y), cvtpk(f0.z,f0.w), cvtpk(f1.x,f1.y), cvtpk(f1.z,f1.w));
}

__global__ void deg_kernel(const int* __restrict__ ei, int* __restrict__ deg){
  int e = blockIdx.x * blockDim.x + threadIdx.x;
  if (e < ECNT) atomicAdd(&deg[ei[ECNT + e]], 1);
}

__global__ void scanA_kernel(const int* __restrict__ deg, int* __restrict__ part){
  __shared__ int s[SCB];
  int t = threadIdx.x, i = blockIdx.x * SCB + t;
  s[t] = (i < NF) ? deg[i] : 0;
  __syncthreads();
  for (int off = SCB/2; off; off >>= 1){ if (t < off) s[t] += s[t + off]; __syncthreads(); }
  if (t == 0) part[blockIdx.x] = s[0];
}

__global__ void scanB_kernel(int* __restrict__ part){
  __shared__ int s[SCB];
  int t = threadIdx.x;
  int v = (t < NB_SCAN) ? part[t] : 0;
  s[t] = v; __syncthreads();
  for (int off = 1; off < SCB; off <<= 1){
    int x = (t >= off) ? s[t - off] : 0;
    __syncthreads(); s[t] += x; __syncthreads();
  }
  if (t < NB_SCAN) part[t] = s[t] - v;   // exclusive
}

__global__ void scanC_kernel(const int* __restrict__ deg, const int* __restrict__ part,
                             int* __restrict__ rowptr){
  __shared__ int s[SCB];
  int t = threadIdx.x, i = blockIdx.x * SCB + t;
  int v = (i < NF) ? deg[i] : 0;
  s[t] = v; __syncthreads();
  for (int off = 1; off < SCB; off <<= 1){
    int x = (t >= off) ? s[t - off] : 0;
    __syncthreads(); s[t] += x; __syncthreads();
  }
  int excl = part[blockIdx.x] + s[t] - v;
  if (i < NF) rowptr[i] = excl;
  if (i == NF - 1) rowptr[NF] = excl + v;
}

__global__ void build_perm_kernel(const int* __restrict__ ei, int* __restrict__ cursor,
                                  int* __restrict__ perm, int* __restrict__ esrc,
                                  int* __restrict__ edst){
  int e = blockIdx.x * blockDim.x + threadIdx.x;
  if (e >= ECNT) return;
  int sI = ei[e], d = ei[ECNT + e];
  int p = atomicAdd(&cursor[d], 1);
  perm[p] = e; esrc[p] = sI; edst[p] = d;
}

// ---------------- standalone LIN2: oA = x@Wa, oB = x@Wb ----------------
__global__ __launch_bounds__(256, 4)
void lin2_kernel(const u16* __restrict__ Wa, const u16* __restrict__ Wb,
                 const u16* __restrict__ x, u16* __restrict__ oA, u16* __restrict__ oB,
                 int n_rows)
{
  __shared__ __align__(16) char ldsA[32 * 256];
  const int tid = threadIdx.x, lane = tid & 63, wid = tid >> 6;
  const int ln = lane & 15, kq = lane >> 4, ncol = wid * 32;

  const int row0 = blockIdx.x << 5;
  #pragma unroll
  for (int c = 0; c < 2; ++c){
    int i = tid + c * 256, row = i >> 4, kk = i & 15, rg = row0 + row;
    if (rg < n_rows)
      *(uint4*)(ldsA + SW(row, kk * 16)) = *(const uint4*)(x + (((size_t)rg) << 7) + (kk << 3));
  }
  __syncthreads();
  bf16x8 af[4][2];
  #pragma unroll
  for (int k0 = 0; k0 < 4; ++k0){
    af[k0][0] = *(const bf16x8*)(ldsA + SW(ln,      k0 * 64 + (kq << 4)));
    af[k0][1] = *(const bf16x8*)(ldsA + SW(16 + ln, k0 * 64 + (kq << 4)));
  }
  const u16* Ws[2] = {Wa, Wb};
  u16*       Os[2] = {oA, oB};
  const f32x4 zz = {0.f, 0.f, 0.f, 0.f};
  #pragma unroll
  for (int w = 0; w < 2; ++w){
    const u16* wp = Ws[w];
    asm volatile("" : "+v"(wp));
    uint4 bfr[4][2];
    #pragma unroll
    for (int k0 = 0; k0 < 4; ++k0)
      #pragma unroll
      for (int nt = 0; nt < 2; ++nt)
        bfr[k0][nt] = *(const uint4*)(wp + (((size_t)((k0*4 + kq)*HD + ncol + nt*16 + ln)) << 3));
    f32x4 cc[2][2] = {{zz, zz}, {zz, zz}};
    #pragma unroll
    for (int k0 = 0; k0 < 4; ++k0){
      bf16x8 w0 = __builtin_bit_cast(bf16x8, bfr[k0][0]);
      bf16x8 w1 = __builtin_bit_cast(bf16x8, bfr[k0][1]);
      cc[0][0] = __builtin_amdgcn_mfma_f32_16x16x32_bf16(af[k0][0], w0, cc[0][0], 0, 0, 0);
      cc[0][1] = __builtin_amdgcn_mfma_f32_16x16x32_bf16(af[k0][0], w1, cc[0][1], 0, 0, 0);
      cc[1][0] = __builtin_amdgcn_mfma_f32_16x16x32_bf16(af[k0][1], w0, cc[1][0], 0, 0, 0);
      cc[1][1] = __builtin_amdgcn_mfma_f32_16x16x32_bf16(af[k0][1], w1, cc[1][1], 0, 0, 0);
    }
    u16* op = Os[w];
    #pragma unroll
    for (int mi = 0; mi < 2; ++mi)
      #pragma unroll
      for (int nt = 0; nt < 2; ++nt)
        #pragma unroll
        for (int r = 0; r < 4; ++r){
          int rg = row0 + mi * 16 + kq * 4 + r;
          if (rg < n_rows) op[(size_t)rg * HD + ncol + nt * 16 + ln] = f2bf(cc[mi][nt][r]);
        }
  }
}

// ---------------- unified fused K=128 MFMA MLP ----------------
enum { M_EDGE = 0, M_NODE = 1, M_DEC12 = 2 };

// EDGE : A=ea; h=elu(A@W0 + P[src]+Q[dst] + b0); cf=h@W1;      out = LN(cf+b1 + A)
//        (permp != nullptr: gather A rows from f32 eaf via perm, convert inline)
// NODE : cf1=x@W0 (+ act: CSR-mean(ea)@W1); h=elu(cf1+b0); cf=h@W2; out = LN(cf+b1 + x)
// DEC12: h1=elu(delta@dW0+db0); eac=elu(h1@W0+b0); h=elu(eac@W1 + XU[clus] + b1);
//        cf=h@W2;                                              out = LN(elu(cf+b2) + eac)
// FUSE>0: after LN store, compute oF[w] = out_tile @ Wf[w] for blocks row0 < fuse_n.
template<int MODE, int FUSE>
__global__ __launch_bounds__(256, 4)
void mlp_kernel(const u16* __restrict__ W0c, const u16* __restrict__ W1c,
                const u16* __restrict__ W2c,
                const float* __restrict__ b0, const float* __restrict__ b1,
                const float* __restrict__ b2,
                const float* __restrict__ gw, const float* __restrict__ bw,
                const u16* __restrict__ tabA, const u16* __restrict__ addP,
                const u16* __restrict__ addQ,
                const int* __restrict__ esrc, const int* __restrict__ edst,
                const int* __restrict__ rowptr, const u16* __restrict__ eatab,
                const int* __restrict__ clus,
                u16* __restrict__ outp, int n_rows,
                const float* __restrict__ dW0, const float* __restrict__ db0,
                const float* __restrict__ pos_c, const float* __restrict__ pos_f,
                const u16* __restrict__ Wf0, const u16* __restrict__ Wf1,
                u16* __restrict__ oF0, u16* __restrict__ oF1, int fuse_n,
                const int* __restrict__ permp, const float* __restrict__ eaf)
{
  constexpr bool ELU2 = (MODE == M_DEC12);

  __shared__ __align__(16) char  ldsA [32 * 256];   // A/x/eac tile (residual source)
  __shared__ __align__(16) char  ldsPQ[32 * 256];   // addend/mean -> h
  __shared__ float ldsSQ[32 * 8];                   // per-row wave partials {s,q} x4
  __shared__ float ldsM [32 * 2];                   // per-row {mu, rs}

  const int tid  = threadIdx.x;
  const int lane = tid & 63;
  const int wid  = tid >> 6;
  const int ln   = lane & 15, kq = lane >> 4;
  const int ncol = wid * 32;

  bf16x8 b1f[4][2];
  #pragma unroll
  for (int k0 = 0; k0 < 4; ++k0)
    #pragma unroll
    for (int nt = 0; nt < 2; ++nt)
      b1f[k0][nt] = *(const bf16x8*)(W0c + (((size_t)((k0*4 + kq)*HD + ncol + nt*16 + ln)) << 3));

  float b0v[2], b1v[2], bfin[2], gv[2], btv[2];
  #pragma unroll
  for (int nt = 0; nt < 2; ++nt){
    int col = ncol + nt*16 + ln;
    b0v[nt] = b0[col]; b1v[nt] = b1[col];
    bfin[nt] = (MODE == M_DEC12) ? b2[col] : b1v[nt];
    gv[nt] = gw[col]; btv[nt] = bw[col];
  }

  const int row0 = blockIdx.x << 5;
  const f32x4 zz = {0.f, 0.f, 0.f, 0.f};
  f32x4 cf[2][2];

  if constexpr (MODE == M_EDGE){
    // ---- stage: ea -> ldsA (perm-gather f32 path for first dispatch), P+Q -> ldsPQ ----
    #pragma unroll
    for (int c = 0; c < 2; ++c){
      int i = tid + c * 256, row = i >> 4, kk = i & 15, rg = row0 + row;   // ECNT%32==0
      uint4 va;
      if (permp){
        int e = permp[rg];
        const float4* src = (const float4*)(eaf + (((size_t)e) << 7) + (kk << 3));
        float4 fa = src[0], fb = src[1];
        va = make_uint4(cvtpk(fa.x,fa.y), cvtpk(fa.z,fa.w), cvtpk(fb.x,fb.y), cvtpk(fb.z,fb.w));
      } else {
        va = *(const uint4*)(tabA + (((size_t)rg) << 7) + (kk << 3));
      }
      *(uint4*)(ldsA + SW(row, kk * 16)) = va;
      int sI = esrc[rg], dI = edst[rg];
      uint4 p = *(const uint4*)(addP + (((size_t)sI) << 7) + (kk << 3));
      uint4 q = *(const uint4*)(addQ + (((size_t)dI) << 7) + (kk << 3));
      *(uint4*)(ldsPQ + SW(row, kk * 16)) =
          make_uint4(addpk(p.x,q.x), addpk(p.y,q.y), addpk(p.z,q.z), addpk(p.w,q.w));
    }
    __syncthreads();   // A
    // GEMM1
    cf[0][0]=zz; cf[0][1]=zz; cf[1][0]=zz; cf[1][1]=zz;
    #pragma unroll
    for (int k0 = 0; k0 < 4; ++k0){
      bf16x8 a0 = *(const bf16x8*)(ldsA + SW(ln,      k0 * 64 + (kq << 4)));
      bf16x8 a1 = *(const bf16x8*)(ldsA + SW(16 + ln, k0 * 64 + (kq << 4)));
      cf[0][0] = __builtin_amdgcn_mfma_f32_16x16x32_bf16(a0, b1f[k0][0], cf[0][0], 0, 0, 0);
      cf[0][1] = __builtin_amdgcn_mfma_f32_16x16x32_bf16(a0, b1f[k0][1], cf[0][1], 0, 0, 0);
      cf[1][0] = __builtin_amdgcn_mfma_f32_16x16x32_bf16(a1, b1f[k0][0], cf[1][0], 0, 0, 0);
      cf[1][1] = __builtin_amdgcn_mfma_f32_16x16x32_bf16(a1, b1f[k0][1], cf[1][1], 0, 0, 0);
    }
    // h = elu(cf + pq + b0) -> ldsPQ in place (same-thread RMW at C positions)
    #pragma unroll
    for (int mi = 0; mi < 2; ++mi)
      #pragma unroll
      for (int nt = 0; nt < 2; ++nt)
        #pragma unroll
        for (int r = 0; r < 4; ++r){
          int row = mi * 16 + kq * 4 + r, col = ncol + nt * 16 + ln;
          u16* pp = (u16*)(ldsPQ + SW(row, col * 2));
          *pp = f2bf(eluf(cf[mi][nt][r] + bf2f(*pp) + b0v[nt]));
        }
    __syncthreads();   // B
    // GEMM2
    {
      const u16* w1p = W1c;
      asm volatile("" : "+v"(w1p));
      uint4 b2r[4][2];
      #pragma unroll
      for (int k0 = 0; k0 < 4; ++k0)
        #pragma unroll
        for (int nt = 0; nt < 2; ++nt)
          b2r[k0][nt] = *(const uint4*)(w1p + (((size_t)((k0*4 + kq)*HD + ncol + nt*16 + ln)) << 3));
      cf[0][0]=zz; cf[0][1]=zz; cf[1][0]=zz; cf[1][1]=zz;
      #pragma unroll
      for (int k0 = 0; k0 < 4; ++k0){
        bf16x8 a0 = *(const bf16x8*)(ldsPQ + SW(ln,      k0 * 64 + (kq << 4)));
        bf16x8 a1 = *(const bf16x8*)(ldsPQ + SW(16 + ln, k0 * 64 + (kq << 4)));
        bf16x8 w0 = __builtin_bit_cast(bf16x8, b2r[k0][0]);
        bf16x8 w1 = __builtin_bit_cast(bf16x8, b2r[k0][1]);
        cf[0][0] = __builtin_amdgcn_mfma_f32_16x16x32_bf16(a0, w0, cf[0][0], 0, 0, 0);
        cf[0][1] = __builtin_amdgcn_mfma_f32_16x16x32_bf16(a0, w1, cf[0][1], 0, 0, 0);
        cf[1][0] = __builtin_amdgcn_mfma_f32_16x16x32_bf16(a1, w0, cf[1][0], 0, 0, 0);
        cf[1][1] = __builtin_amdgcn_mfma_f32_16x16x32_bf16(a1, w1, cf[1][1], 0, 0, 0);
      }
    }
  } else if constexpr (MODE == M_NODE){
    // ---- stage: x -> ldsA ; act: CSR mean -> ldsPQ ----
    #pragma unroll
    for (int c = 0; c < 2; ++c){
      int i = tid + c * 256, row = i >> 4, kk = i & 15, rg = row0 + row;
      if (rg < n_rows)
        *(uint4*)(ldsA + SW(row, kk * 16)) =
            *(const uint4*)(tabA + (((size_t)rg) << 7) + (kk << 3));
    }
    const bool act = (row0 < NC);   // rows >= NC have degree 0 (block-uniform)
    if (act){
      for (int s = 0; s < 8; ++s){
        int nd = wid * 8 + s, rg = row0 + nd;
        if (rg < n_rows){
          int rp0 = rowptr[rg], rp1 = rowptr[rg + 1];
          float s0 = 0.f, s1 = 0.f, t0 = 0.f, t1 = 0.f;
          int i2 = rp0;
          for (; i2 + 3 < rp1; i2 += 4){
            u32 ua = *(const u32*)(eatab + (((size_t) i2     ) << 7) + (lane << 1));
            u32 ub = *(const u32*)(eatab + (((size_t)(i2 + 1)) << 7) + (lane << 1));
            u32 uc = *(const u32*)(eatab + (((size_t)(i2 + 2)) << 7) + (lane << 1));
            u32 ud = *(const u32*)(eatab + (((size_t)(i2 + 3)) << 7) + (lane << 1));
            s0 += bf2f(ua & 0xffffu) + bf2f(ub & 0xffffu);
            s1 += bf2f(ua >> 16)     + bf2f(ub >> 16);
            t0 += bf2f(uc & 0xffffu) + bf2f(ud & 0xffffu);
            t1 += bf2f(uc >> 16)     + bf2f(ud >> 16);
          }
          for (; i2 < rp1; ++i2){
            u32 ua = *(const u32*)(eatab + (((size_t)i2) << 7) + (lane << 1));
            s0 += bf2f(ua & 0xffffu); s1 += bf2f(ua >> 16);
          }
          s0 += t0; s1 += t1;
          int dg = rp1 - rp0;
          float rd = 1.f / (float)(dg > 0 ? dg : 1);
          *(u32*)(ldsPQ + SW(nd, lane << 2)) = cvtpk(s0 * rd, s1 * rd);
        }
      }
    }
    __syncthreads();   // A
    // GEMM1: cf = x @ nW0a
    cf[0][0]=zz; cf[0][1]=zz; cf[1][0]=zz; cf[1][1]=zz;
    #pragma unroll
    for (int k0 = 0; k0 < 4; ++k0){
      bf16x8 a0 = *(const bf16x8*)(ldsA + SW(ln,      k0 * 64 + (kq << 4)));
      bf16x8 a1 = *(const bf16x8*)(ldsA + SW(16 + ln, k0 * 64 + (kq << 4)));
      cf[0][0] = __builtin_amdgcn_mfma_f32_16x16x32_bf16(a0, b1f[k0][0], cf[0][0], 0, 0, 0);
      cf[0][1] = __builtin_amdgcn_mfma_f32_16x16x32_bf16(a0, b1f[k0][1], cf[0][1], 0, 0, 0);
      cf[1][0] = __builtin_amdgcn_mfma_f32_16x16x32_bf16(a1, b1f[k0][0], cf[1][0], 0, 0, 0);
      cf[1][1] = __builtin_amdgcn_mfma_f32_16x16x32_bf16(a1, b1f[k0][1], cf[1][1], 0, 0, 0);
    }
    if (act){
      // cf += mean @ nW0b
      const u16* wbp = W1c;
      asm volatile("" : "+v"(wbp));
      uint4 bbr[4][2];
      #pragma unroll
      for (int k0 = 0; k0 < 4; ++k0)
        #pragma unroll
        for (int nt = 0; nt < 2; ++nt)
          bbr[k0][nt] = *(const uint4*)(wbp + (((size_t)((k0*4 + kq)*HD + ncol + nt*16 + ln)) << 3));
      #pragma unroll
      for (int k0 = 0; k0 < 4; ++k0){
        bf16x8 a0 = *(const bf16x8*)(ldsPQ + SW(ln,      k0 * 64 + (kq << 4)));
        bf16x8 a1 = *(const bf16x8*)(ldsPQ + SW(16 + ln, k0 * 64 + (kq << 4)));
        bf16x8 w0 = __builtin_bit_cast(bf16x8, bbr[k0][0]);
        bf16x8 w1 = __builtin_bit_cast(bf16x8, bbr[k0][1]);
        cf[0][0] = __builtin_amdgcn_mfma_f32_16x16x32_bf16(a0, w0, cf[0][0], 0, 0, 0);
        cf[0][1] = __builtin_amdgcn_mfma_f32_16x16x32_bf16(a0, w1, cf[0][1], 0, 0, 0);
        cf[1][0] = __builtin_amdgcn_mfma_f32_16x16x32_bf16(a1, w0, cf[1][0], 0, 0, 0);
        cf[1][1] = __builtin_amdgcn_mfma_f32_16x16x32_bf16(a1, w1, cf[1][1], 0, 0, 0);
      }
    }
    __syncthreads();   // B: mean reads done
    // h = elu(cf + b0) -> ldsPQ (C positions)
    #pragma unroll
    for (int mi = 0; mi < 2; ++mi)
      #pragma unroll
      for (int nt = 0; nt < 2; ++nt)
        #pragma unroll
        for (int r = 0; r < 4; ++r){
          int row = mi * 16 + kq * 4 + r, col = ncol + nt * 16 + ln;
          *(u16*)(ldsPQ + SW(row, col * 2)) = f2bf(eluf(cf[mi][nt][r] + b0v[nt]));
        }
    __syncthreads();   // C
    // GEMM2: cf = h @ nW1
    {
      const u16* w2p = W2c;
      asm volatile("" : "+v"(w2p));
      uint4 b3r[4][2];
      #pragma unroll
      for (int k0 = 0; k0 < 4; ++k0)
        #pragma unroll
        for (int nt = 0; nt < 2; ++nt)
          b3r[k0][nt] = *(const uint4*)(w2p + (((size_t)((k0*4 + kq)*HD + ncol + nt*16 + ln)) << 3));
      cf[0][0]=zz; cf[0][1]=zz; cf[1][0]=zz; cf[1][1]=zz;
      #pragma unroll
      for (int k0 = 0; k0 < 4; ++k0){
        bf16x8 a0 = *(const bf16x8*)(ldsPQ + SW(ln,      k0 * 64 + (kq << 4)));
        bf16x8 a1 = *(const bf16x8*)(ldsPQ + SW(16 + ln, k0 * 64 + (kq << 4)));
        bf16x8 w0 = __builtin_bit_cast(bf16x8, b3r[k0][0]);
        bf16x8 w1 = __builtin_bit_cast(bf16x8, b3r[k0][1]);
        cf[0][0] = __builtin_amdgcn_mfma_f32_16x16x32_bf16(a0, w0, cf[0][0], 0, 0, 0);
        cf[0][1] = __builtin_amdgcn_mfma_f32_16x16x32_bf16(a0, w1, cf[0][1], 0, 0, 0);
        cf[1][0] = __builtin_amdgcn_mfma_f32_16x16x32_bf16(a1, w0, cf[1][0], 0, 0, 0);
        cf[1][1] = __builtin_amdgcn_mfma_f32_16x16x32_bf16(a1, w1, cf[1][1], 0, 0, 0);
      }
    }
  } else { // M_DEC12
    // ---- stage: h1 = elu(delta@dW0+db0) -> ldsA ; XU[clus] -> ldsPQ ----
    #pragma unroll
    for (int c = 0; c < 2; ++c){
      int i = tid + c * 256, row = i >> 4, c8 = i & 15, rg = row0 + row;
      if (rg < n_rows){
        int cl = clus[rg];
        *(uint4*)(ldsPQ + SW(row, c8 * 16)) =
            *(const uint4*)(addP + (((size_t)cl) << 7) + (c8 << 3));
        float d0 = pos_c[cl * 2]     - pos_f[rg * 2];
        float d1 = pos_c[cl * 2 + 1] - pos_f[rg * 2 + 1];
        u32 wq[4];
        #pragma unroll
        for (int q = 0; q < 4; ++q){
          int cc = c8 * 8 + q * 2;
          float va = eluf(fmaf(d0, dW0[cc],     fmaf(d1, dW0[HD + cc],     db0[cc])));
          float vb = eluf(fmaf(d0, dW0[cc + 1], fmaf(d1, dW0[HD + cc + 1], db0[cc + 1])));
          wq[q] = cvtpk(va, vb);
        }
        *(uint4*)(ldsA + SW(row, c8 * 16)) = make_uint4(wq[0], wq[1], wq[2], wq[3]);
      }
    }
    __syncthreads();   // A
    // GEMM1: cf = h1 @ dW1
    cf[0][0]=zz; cf[0][1]=zz; cf[1][0]=zz; cf[1][1]=zz;
    #pragma unroll
    for (int k0 = 0; k0 < 4; ++k0){
      bf16x8 a0 = *(const bf16x8*)(ldsA + SW(ln,      k0 * 64 + (kq << 4)));
      bf16x8 a1 = *(const bf16x8*)(ldsA + SW(16 + ln, k0 * 64 + (kq << 4)));
      cf[0][0] = __builtin_amdgcn_mfma_f32_16x16x32_bf16(a0, b1f[k0][0], cf[0][0], 0, 0, 0);
      cf[0][1] = __builtin_amdgcn_mfma_f32_16x16x32_bf16(a0, b1f[k0][1], cf[0][1], 0, 0, 0);
      cf[1][0] = __builtin_amdgcn_mfma_f32_16x16x32_bf16(a1, b1f[k0][0], cf[1][0], 0, 0, 0);
      cf[1][1] = __builtin_amdgcn_mfma_f32_16x16x32_bf16(a1, b1f[k0][1], cf[1][1], 0, 0, 0);
    }
    __syncthreads();   // B: h1 reads done
    // eac = elu(cf + b0) -> ldsA (C positions)
    #pragma unroll
    for (int mi = 0; mi < 2; ++mi)
      #pragma unroll
      for (int nt = 0; nt < 2; ++nt)
        #pragma unroll
        for (int r = 0; r < 4; ++r){
          int row = mi * 16 + kq * 4 + r, col = ncol + nt * 16 + ln;
          *(u16*)(ldsA + SW(row, col * 2)) = f2bf(eluf(cf[mi][nt][r] + b0v[nt]));
        }
    __syncthreads();   // C: eac visible
    // GEMM2: cf = eac @ uW0a ; h = elu(cf + XU + b1) -> ldsPQ in place
    {
      const u16* w1p = W1c;
      asm volatile("" : "+v"(w1p));
      uint4 b2r[4][2];
      #pragma unroll
      for (int k0 = 0; k0 < 4; ++k0)
        #pragma unroll
        for (int nt = 0; nt < 2; ++nt)
          b2r[k0][nt] = *(const uint4*)(w1p + (((size_t)((k0*4 + kq)*HD + ncol + nt*16 + ln)) << 3));
      cf[0][0]=zz; cf[0][1]=zz; cf[1][0]=zz; cf[1][1]=zz;
      #pragma unroll
      for (int k0 = 0; k0 < 4; ++k0){
        bf16x8 a0 = *(const bf16x8*)(ldsA + SW(ln,      k0 * 64 + (kq << 4)));
        bf16x8 a1 = *(const bf16x8*)(ldsA + SW(16 + ln, k0 * 64 + (kq << 4)));
        bf16x8 w0 = __builtin_bit_cast(bf16x8, b2r[k0][0]);
        bf16x8 w1 = __builtin_bit_cast(bf16x8, b2r[k0][1]);
        cf[0][0] = __builtin_amdgcn_mfma_f32_16x16x32_bf16(a0, w0, cf[0][0], 0, 0, 0);
        cf[0][1] = __builtin_amdgcn_mfma_f32_16x16x32_bf16(a0, w1, cf[0][1], 0, 0, 0);
        cf[1][0] = __builtin_amdgcn_mfma_f32_16x16x32_bf16(a1, w0, cf[1][0], 0, 0, 0);
        cf[1][1] = __builtin_amdgcn_mfma_f32_16x16x32_bf16(a1, w1, cf[1][1], 0, 0, 0);
      }
      #pragma unroll
      for (int mi = 0; mi < 2; ++mi)
        #pragma unroll
        for (int nt = 0; nt < 2; ++nt)
          #pragma unroll
          for (int r = 0; r < 4; ++r){
            int row = mi * 16 + kq * 4 + r, col = ncol + nt * 16 + ln;
            u16* pp = (u16*)(ldsPQ + SW(row, col * 2));
            *pp = f2bf(eluf(cf[mi][nt][r] + bf2f(*pp) + b1v[nt]));
          }
    }
    __syncthreads();   // D
    // GEMM3: cf = h @ uW1
    {
      const u16* w2p = W2c;
      asm volatile("" : "+v"(w2p));
      uint4 b3r[4][2];
      #pragma unroll
      for (int k0 = 0; k0 < 4; ++k0)
        #pragma unroll
        for (int nt = 0; nt < 2; ++nt)
          b3r[k0][nt] = *(const uint4*)(w2p + (((size_t)((k0*4 + kq)*HD + ncol + nt*16 + ln)) << 3));
      cf[0][0]=zz; cf[0][1]=zz; cf[1][0]=zz; cf[1][1]=zz;
      #pragma unroll
      for (int k0 = 0; k0 < 4; ++k0){
        bf16x8 a0 = *(const bf16x8*)(ldsPQ + SW(ln,      k0 * 64 + (kq << 4)));
        bf16x8 a1 = *(const bf16x8*)(ldsPQ + SW(16 + ln, k0 * 64 + (kq << 4)));
        bf16x8 w0 = __builtin_bit_cast(bf16x8, b3r[k0][0]);
        bf16x8 w1 = __builtin_bit_cast(bf16x8, b3r[k0][1]);
        cf[0][0] = __builtin_amdgcn_mfma_f32_16x16x32_bf16(a0, w0, cf[0][0], 0, 0, 0);
        cf[0][1] = __builtin_amdgcn_mfma_f32_16x16x32_bf16(a0, w1, cf[0][1], 0, 0, 0);
        cf[1][0] = __builtin_amdgcn_mfma_f32_16x16x32_bf16(a1, w0, cf[1][0], 0, 0, 0);
        cf[1][1] = __builtin_amdgcn_mfma_f32_16x16x32_bf16(a1, w1, cf[1][1], 0, 0, 0);
      }
    }
  }

  // ================= shared register-direct LN epilogue =================
  #pragma unroll
  for (int mi = 0; mi < 2; ++mi)
    #pragma unroll
    for (int nt = 0; nt < 2; ++nt)
      #pragma unroll
      for (int r = 0; r < 4; ++r){
        int row = mi * 16 + kq * 4 + r, col = ncol + nt * 16 + ln;
        float v = cf[mi][nt][r] + bfin[nt];
        if constexpr (ELU2) v = eluf(v);
        v += bf2f(*(const u16*)(ldsA + SW(row, col * 2)));
        cf[mi][nt][r] = v;
      }
  float sp[8], qp[8];
  #pragma unroll
  for (int mi = 0; mi < 2; ++mi)
    #pragma unroll
    for (int r = 0; r < 4; ++r){
      int ri = mi * 4 + r;
      float a = cf[mi][0][r], b = cf[mi][1][r];
      sp[ri] = a + b; qp[ri] = a * a + b * b;
    }
  #pragma unroll
  for (int off = 1; off < 16; off <<= 1)
    #pragma unroll
    for (int ri = 0; ri < 8; ++ri){
      sp[ri] += __shfl_xor(sp[ri], off);
      qp[ri] += __shfl_xor(qp[ri], off);
    }
  if (ln == 0){
    #pragma unroll
    for (int mi = 0; mi < 2; ++mi)
      #pragma unroll
      for (int r = 0; r < 4; ++r){
        int row = mi * 16 + kq * 4 + r;
        ldsSQ[row * 8 + wid * 2]     = sp[mi * 4 + r];
        ldsSQ[row * 8 + wid * 2 + 1] = qp[mi * 4 + r];
      }
  }
  __syncthreads();
  if (tid < 32){
    float s = ldsSQ[tid*8+0] + ldsSQ[tid*8+2] + ldsSQ[tid*8+4] + ldsSQ[tid*8+6];
    float q = ldsSQ[tid*8+1] + ldsSQ[tid*8+3] + ldsSQ[tid*8+5] + ldsSQ[tid*8+7];
    float mu  = s * (1.f / 128.f);
    float var = q * (1.f / 128.f) - mu * mu;
    ldsM[tid * 2]     = mu;
    ldsM[tid * 2 + 1] = rsqrtf(var + 1e-5f);
  }
  __syncthreads();
  #pragma unroll
  for (int mi = 0; mi < 2; ++mi)
    #pragma unroll
    for (int r = 0; r < 4; ++r){
      int row = mi * 16 + kq * 4 + r, rg = row0 + row;
      float mu = ldsM[row * 2], rs = ldsM[row * 2 + 1];
      #pragma unroll
      for (int nt = 0; nt < 2; ++nt){
        int col = ncol + nt * 16 + ln;
        float y = (cf[mi][nt][r] - mu) * rs * gv[nt] + btv[nt];
        u16 yb = f2bf(y);
        if (MODE == M_EDGE || rg < n_rows)
          outp[(((size_t)rg) << 7) + col] = yb;
        if constexpr (FUSE > 0)
          *(u16*)(ldsA + SW(row, col * 2)) = yb;
      }
    }

  // ================= fused next-LIN GEMMs =================
  if constexpr (FUSE > 0){
    __syncthreads();
    if (row0 < fuse_n){   // block-uniform
      bf16x8 af[4][2];
      #pragma unroll
      for (int k0 = 0; k0 < 4; ++k0){
        af[k0][0] = *(const bf16x8*)(ldsA + SW(ln,      k0 * 64 + (kq << 4)));
        af[k0][1] = *(const bf16x8*)(ldsA + SW(16 + ln, k0 * 64 + (kq << 4)));
      }
      const u16* Ws[2] = {Wf0, Wf1};
      u16*       Os[2] = {oF0, oF1};
      #pragma unroll
      for (int w = 0; w < FUSE; ++w){
        const u16* wp = Ws[w];
        asm volatile("" : "+v"(wp));
        uint4 bfr[4][2];
        #pragma unroll
        for (int k0 = 0; k0 < 4; ++k0)
          #pragma unroll
          for (int nt = 0; nt < 2; ++nt)
            bfr[k0][nt] = *(const uint4*)(wp + (((size_t)((k0*4 + kq)*HD + ncol + nt*16 + ln)) << 3));
        f32x4 cc[2][2] = {{zz, zz}, {zz, zz}};
        #pragma unroll
        for (int k0 = 0; k0 < 4; ++k0){
          bf16x8 w0 = __builtin_bit_cast(bf16x8, bfr[k0][0]);
          bf16x8 w1 = __builtin_bit_cast(bf16x8, bfr[k0][1]);
          cc[0][0] = __builtin_amdgcn_mfma_f32_16x16x32_bf16(af[k0][0], w0, cc[0][0], 0, 0, 0);
          cc[0][1] = __builtin_amdgcn_mfma_f32_16x16x32_bf16(af[k0][0], w1, cc[0][1], 0, 0, 0);
          cc[1][0] = __builtin_amdgcn_mfma_f32_16x16x32_bf16(af[k0][1], w0, cc[1][0], 0, 0, 0);
          cc[1][1] = __builtin_amdgcn_mfma_f32_16x16x32_bf16(af[k0][1], w1, cc[1][1], 0, 0, 0);
        }
        u16* op = Os[w];
        #pragma unroll
        for (int mi = 0; mi < 2; ++mi)
          #pragma unroll
          for (int nt = 0; nt < 2; ++nt)
            #pragma unroll
            for (int r = 0; r < 4; ++r){
              int rg = row0 + mi * 16 + kq * 4 + r;
              if (rg < fuse_n)
                op[(size_t)rg * HD + ncol + nt * 16 + ln] = f2bf(cc[mi][nt][r]);
            }
      }
    }
  }
}

// out0 = elu(x @ oW + ob)
__global__ void outhead_kernel(const u16* __restrict__ x, const float* __restrict__ oW,
                               const float* __restrict__ ob, float* __restrict__ out){
  int row  = (blockIdx.x * blockDim.x + threadIdx.x) >> 6;
  int lane = threadIdx.x & 63;
  if (row >= NF) return;
  float x0 = bf2f(x[((size_t)row << 7) + lane]);
  float x1 = bf2f(x[((size_t)row << 7) + 64 + lane]);
  float s0 = x0 * oW[lane * 3 + 0] + x1 * oW[(64 + lane) * 3 + 0];
  float s1 = x0 * oW[lane * 3 + 1] + x1 * oW[(64 + lane) * 3 + 1];
  float s2 = x0 * oW[lane * 3 + 2] + x1 * oW[(64 + lane) * 3 + 2];
  #pragma unroll
  for (int o = 32; o; o >>= 1){
    s0 += __shfl_xor(s0, o); s1 += __shfl_xor(s1, o); s2 += __shfl_xor(s2, o);
  }
  if (lane == 0){
    out[row * 3 + 0] = eluf(s0 + ob[0]);
    out[row * 3 + 1] = eluf(s1 + ob[1]);
    out[row * 3 + 2] = eluf(s2 + ob[2]);
  }
}

__global__ void idxcopy_kernel(const int* __restrict__ ei, float* __restrict__ out){
  int i = blockIdx.x * blockDim.x + threadIdx.x;
  if (i < 2 * ECNT) out[i] = (float)ei[i];
}

extern "C" void kernel_launch(void* const* d_in, const int* in_sizes, int n_in,
                              void* d_out, int out_size, void* d_ws, size_t ws_size,
                              hipStream_t stream)
{
  const float* x_in  = (const float*)d_in[0];
  const float* ea_in = (const float*)d_in[1];
  const float* pos_c = (const float*)d_in[2];
  const float* pos_f = (const float*)d_in[3];
  const int*   ei    = (const int*)d_in[4];
  const int*   clus  = (const int*)d_in[5];
  const float* eW0 = (const float*)d_in[7];
  const float* eb0 = (const float*)d_in[8];
  const float* eW1 = (const float*)d_in[9];
  const float* eb1 = (const float*)d_in[10];
  const float* eg  = (const float*)d_in[11];
  const float* ebt = (const float*)d_in[12];
  const float* nW0 = (const float*)d_in[13];
  const float* nb0 = (const float*)d_in[14];
  const float* nW1 = (const float*)d_in[15];
  const float* nb1 = (const float*)d_in[16];
  const float* ng  = (const float*)d_in[17];
  const float* nbt = (const float*)d_in[18];
  const float* dW0 = (const float*)d_in[19];
  const float* db0 = (const float*)d_in[20];
  const float* dW1 = (const float*)d_in[21];
  const float* db1 = (const float*)d_in[22];
  const float* uW0 = (const float*)d_in[23];
  const float* ub0 = (const float*)d_in[24];
  const float* uW1 = (const float*)d_in[25];
  const float* ub1 = (const float*)d_in[26];
  const float* ug  = (const float*)d_in[27];
  const float* ubt = (const float*)d_in[28];
  const float* oW  = (const float*)d_in[29];
  const float* ob  = (const float*)d_in[30];

  char* w = (char*)d_ws;
  auto alloc = [&](size_t bytes) -> char* {
    char* p = w; w += (bytes + 255) & ~(size_t)255; return p;
  };
  u16*   ea_s   = (u16*)alloc((size_t)ECNT * HD * 2);
  u16*   xa     = (u16*)alloc((size_t)NC * HD * 2);
  u16*   xb     = (u16*)alloc((size_t)NF * HD * 2);
  u16*   P      = (u16*)alloc((size_t)NC * HD * 2);
  u16*   Q      = (u16*)alloc((size_t)NC * HD * 2);
  u16*   XU     = (u16*)alloc((size_t)NC * HD * 2);
  int*   deg    = (int*)alloc((size_t)NF * 4);
  int*   rowptr = (int*)alloc((size_t)(NF + 1) * 4);
  int*   cursor = (int*)alloc((size_t)NF * 4);
  int*   perm   = (int*)alloc((size_t)ECNT * 4);
  int*   esrc   = (int*)alloc((size_t)ECNT * 4);
  int*   edst   = (int*)alloc((size_t)ECNT * 4);
  int*   part   = (int*)alloc((size_t)SCB * 4);
  u16*   c_eW0  = (u16*)alloc((size_t)2 * 384 * HD * 2);
  u16*   c_eW1  = (u16*)alloc((size_t)2 * HD * HD * 2);
  u16*   c_nW0  = (u16*)alloc((size_t)2 * 256 * HD * 2);
  u16*   c_nW1  = (u16*)alloc((size_t)2 * HD * HD * 2);
  u16*   c_uW0  = (u16*)alloc((size_t)256 * HD * 2);
  u16*   c_uW1  = (u16*)alloc((size_t)HD * HD * 2);
  u16*   c_dW1  = (u16*)alloc((size_t)HD * HD * 2);

  prep_all_kernel<<<1152, 256, 0, stream>>>(eW0, eW1, nW0, nW1, uW0, uW1, dW1,
                                            c_eW0, c_eW1, c_nW0, c_nW1, c_uW0, c_uW1, c_dW1);
  f32_to_bf16_vec<<<(NC * HD / 8 + 255) / 256, 256, 0, stream>>>(x_in, xa, NC * HD / 8);

  hipMemsetAsync(deg, 0, (size_t)NF * 4, stream);
  deg_kernel<<<(ECNT + 255) / 256, 256, 0, stream>>>(ei, deg);
  scanA_kernel<<<NB_SCAN, SCB, 0, stream>>>(deg, part);
  scanB_kernel<<<1, SCB, 0, stream>>>(part);
  scanC_kernel<<<NB_SCAN, SCB, 0, stream>>>(deg, part, rowptr);
  hipMemcpyAsync(cursor, rowptr, (size_t)NF * 4, hipMemcpyDeviceToDevice, stream);
  build_perm_kernel<<<(ECNT + 255) / 256, 256, 0, stream>>>(ei, cursor, perm, esrc, edst);

  auto grd = [](int rows){ return (rows + 31) / 32; };
  const int KS = 16 * HD * 8;   // u16 offset of one 128-K slice in chunked layout

  auto eslice = [&](int i, int s){ return c_eW0 + (size_t)i * 384 * HD + (size_t)s * KS; };

  // EDGE dispatch; first one gathers original f32 ea via perm (permute fused)
  auto edge = [&](int i, const int* pp, const float* ef){
    mlp_kernel<M_EDGE, 0><<<grd(ECNT), 256, 0, stream>>>(
      eslice(i, 2), c_eW1 + (size_t)i*HD*HD, nullptr,
      eb0 + i*HD, eb1 + i*HD, nullptr, eg + i*HD, ebt + i*HD,
      ea_s, P, Q, esrc, edst, nullptr, nullptr, nullptr,
      ea_s, ECNT, nullptr, nullptr, nullptr, nullptr,
      nullptr, nullptr, nullptr, nullptr, 0, pp, ef);
  };
  auto node = [&](u16* x, int n, int i, int F,
                  const u16* Wf0, const u16* Wf1, u16* oF0, u16* oF1){
    if (F == 2)
      mlp_kernel<M_NODE, 2><<<grd(n), 256, 0, stream>>>(
        c_nW0 + (size_t)i*256*HD, c_nW0 + (size_t)i*256*HD + KS, c_nW1 + (size_t)i*HD*HD,
        nb0 + i*HD, nb1 + i*HD, nullptr, ng + i*HD, nbt + i*HD,
        x, nullptr, nullptr, nullptr, nullptr, rowptr, ea_s, nullptr,
        x, n, nullptr, nullptr, nullptr, nullptr, Wf0, Wf1, oF0, oF1, NC,
        nullptr, nullptr);
    else if (F == 1)
      mlp_kernel<M_NODE, 1><<<grd(n), 256, 0, stream>>>(
        c_nW0 + (size_t)i*256*HD, c_nW0 + (size_t)i*256*HD + KS, c_nW1 + (size_t)i*HD*HD,
        nb0 + i*HD, nb1 + i*HD, nullptr, ng + i*HD, nbt + i*HD,
        x, nullptr, nullptr, nullptr, nullptr, rowptr, ea_s, nullptr,
        x, n, nullptr, nullptr, nullptr, nullptr, Wf0, nullptr, oF0, nullptr, NC,
        nullptr, nullptr);
    else
      mlp_kernel<M_NODE, 0><<<grd(n), 256, 0, stream>>>(
        c_nW0 + (size_t)i*256*HD, c_nW0 + (size_t)i*256*HD + KS, c_nW1 + (size_t)i*HD*HD,
        nb0 + i*HD, nb1 + i*HD, nullptr, ng + i*HD, nbt + i*HD,
        x, nullptr, nullptr, nullptr, nullptr, rowptr, ea_s, nullptr,
        x, n, nullptr, nullptr, nullptr, nullptr, nullptr, nullptr, nullptr, nullptr, 0,
        nullptr, nullptr);
  };

  // ---- pass 1 on xa ----
  lin2_kernel<<<grd(NC), 256, 0, stream>>>(eslice(0,0), eslice(0,1), xa, P, Q, NC);
  edge(0, perm, ea_in);                                        // gathers + converts ea inline
  node(xa, NC, 0, 2, eslice(1,0), eslice(1,1), P, Q);          // next-iter P,Q
  edge(1, nullptr, nullptr);
  node(xa, NC, 1, 1, c_uW0 + KS, nullptr, XU, nullptr);        // XU = xa @ uW0b

  // ---- decoder (fused DEC1+DEC2), fuses pass-2 first P,Q ----
  mlp_kernel<M_DEC12, 2><<<grd(NF), 256, 0, stream>>>(
    c_dW1, c_uW0, c_uW1,
    db1, ub0, ub1, ug, ubt,
    nullptr, XU, nullptr, nullptr, nullptr, nullptr, nullptr, clus,
    xb, NF, dW0, db0, pos_c, pos_f,
    eslice(0,0), eslice(0,1), P, Q, NC,
    nullptr, nullptr);

  // ---- pass 2 on xb ----
  edge(0, nullptr, nullptr);
  node(xb, NF, 0, 2, eslice(1,0), eslice(1,1), P, Q);
  edge(1, nullptr, nullptr);
  node(xb, NF, 1, 0, nullptr, nullptr, nullptr, nullptr);

  float* out = (float*)d_out;
  outhead_kernel<<<(NF + 3) / 4, 256, 0, stream>>>(xb, oW, ob, out);
  idxcopy_kernel<<<(2 * ECNT + 255) / 256, 256, 0, stream>>>(ei, out + (size_t)NF * OUTD);
}

// Round 14
// 788.746 us; speedup vs baseline: 2.4872x; 1.0376x over previous
//
#include <hip/hip_runtime.h>

// Decoder_48378511622552 — CSR-sorted, bf16, K=128 MFMA fused GNN decoder (gfx950)
// Round 14: PERM as template param — steady EDGE dispatches compile without the f32
// gather path (restores R12 codegen: VGPR 48, FETCH ~104MB); only first EDGE has PERM=1.

#define HD   128
#define NC   50000
#define NF   150000
#define ECNT 400000
#define OUTD 3
#define SCB  512
#define NB_SCAN ((NF + SCB - 1) / SCB)   // 293

typedef unsigned short u16;
typedef unsigned int   u32;
typedef short bf16x8 __attribute__((ext_vector_type(8)));
typedef float f32x4  __attribute__((ext_vector_type(4)));

__device__ __forceinline__ float bf2f(u32 u){ return __uint_as_float(u << 16); }
__device__ __forceinline__ u32 cvtpk(float a, float b){   // lo = bf16(a), hi = bf16(b)
  u32 r; asm("v_cvt_pk_bf16_f32 %0, %1, %2" : "=v"(r) : "v"(a), "v"(b)); return r;
}
__device__ __forceinline__ u16 f2bf(float f){ return (u16)cvtpk(f, f); }
__device__ __forceinline__ u32 addpk(u32 a, u32 b){
  return cvtpk(bf2f(a & 0xffffu) + bf2f(b & 0xffffu),
               __uint_as_float(a & 0xffff0000u) + __uint_as_float(b & 0xffff0000u));
}
__device__ __forceinline__ float eluf(float x){ return x > 0.f ? x : __expf(x) - 1.f; }
// swizzle for bf16 [32][256B] tiles
__device__ __forceinline__ int SW(int row, int byte){ return row * 256 + (byte ^ ((row & 7) << 4)); }

// ---------------- prep kernels ----------------

__global__ void prep_all_kernel(const float* __restrict__ eW0, const float* __restrict__ eW1,
                                const float* __restrict__ nW0, const float* __restrict__ nW1,
                                const float* __restrict__ uW0, const float* __restrict__ uW1,
                                const float* __restrict__ dW1,
                                u16* c_eW0, u16* c_eW1, u16* c_nW0, u16* c_nW1,
                                u16* c_uW0, u16* c_uW1, u16* c_dW1)
{
  int b = blockIdx.x;
  const float* src; u16* dst; int kb;
  if      (b <  384){ src = eW0; dst = c_eW0; kb = b * 2; }          // K=768 (2 mats)
  else if (b <  512){ src = eW1; dst = c_eW1; kb = (b - 384) * 2; }  // K=256
  else if (b <  768){ src = nW0; dst = c_nW0; kb = (b - 512) * 2; }  // K=512
  else if (b <  896){ src = nW1; dst = c_nW1; kb = (b - 768) * 2; }  // K=256
  else if (b < 1024){ src = uW0; dst = c_uW0; kb = (b - 896) * 2; }  // K=256
  else if (b < 1088){ src = uW1; dst = c_uW1; kb = (b - 1024) * 2; } // K=128
  else              { src = dW1; dst = c_dW1; kb = (b - 1088) * 2; } // K=128
  int t = threadIdx.x;
  int k = kb + (t >> 7), j = t & 127;
  dst[(((k >> 3) * HD + j) << 3) + (k & 7)] = f2bf(src[k * HD + j]);
}

__global__ void f32_to_bf16_vec(const float* __restrict__ in, u16* __restrict__ out, int n8){
  int i = blockIdx.x * blockDim.x + threadIdx.x;
  if (i >= n8) return;
  float4 f0 = ((const float4*)in)[i * 2];
  float4 f1 = ((const float4*)in)[i * 2 + 1];
  ((uint4*)out)[i] = make_uint4(cvtpk(f0.x,f0.y), cvtpk(f0.z,f0.w), cvtpk(f1.x,f1.y), cvtpk(f1.z,f1.w));
}

__global__ void deg_kernel(const int* __restrict__ ei, int* __restrict__ deg){
  int e = blockIdx.x * blockDim.x + threadIdx.x;
  if (e < ECNT) atomicAdd(&deg[ei[ECNT + e]], 1);
}

__global__ void scanA_kernel(const int* __restrict__ deg, int* __restrict__ part){
  __shared__ int s[SCB];
  int t = threadIdx.x, i = blockIdx.x * SCB + t;
  s[t] = (i < NF) ? deg[i] : 0;
  __syncthreads();
  for (int off = SCB/2; off; off >>= 1){ if (t < off) s[t] += s[t + off]; __syncthreads(); }
  if (t == 0) part[blockIdx.x] = s[0];
}

__global__ void scanB_kernel(int* __restrict__ part){
  __shared__ int s[SCB];
  int t = threadIdx.x;
  int v = (t < NB_SCAN) ? part[t] : 0;
  s[t] = v; __syncthreads();
  for (int off = 1; off < SCB; off <<= 1){
    int x = (t >= off) ? s[t - off] : 0;
    __syncthreads(); s[t] += x; __syncthreads();
  }
  if (t < NB_SCAN) part[t] = s[t] - v;   // exclusive
}

__global__ void scanC_kernel(const int* __restrict__ deg, const int* __restrict__ part,
                             int* __restrict__ rowptr){
  __shared__ int s[SCB];
  int t = threadIdx.x, i = blockIdx.x * SCB + t;
  int v = (i < NF) ? deg[i] : 0;
  s[t] = v; __syncthreads();
  for (int off = 1; off < SCB; off <<= 1){
    int x = (t >= off) ? s[t - off] : 0;
    __syncthreads(); s[t] += x; __syncthreads();
  }
  int excl = part[blockIdx.x] + s[t] - v;
  if (i < NF) rowptr[i] = excl;
  if (i == NF - 1) rowptr[NF] = excl + v;
}

__global__ void build_perm_kernel(const int* __restrict__ ei, int* __restrict__ cursor,
                                  int* __restrict__ perm, int* __restrict__ esrc,
                                  int* __restrict__ edst){
  int e = blockIdx.x * blockDim.x + threadIdx.x;
  if (e >= ECNT) return;
  int sI = ei[e], d = ei[ECNT + e];
  int p = atomicAdd(&cursor[d], 1);
  perm[p] = e; esrc[p] = sI; edst[p] = d;
}

// ---------------- standalone LIN2: oA = x@Wa, oB = x@Wb ----------------
__global__ __launch_bounds__(256, 4)
void lin2_kernel(const u16* __restrict__ Wa, const u16* __restrict__ Wb,
                 const u16* __restrict__ x, u16* __restrict__ oA, u16* __restrict__ oB,
                 int n_rows)
{
  __shared__ __align__(16) char ldsA[32 * 256];
  const int tid = threadIdx.x, lane = tid & 63, wid = tid >> 6;
  const int ln = lane & 15, kq = lane >> 4, ncol = wid * 32;

  const int row0 = blockIdx.x << 5;
  #pragma unroll
  for (int c = 0; c < 2; ++c){
    int i = tid + c * 256, row = i >> 4, kk = i & 15, rg = row0 + row;
    if (rg < n_rows)
      *(uint4*)(ldsA + SW(row, kk * 16)) = *(const uint4*)(x + (((size_t)rg) << 7) + (kk << 3));
  }
  __syncthreads();
  bf16x8 af[4][2];
  #pragma unroll
  for (int k0 = 0; k0 < 4; ++k0){
    af[k0][0] = *(const bf16x8*)(ldsA + SW(ln,      k0 * 64 + (kq << 4)));
    af[k0][1] = *(const bf16x8*)(ldsA + SW(16 + ln, k0 * 64 + (kq << 4)));
  }
  const u16* Ws[2] = {Wa, Wb};
  u16*       Os[2] = {oA, oB};
  const f32x4 zz = {0.f, 0.f, 0.f, 0.f};
  #pragma unroll
  for (int w = 0; w < 2; ++w){
    const u16* wp = Ws[w];
    asm volatile("" : "+v"(wp));
    uint4 bfr[4][2];
    #pragma unroll
    for (int k0 = 0; k0 < 4; ++k0)
      #pragma unroll
      for (int nt = 0; nt < 2; ++nt)
        bfr[k0][nt] = *(const uint4*)(wp + (((size_t)((k0*4 + kq)*HD + ncol + nt*16 + ln)) << 3));
    f32x4 cc[2][2] = {{zz, zz}, {zz, zz}};
    #pragma unroll
    for (int k0 = 0; k0 < 4; ++k0){
      bf16x8 w0 = __builtin_bit_cast(bf16x8, bfr[k0][0]);
      bf16x8 w1 = __builtin_bit_cast(bf16x8, bfr[k0][1]);
      cc[0][0] = __builtin_amdgcn_mfma_f32_16x16x32_bf16(af[k0][0], w0, cc[0][0], 0, 0, 0);
      cc[0][1] = __builtin_amdgcn_mfma_f32_16x16x32_bf16(af[k0][0], w1, cc[0][1], 0, 0, 0);
      cc[1][0] = __builtin_amdgcn_mfma_f32_16x16x32_bf16(af[k0][1], w0, cc[1][0], 0, 0, 0);
      cc[1][1] = __builtin_amdgcn_mfma_f32_16x16x32_bf16(af[k0][1], w1, cc[1][1], 0, 0, 0);
    }
    u16* op = Os[w];
    #pragma unroll
    for (int mi = 0; mi < 2; ++mi)
      #pragma unroll
      for (int nt = 0; nt < 2; ++nt)
        #pragma unroll
        for (int r = 0; r < 4; ++r){
          int rg = row0 + mi * 16 + kq * 4 + r;
          if (rg < n_rows) op[(size_t)rg * HD + ncol + nt * 16 + ln] = f2bf(cc[mi][nt][r]);
        }
  }
}

// ---------------- unified fused K=128 MFMA MLP ----------------
enum { M_EDGE = 0, M_NODE = 1, M_DEC12 = 2 };

// EDGE : A=ea; h=elu(A@W0 + P[src]+Q[dst] + b0); cf=h@W1;      out = LN(cf+b1 + A)
//        (PERM=1: gather A rows from f32 eaf via perm, convert inline)
// NODE : cf1=x@W0 (+ act: CSR-mean(ea)@W1); h=elu(cf1+b0); cf=h@W2; out = LN(cf+b1 + x)
// DEC12: h1=elu(delta@dW0+db0); eac=elu(h1@W0+b0); h=elu(eac@W1 + XU[clus] + b1);
//        cf=h@W2;                                              out = LN(elu(cf+b2) + eac)
// FUSE>0: after LN store, compute oF[w] = out_tile @ Wf[w] for blocks row0 < fuse_n.
template<int MODE, int FUSE, int PERM>
__global__ __launch_bounds__(256, 4)
void mlp_kernel(const u16* __restrict__ W0c, const u16* __restrict__ W1c,
                const u16* __restrict__ W2c,
                const float* __restrict__ b0, const float* __restrict__ b1,
                const float* __restrict__ b2,
                const float* __restrict__ gw, const float* __restrict__ bw,
                const u16* __restrict__ tabA, const u16* __restrict__ addP,
                const u16* __restrict__ addQ,
                const int* __restrict__ esrc, const int* __restrict__ edst,
                const int* __restrict__ rowptr, const u16* __restrict__ eatab,
                const int* __restrict__ clus,
                u16* __restrict__ outp, int n_rows,
                const float* __restrict__ dW0, const float* __restrict__ db0,
                const float* __restrict__ pos_c, const float* __restrict__ pos_f,
                const u16* __restrict__ Wf0, const u16* __restrict__ Wf1,
                u16* __restrict__ oF0, u16* __restrict__ oF1, int fuse_n,
                const int* __restrict__ permp, const float* __restrict__ eaf)
{
  constexpr bool ELU2 = (MODE == M_DEC12);

  __shared__ __align__(16) char  ldsA [32 * 256];   // A/x/eac tile (residual source)
  __shared__ __align__(16) char  ldsPQ[32 * 256];   // addend/mean -> h
  __shared__ float ldsSQ[32 * 8];                   // per-row wave partials {s,q} x4
  __shared__ float ldsM [32 * 2];                   // per-row {mu, rs}

  const int tid  = threadIdx.x;
  const int lane = tid & 63;
  const int wid  = tid >> 6;
  const int ln   = lane & 15, kq = lane >> 4;
  const int ncol = wid * 32;

  bf16x8 b1f[4][2];
  #pragma unroll
  for (int k0 = 0; k0 < 4; ++k0)
    #pragma unroll
    for (int nt = 0; nt < 2; ++nt)
      b1f[k0][nt] = *(const bf16x8*)(W0c + (((size_t)((k0*4 + kq)*HD + ncol + nt*16 + ln)) << 3));

  float b0v[2], b1v[2], bfin[2], gv[2], btv[2];
  #pragma unroll
  for (int nt = 0; nt < 2; ++nt){
    int col = ncol + nt*16 + ln;
    b0v[nt] = b0[col]; b1v[nt] = b1[col];
    bfin[nt] = (MODE == M_DEC12) ? b2[col] : b1v[nt];
    gv[nt] = gw[col]; btv[nt] = bw[col];
  }

  const int row0 = blockIdx.x << 5;
  const f32x4 zz = {0.f, 0.f, 0.f, 0.f};
  f32x4 cf[2][2];

  if constexpr (MODE == M_EDGE){
    // ---- stage: ea -> ldsA (PERM: gather f32 + convert), P+Q -> ldsPQ ----
    #pragma unroll
    for (int c = 0; c < 2; ++c){
      int i = tid + c * 256, row = i >> 4, kk = i & 15, rg = row0 + row;   // ECNT%32==0
      uint4 va;
      if constexpr (PERM){
        int e = permp[rg];
        const float4* src = (const float4*)(eaf + (((size_t)e) << 7) + (kk << 3));
        float4 fa = src[0], fb = src[1];
        va = make_uint4(cvtpk(fa.x,fa.y), cvtpk(fa.z,fa.w), cvtpk(fb.x,fb.y), cvtpk(fb.z,fb.w));
      } else {
        va = *(const uint4*)(tabA + (((size_t)rg) << 7) + (kk << 3));
      }
      *(uint4*)(ldsA + SW(row, kk * 16)) = va;
      int sI = esrc[rg], dI = edst[rg];
      uint4 p = *(const uint4*)(addP + (((size_t)sI) << 7) + (kk << 3));
      uint4 q = *(const uint4*)(addQ + (((size_t)dI) << 7) + (kk << 3));
      *(uint4*)(ldsPQ + SW(row, kk * 16)) =
          make_uint4(addpk(p.x,q.x), addpk(p.y,q.y), addpk(p.z,q.z), addpk(p.w,q.w));
    }
    __syncthreads();   // A
    // GEMM1
    cf[0][0]=zz; cf[0][1]=zz; cf[1][0]=zz; cf[1][1]=zz;
    #pragma unroll
    for (int k0 = 0; k0 < 4; ++k0){
      bf16x8 a0 = *(const bf16x8*)(ldsA + SW(ln,      k0 * 64 + (kq << 4)));
      bf16x8 a1 = *(const bf16x8*)(ldsA + SW(16 + ln, k0 * 64 + (kq << 4)));
      cf[0][0] = __builtin_amdgcn_mfma_f32_16x16x32_bf16(a0, b1f[k0][0], cf[0][0], 0, 0, 0);
      cf[0][1] = __builtin_amdgcn_mfma_f32_16x16x32_bf16(a0, b1f[k0][1], cf[0][1], 0, 0, 0);
      cf[1][0] = __builtin_amdgcn_mfma_f32_16x16x32_bf16(a1, b1f[k0][0], cf[1][0], 0, 0, 0);
      cf[1][1] = __builtin_amdgcn_mfma_f32_16x16x32_bf16(a1, b1f[k0][1], cf[1][1], 0, 0, 0);
    }
    // h = elu(cf + pq + b0) -> ldsPQ in place (same-thread RMW at C positions)
    #pragma unroll
    for (int mi = 0; mi < 2; ++mi)
      #pragma unroll
      for (int nt = 0; nt < 2; ++nt)
        #pragma unroll
        for (int r = 0; r < 4; ++r){
          int row = mi * 16 + kq * 4 + r, col = ncol + nt * 16 + ln;
          u16* pp = (u16*)(ldsPQ + SW(row, col * 2));
          *pp = f2bf(eluf(cf[mi][nt][r] + bf2f(*pp) + b0v[nt]));
        }
    __syncthreads();   // B
    // GEMM2
    {
      const u16* w1p = W1c;
      asm volatile("" : "+v"(w1p));
      uint4 b2r[4][2];
      #pragma unroll
      for (int k0 = 0; k0 < 4; ++k0)
        #pragma unroll
        for (int nt = 0; nt < 2; ++nt)
          b2r[k0][nt] = *(const uint4*)(w1p + (((size_t)((k0*4 + kq)*HD + ncol + nt*16 + ln)) << 3));
      cf[0][0]=zz; cf[0][1]=zz; cf[1][0]=zz; cf[1][1]=zz;
      #pragma unroll
      for (int k0 = 0; k0 < 4; ++k0){
        bf16x8 a0 = *(const bf16x8*)(ldsPQ + SW(ln,      k0 * 64 + (kq << 4)));
        bf16x8 a1 = *(const bf16x8*)(ldsPQ + SW(16 + ln, k0 * 64 + (kq << 4)));
        bf16x8 w0 = __builtin_bit_cast(bf16x8, b2r[k0][0]);
        bf16x8 w1 = __builtin_bit_cast(bf16x8, b2r[k0][1]);
        cf[0][0] = __builtin_amdgcn_mfma_f32_16x16x32_bf16(a0, w0, cf[0][0], 0, 0, 0);
        cf[0][1] = __builtin_amdgcn_mfma_f32_16x16x32_bf16(a0, w1, cf[0][1], 0, 0, 0);
        cf[1][0] = __builtin_amdgcn_mfma_f32_16x16x32_bf16(a1, w0, cf[1][0], 0, 0, 0);
        cf[1][1] = __builtin_amdgcn_mfma_f32_16x16x32_bf16(a1, w1, cf[1][1], 0, 0, 0);
      }
    }
  } else if constexpr (MODE == M_NODE){
    // ---- stage: x -> ldsA ; act: CSR mean -> ldsPQ ----
    #pragma unroll
    for (int c = 0; c < 2; ++c){
      int i = tid + c * 256, row = i >> 4, kk = i & 15, rg = row0 + row;
      if (rg < n_rows)
        *(uint4*)(ldsA + SW(row, kk * 16)) =
            *(const uint4*)(tabA + (((size_t)rg) << 7) + (kk << 3));
    }
    const bool act = (row0 < NC);   // rows >= NC have degree 0 (block-uniform)
    if (act){
      for (int s = 0; s < 8; ++s){
        int nd = wid * 8 + s, rg = row0 + nd;
        if (rg < n_rows){
          int rp0 = rowptr[rg], rp1 = rowptr[rg + 1];
          float s0 = 0.f, s1 = 0.f, t0 = 0.f, t1 = 0.f;
          int i2 = rp0;
          for (; i2 + 3 < rp1; i2 += 4){
            u32 ua = *(const u32*)(eatab + (((size_t) i2     ) << 7) + (lane << 1));
            u32 ub = *(const u32*)(eatab + (((size_t)(i2 + 1)) << 7) + (lane << 1));
            u32 uc = *(const u32*)(eatab + (((size_t)(i2 + 2)) << 7) + (lane << 1));
            u32 ud = *(const u32*)(eatab + (((size_t)(i2 + 3)) << 7) + (lane << 1));
            s0 += bf2f(ua & 0xffffu) + bf2f(ub & 0xffffu);
            s1 += bf2f(ua >> 16)     + bf2f(ub >> 16);
            t0 += bf2f(uc & 0xffffu) + bf2f(ud & 0xffffu);
            t1 += bf2f(uc >> 16)     + bf2f(ud >> 16);
          }
          for (; i2 < rp1; ++i2){
            u32 ua = *(const u32*)(eatab + (((size_t)i2) << 7) + (lane << 1));
            s0 += bf2f(ua & 0xffffu); s1 += bf2f(ua >> 16);
          }
          s0 += t0; s1 += t1;
          int dg = rp1 - rp0;
          float rd = 1.f / (float)(dg > 0 ? dg : 1);
          *(u32*)(ldsPQ + SW(nd, lane << 2)) = cvtpk(s0 * rd, s1 * rd);
        }
      }
    }
    __syncthreads();   // A
    // GEMM1: cf = x @ nW0a
    cf[0][0]=zz; cf[0][1]=zz; cf[1][0]=zz; cf[1][1]=zz;
    #pragma unroll
    for (int k0 = 0; k0 < 4; ++k0){
      bf16x8 a0 = *(const bf16x8*)(ldsA + SW(ln,      k0 * 64 + (kq << 4)));
      bf16x8 a1 = *(const bf16x8*)(ldsA + SW(16 + ln, k0 * 64 + (kq << 4)));
      cf[0][0] = __builtin_amdgcn_mfma_f32_16x16x32_bf16(a0, b1f[k0][0], cf[0][0], 0, 0, 0);
      cf[0][1] = __builtin_amdgcn_mfma_f32_16x16x32_bf16(a0, b1f[k0][1], cf[0][1], 0, 0, 0);
      cf[1][0] = __builtin_amdgcn_mfma_f32_16x16x32_bf16(a1, b1f[k0][0], cf[1][0], 0, 0, 0);
      cf[1][1] = __builtin_amdgcn_mfma_f32_16x16x32_bf16(a1, b1f[k0][1], cf[1][1], 0, 0, 0);
    }
    if (act){
      // cf += mean @ nW0b
      const u16* wbp = W1c;
      asm volatile("" : "+v"(wbp));
      uint4 bbr[4][2];
      #pragma unroll
      for (int k0 = 0; k0 < 4; ++k0)
        #pragma unroll
        for (int nt = 0; nt < 2; ++nt)
          bbr[k0][nt] = *(const uint4*)(wbp + (((size_t)((k0*4 + kq)*HD + ncol + nt*16 + ln)) << 3));
      #pragma unroll
      for (int k0 = 0; k0 < 4; ++k0){
        bf16x8 a0 = *(const bf16x8*)(ldsPQ + SW(ln,      k0 * 64 + (kq << 4)));
        bf16x8 a1 = *(const bf16x8*)(ldsPQ + SW(16 + ln, k0 * 64 + (kq << 4)));
        bf16x8 w0 = __builtin_bit_cast(bf16x8, bbr[k0][0]);
        bf16x8 w1 = __builtin_bit_cast(bf16x8, bbr[k0][1]);
        cf[0][0] = __builtin_amdgcn_mfma_f32_16x16x32_bf16(a0, w0, cf[0][0], 0, 0, 0);
        cf[0][1] = __builtin_amdgcn_mfma_f32_16x16x32_bf16(a0, w1, cf[0][1], 0, 0, 0);
        cf[1][0] = __builtin_amdgcn_mfma_f32_16x16x32_bf16(a1, w0, cf[1][0], 0, 0, 0);
        cf[1][1] = __builtin_amdgcn_mfma_f32_16x16x32_bf16(a1, w1, cf[1][1], 0, 0, 0);
      }
    }
    __syncthreads();   // B: mean reads done
    // h = elu(cf + b0) -> ldsPQ (C positions)
    #pragma unroll
    for (int mi = 0; mi < 2; ++mi)
      #pragma unroll
      for (int nt = 0; nt < 2; ++nt)
        #pragma unroll
        for (int r = 0; r < 4; ++r){
          int row = mi * 16 + kq * 4 + r, col = ncol + nt * 16 + ln;
          *(u16*)(ldsPQ + SW(row, col * 2)) = f2bf(eluf(cf[mi][nt][r] + b0v[nt]));
        }
    __syncthreads();   // C
    // GEMM2: cf = h @ nW1
    {
      const u16* w2p = W2c;
      asm volatile("" : "+v"(w2p));
      uint4 b3r[4][2];
      #pragma unroll
      for (int k0 = 0; k0 < 4; ++k0)
        #pragma unroll
        for (int nt = 0; nt < 2; ++nt)
          b3r[k0][nt] = *(const uint4*)(w2p + (((size_t)((k0*4 + kq)*HD + ncol + nt*16 + ln)) << 3));
      cf[0][0]=zz; cf[0][1]=zz; cf[1][0]=zz; cf[1][1]=zz;
      #pragma unroll
      for (int k0 = 0; k0 < 4; ++k0){
        bf16x8 a0 = *(const bf16x8*)(ldsPQ + SW(ln,      k0 * 64 + (kq << 4)));
        bf16x8 a1 = *(const bf16x8*)(ldsPQ + SW(16 + ln, k0 * 64 + (kq << 4)));
        bf16x8 w0 = __builtin_bit_cast(bf16x8, b3r[k0][0]);
        bf16x8 w1 = __builtin_bit_cast(bf16x8, b3r[k0][1]);
        cf[0][0] = __builtin_amdgcn_mfma_f32_16x16x32_bf16(a0, w0, cf[0][0], 0, 0, 0);
        cf[0][1] = __builtin_amdgcn_mfma_f32_16x16x32_bf16(a0, w1, cf[0][1], 0, 0, 0);
        cf[1][0] = __builtin_amdgcn_mfma_f32_16x16x32_bf16(a1, w0, cf[1][0], 0, 0, 0);
        cf[1][1] = __builtin_amdgcn_mfma_f32_16x16x32_bf16(a1, w1, cf[1][1], 0, 0, 0);
      }
    }
  } else { // M_DEC12
    // ---- stage: h1 = elu(delta@dW0+db0) -> ldsA ; XU[clus] -> ldsPQ ----
    #pragma unroll
    for (int c = 0; c < 2; ++c){
      int i = tid + c * 256, row = i >> 4, c8 = i & 15, rg = row0 + row;
      if (rg < n_rows){
        int cl = clus[rg];
        *(uint4*)(ldsPQ + SW(row, c8 * 16)) =
            *(const uint4*)(addP + (((size_t)cl) << 7) + (c8 << 3));
        float d0 = pos_c[cl * 2]     - pos_f[rg * 2];
        float d1 = pos_c[cl * 2 + 1] - pos_f[rg * 2 + 1];
        u32 wq[4];
        #pragma unroll
        for (int q = 0; q < 4; ++q){
          int cc = c8 * 8 + q * 2;
          float va = eluf(fmaf(d0, dW0[cc],     fmaf(d1, dW0[HD + cc],     db0[cc])));
          float vb = eluf(fmaf(d0, dW0[cc + 1], fmaf(d1, dW0[HD + cc + 1], db0[cc + 1])));
          wq[q] = cvtpk(va, vb);
        }
        *(uint4*)(ldsA + SW(row, c8 * 16)) = make_uint4(wq[0], wq[1], wq[2], wq[3]);
      }
    }
    __syncthreads();   // A
    // GEMM1: cf = h1 @ dW1
    cf[0][0]=zz; cf[0][1]=zz; cf[1][0]=zz; cf[1][1]=zz;
    #pragma unroll
    for (int k0 = 0; k0 < 4; ++k0){
      bf16x8 a0 = *(const bf16x8*)(ldsA + SW(ln,      k0 * 64 + (kq << 4)));
      bf16x8 a1 = *(const bf16x8*)(ldsA + SW(16 + ln, k0 * 64 + (kq << 4)));
      cf[0][0] = __builtin_amdgcn_mfma_f32_16x16x32_bf16(a0, b1f[k0][0], cf[0][0], 0, 0, 0);
      cf[0][1] = __builtin_amdgcn_mfma_f32_16x16x32_bf16(a0, b1f[k0][1], cf[0][1], 0, 0, 0);
      cf[1][0] = __builtin_amdgcn_mfma_f32_16x16x32_bf16(a1, b1f[k0][0], cf[1][0], 0, 0, 0);
      cf[1][1] = __builtin_amdgcn_mfma_f32_16x16x32_bf16(a1, b1f[k0][1], cf[1][1], 0, 0, 0);
    }
    __syncthreads();   // B: h1 reads done
    // eac = elu(cf + b0) -> ldsA (C positions)
    #pragma unroll
    for (int mi = 0; mi < 2; ++mi)
      #pragma unroll
      for (int nt = 0; nt < 2; ++nt)
        #pragma unroll
        for (int r = 0; r < 4; ++r){
          int row = mi * 16 + kq * 4 + r, col = ncol + nt * 16 + ln;
          *(u16*)(ldsA + SW(row, col * 2)) = f2bf(eluf(cf[mi][nt][r] + b0v[nt]));
        }
    __syncthreads();   // C: eac visible
    // GEMM2: cf = eac @ uW0a ; h = elu(cf + XU + b1) -> ldsPQ in place
    {
      const u16* w1p = W1c;
      asm volatile("" : "+v"(w1p));
      uint4 b2r[4][2];
      #pragma unroll
      for (int k0 = 0; k0 < 4; ++k0)
        #pragma unroll
        for (int nt = 0; nt < 2; ++nt)
          b2r[k0][nt] = *(const uint4*)(w1p + (((size_t)((k0*4 + kq)*HD + ncol + nt*16 + ln)) << 3));
      cf[0][0]=zz; cf[0][1]=zz; cf[1][0]=zz; cf[1][1]=zz;
      #pragma unroll
      for (int k0 = 0; k0 < 4; ++k0){
        bf16x8 a0 = *(const bf16x8*)(ldsA + SW(ln,      k0 * 64 + (kq << 4)));
        bf16x8 a1 = *(const bf16x8*)(ldsA + SW(16 + ln, k0 * 64 + (kq << 4)));
        bf16x8 w0 = __builtin_bit_cast(bf16x8, b2r[k0][0]);
        bf16x8 w1 = __builtin_bit_cast(bf16x8, b2r[k0][1]);
        cf[0][0] = __builtin_amdgcn_mfma_f32_16x16x32_bf16(a0, w0, cf[0][0], 0, 0, 0);
        cf[0][1] = __builtin_amdgcn_mfma_f32_16x16x32_bf16(a0, w1, cf[0][1], 0, 0, 0);
        cf[1][0] = __builtin_amdgcn_mfma_f32_16x16x32_bf16(a1, w0, cf[1][0], 0, 0, 0);
        cf[1][1] = __builtin_amdgcn_mfma_f32_16x16x32_bf16(a1, w1, cf[1][1], 0, 0, 0);
      }
      #pragma unroll
      for (int mi = 0; mi < 2; ++mi)
        #pragma unroll
        for (int nt = 0; nt < 2; ++nt)
          #pragma unroll
          for (int r = 0; r < 4; ++r){
            int row = mi * 16 + kq * 4 + r, col = ncol + nt * 16 + ln;
            u16* pp = (u16*)(ldsPQ + SW(row, col * 2));
            *pp = f2bf(eluf(cf[mi][nt][r] + bf2f(*pp) + b1v[nt]));
          }
    }
    __syncthreads();   // D
    // GEMM3: cf = h @ uW1
    {
      const u16* w2p = W2c;
      asm volatile("" : "+v"(w2p));
      uint4 b3r[4][2];
      #pragma unroll
      for (int k0 = 0; k0 < 4; ++k0)
        #pragma unroll
        for (int nt = 0; nt < 2; ++nt)
          b3r[k0][nt] = *(const uint4*)(w2p + (((size_t)((k0*4 + kq)*HD + ncol + nt*16 + ln)) << 3));
      cf[0][0]=zz; cf[0][1]=zz; cf[1][0]=zz; cf[1][1]=zz;
      #pragma unroll
      for (int k0 = 0; k0 < 4; ++k0){
        bf16x8 a0 = *(const bf16x8*)(ldsPQ + SW(ln,      k0 * 64 + (kq << 4)));
        bf16x8 a1 = *(const bf16x8*)(ldsPQ + SW(16 + ln, k0 * 64 + (kq << 4)));
        bf16x8 w0 = __builtin_bit_cast(bf16x8, b3r[k0][0]);
        bf16x8 w1 = __builtin_bit_cast(bf16x8, b3r[k0][1]);
        cf[0][0] = __builtin_amdgcn_mfma_f32_16x16x32_bf16(a0, w0, cf[0][0], 0, 0, 0);
        cf[0][1] = __builtin_amdgcn_mfma_f32_16x16x32_bf16(a0, w1, cf[0][1], 0, 0, 0);
        cf[1][0] = __builtin_amdgcn_mfma_f32_16x16x32_bf16(a1, w0, cf[1][0], 0, 0, 0);
        cf[1][1] = __builtin_amdgcn_mfma_f32_16x16x32_bf16(a1, w1, cf[1][1], 0, 0, 0);
      }
    }
  }

  // ================= shared register-direct LN epilogue =================
  #pragma unroll
  for (int mi = 0; mi < 2; ++mi)
    #pragma unroll
    for (int nt = 0; nt < 2; ++nt)
      #pragma unroll
      for (int r = 0; r < 4; ++r){
        int row = mi * 16 + kq * 4 + r, col = ncol + nt * 16 + ln;
        float v = cf[mi][nt][r] + bfin[nt];
        if constexpr (ELU2) v = eluf(v);
        v += bf2f(*(const u16*)(ldsA + SW(row, col * 2)));
        cf[mi][nt][r] = v;
      }
  float sp[8], qp[8];
  #pragma unroll
  for (int mi = 0; mi < 2; ++mi)
    #pragma unroll
    for (int r = 0; r < 4; ++r){
      int ri = mi * 4 + r;
      float a = cf[mi][0][r], b = cf[mi][1][r];
      sp[ri] = a + b; qp[ri] = a * a + b * b;
    }
  #pragma unroll
  for (int off = 1; off < 16; off <<= 1)
    #pragma unroll
    for (int ri = 0; ri < 8; ++ri){
      sp[ri] += __shfl_xor(sp[ri], off);
      qp[ri] += __shfl_xor(qp[ri], off);
    }
  if (ln == 0){
    #pragma unroll
    for (int mi = 0; mi < 2; ++mi)
      #pragma unroll
      for (int r = 0; r < 4; ++r){
        int row = mi * 16 + kq * 4 + r;
        ldsSQ[row * 8 + wid * 2]     = sp[mi * 4 + r];
        ldsSQ[row * 8 + wid * 2 + 1] = qp[mi * 4 + r];
      }
  }
  __syncthreads();
  if (tid < 32){
    float s = ldsSQ[tid*8+0] + ldsSQ[tid*8+2] + ldsSQ[tid*8+4] + ldsSQ[tid*8+6];
    float q = ldsSQ[tid*8+1] + ldsSQ[tid*8+3] + ldsSQ[tid*8+5] + ldsSQ[tid*8+7];
    float mu  = s * (1.f / 128.f);
    float var = q * (1.f / 128.f) - mu * mu;
    ldsM[tid * 2]     = mu;
    ldsM[tid * 2 + 1] = rsqrtf(var + 1e-5f);
  }
  __syncthreads();
  #pragma unroll
  for (int mi = 0; mi < 2; ++mi)
    #pragma unroll
    for (int r = 0; r < 4; ++r){
      int row = mi * 16 + kq * 4 + r, rg = row0 + row;
      float mu = ldsM[row * 2], rs = ldsM[row * 2 + 1];
      #pragma unroll
      for (int nt = 0; nt < 2; ++nt){
        int col = ncol + nt * 16 + ln;
        float y = (cf[mi][nt][r] - mu) * rs * gv[nt] + btv[nt];
        u16 yb = f2bf(y);
        if (MODE == M_EDGE || rg < n_rows)
          outp[(((size_t)rg) << 7) + col] = yb;
        if constexpr (FUSE > 0)
          *(u16*)(ldsA + SW(row, col * 2)) = yb;
      }
    }

  // ================= fused next-LIN GEMMs =================
  if constexpr (FUSE > 0){
    __syncthreads();
    if (row0 < fuse_n){   // block-uniform
      bf16x8 af[4][2];
      #pragma unroll
      for (int k0 = 0; k0 < 4; ++k0){
        af[k0][0] = *(const bf16x8*)(ldsA + SW(ln,      k0 * 64 + (kq << 4)));
        af[k0][1] = *(const bf16x8*)(ldsA + SW(16 + ln, k0 * 64 + (kq << 4)));
      }
      const u16* Ws[2] = {Wf0, Wf1};
      u16*       Os[2] = {oF0, oF1};
      #pragma unroll
      for (int w = 0; w < FUSE; ++w){
        const u16* wp = Ws[w];
        asm volatile("" : "+v"(wp));
        uint4 bfr[4][2];
        #pragma unroll
        for (int k0 = 0; k0 < 4; ++k0)
          #pragma unroll
          for (int nt = 0; nt < 2; ++nt)
            bfr[k0][nt] = *(const uint4*)(wp + (((size_t)((k0*4 + kq)*HD + ncol + nt*16 + ln)) << 3));
        f32x4 cc[2][2] = {{zz, zz}, {zz, zz}};
        #pragma unroll
        for (int k0 = 0; k0 < 4; ++k0){
          bf16x8 w0 = __builtin_bit_cast(bf16x8, bfr[k0][0]);
          bf16x8 w1 = __builtin_bit_cast(bf16x8, bfr[k0][1]);
          cc[0][0] = __builtin_amdgcn_mfma_f32_16x16x32_bf16(af[k0][0], w0, cc[0][0], 0, 0, 0);
          cc[0][1] = __builtin_amdgcn_mfma_f32_16x16x32_bf16(af[k0][0], w1, cc[0][1], 0, 0, 0);
          cc[1][0] = __builtin_amdgcn_mfma_f32_16x16x32_bf16(af[k0][1], w0, cc[1][0], 0, 0, 0);
          cc[1][1] = __builtin_amdgcn_mfma_f32_16x16x32_bf16(af[k0][1], w1, cc[1][1], 0, 0, 0);
        }
        u16* op = Os[w];
        #pragma unroll
        for (int mi = 0; mi < 2; ++mi)
          #pragma unroll
          for (int nt = 0; nt < 2; ++nt)
            #pragma unroll
            for (int r = 0; r < 4; ++r){
              int rg = row0 + mi * 16 + kq * 4 + r;
              if (rg < fuse_n)
                op[(size_t)rg * HD + ncol + nt * 16 + ln] = f2bf(cc[mi][nt][r]);
            }
      }
    }
  }
}

// out0 = elu(x @ oW + ob)
__global__ void outhead_kernel(const u16* __restrict__ x, const float* __restrict__ oW,
                               const float* __restrict__ ob, float* __restrict__ out){
  int row  = (blockIdx.x * blockDim.x + threadIdx.x) >> 6;
  int lane = threadIdx.x & 63;
  if (row >= NF) return;
  float x0 = bf2f(x[((size_t)row << 7) + lane]);
  float x1 = bf2f(x[((size_t)row << 7) + 64 + lane]);
  float s0 = x0 * oW[lane * 3 + 0] + x1 * oW[(64 + lane) * 3 + 0];
  float s1 = x0 * oW[lane * 3 + 1] + x1 * oW[(64 + lane) * 3 + 1];
  float s2 = x0 * oW[lane * 3 + 2] + x1 * oW[(64 + lane) * 3 + 2];
  #pragma unroll
  for (int o = 32; o; o >>= 1){
    s0 += __shfl_xor(s0, o); s1 += __shfl_xor(s1, o); s2 += __shfl_xor(s2, o);
  }
  if (lane == 0){
    out[row * 3 + 0] = eluf(s0 + ob[0]);
    out[row * 3 + 1] = eluf(s1 + ob[1]);
    out[row * 3 + 2] = eluf(s2 + ob[2]);
  }
}

__global__ void idxcopy_kernel(const int* __restrict__ ei, float* __restrict__ out){
  int i = blockIdx.x * blockDim.x + threadIdx.x;
  if (i < 2 * ECNT) out[i] = (float)ei[i];
}

extern "C" void kernel_launch(void* const* d_in, const int* in_sizes, int n_in,
                              void* d_out, int out_size, void* d_ws, size_t ws_size,
                              hipStream_t stream)
{
  const float* x_in  = (const float*)d_in[0];
  const float* ea_in = (const float*)d_in[1];
  const float* pos_c = (const float*)d_in[2];
  const float* pos_f = (const float*)d_in[3];
  const int*   ei    = (const int*)d_in[4];
  const int*   clus  = (const int*)d_in[5];
  const float* eW0 = (const float*)d_in[7];
  const float* eb0 = (const float*)d_in[8];
  const float* eW1 = (const float*)d_in[9];
  const float* eb1 = (const float*)d_in[10];
  const float* eg  = (const float*)d_in[11];
  const float* ebt = (const float*)d_in[12];
  const float* nW0 = (const float*)d_in[13];
  const float* nb0 = (const float*)d_in[14];
  const float* nW1 = (const float*)d_in[15];
  const float* nb1 = (const float*)d_in[16];
  const float* ng  = (const float*)d_in[17];
  const float* nbt = (const float*)d_in[18];
  const float* dW0 = (const float*)d_in[19];
  const float* db0 = (const float*)d_in[20];
  const float* dW1 = (const float*)d_in[21];
  const float* db1 = (const float*)d_in[22];
  const float* uW0 = (const float*)d_in[23];
  const float* ub0 = (const float*)d_in[24];
  const float* uW1 = (const float*)d_in[25];
  const float* ub1 = (const float*)d_in[26];
  const float* ug  = (const float*)d_in[27];
  const float* ubt = (const float*)d_in[28];
  const float* oW  = (const float*)d_in[29];
  const float* ob  = (const float*)d_in[30];

  char* w = (char*)d_ws;
  auto alloc = [&](size_t bytes) -> char* {
    char* p = w; w += (bytes + 255) & ~(size_t)255; return p;
  };
  u16*   ea_s   = (u16*)alloc((size_t)ECNT * HD * 2);
  u16*   xa     = (u16*)alloc((size_t)NC * HD * 2);
  u16*   xb     = (u16*)alloc((size_t)NF * HD * 2);
  u16*   P      = (u16*)alloc((size_t)NC * HD * 2);
  u16*   Q      = (u16*)alloc((size_t)NC * HD * 2);
  u16*   XU     = (u16*)alloc((size_t)NC * HD * 2);
  int*   deg    = (int*)alloc((size_t)NF * 4);
  int*   rowptr = (int*)alloc((size_t)(NF + 1) * 4);
  int*   cursor = (int*)alloc((size_t)NF * 4);
  int*   perm   = (int*)alloc((size_t)ECNT * 4);
  int*   esrc   = (int*)alloc((size_t)ECNT * 4);
  int*   edst   = (int*)alloc((size_t)ECNT * 4);
  int*   part   = (int*)alloc((size_t)SCB * 4);
  u16*   c_eW0  = (u16*)alloc((size_t)2 * 384 * HD * 2);
  u16*   c_eW1  = (u16*)alloc((size_t)2 * HD * HD * 2);
  u16*   c_nW0  = (u16*)alloc((size_t)2 * 256 * HD * 2);
  u16*   c_nW1  = (u16*)alloc((size_t)2 * HD * HD * 2);
  u16*   c_uW0  = (u16*)alloc((size_t)256 * HD * 2);
  u16*   c_uW1  = (u16*)alloc((size_t)HD * HD * 2);
  u16*   c_dW1  = (u16*)alloc((size_t)HD * HD * 2);

  prep_all_kernel<<<1152, 256, 0, stream>>>(eW0, eW1, nW0, nW1, uW0, uW1, dW1,
                                            c_eW0, c_eW1, c_nW0, c_nW1, c_uW0, c_uW1, c_dW1);
  f32_to_bf16_vec<<<(NC * HD / 8 + 255) / 256, 256, 0, stream>>>(x_in, xa, NC * HD / 8);

  hipMemsetAsync(deg, 0, (size_t)NF * 4, stream);
  deg_kernel<<<(ECNT + 255) / 256, 256, 0, stream>>>(ei, deg);
  scanA_kernel<<<NB_SCAN, SCB, 0, stream>>>(deg, part);
  scanB_kernel<<<1, SCB, 0, stream>>>(part);
  scanC_kernel<<<NB_SCAN, SCB, 0, stream>>>(deg, part, rowptr);
  hipMemcpyAsync(cursor, rowptr, (size_t)NF * 4, hipMemcpyDeviceToDevice, stream);
  build_perm_kernel<<<(ECNT + 255) / 256, 256, 0, stream>>>(ei, cursor, perm, esrc, edst);

  auto grd = [](int rows){ return (rows + 31) / 32; };
  const int KS = 16 * HD * 8;   // u16 offset of one 128-K slice in chunked layout

  auto eslice = [&](int i, int s){ return c_eW0 + (size_t)i * 384 * HD + (size_t)s * KS; };

  // EDGE dispatch; PERM=1 for the first (gathers original f32 ea via perm)
  auto edgeP = [&](int i){
    mlp_kernel<M_EDGE, 0, 1><<<grd(ECNT), 256, 0, stream>>>(
      eslice(i, 2), c_eW1 + (size_t)i*HD*HD, nullptr,
      eb0 + i*HD, eb1 + i*HD, nullptr, eg + i*HD, ebt + i*HD,
      ea_s, P, Q, esrc, edst, nullptr, nullptr, nullptr,
      ea_s, ECNT, nullptr, nullptr, nullptr, nullptr,
      nullptr, nullptr, nullptr, nullptr, 0, perm, ea_in);
  };
  auto edge = [&](int i){
    mlp_kernel<M_EDGE, 0, 0><<<grd(ECNT), 256, 0, stream>>>(
      eslice(i, 2), c_eW1 + (size_t)i*HD*HD, nullptr,
      eb0 + i*HD, eb1 + i*HD, nullptr, eg + i*HD, ebt + i*HD,
      ea_s, P, Q, esrc, edst, nullptr, nullptr, nullptr,
      ea_s, ECNT, nullptr, nullptr, nullptr, nullptr,
      nullptr, nullptr, nullptr, nullptr, 0, nullptr, nullptr);
  };
  auto node = [&](u16* x, int n, int i, int F,
                  const u16* Wf0, const u16* Wf1, u16* oF0, u16* oF1){
    if (F == 2)
      mlp_kernel<M_NODE, 2, 0><<<grd(n), 256, 0, stream>>>(
        c_nW0 + (size_t)i*256*HD, c_nW0 + (size_t)i*256*HD + KS, c_nW1 + (size_t)i*HD*HD,
        nb0 + i*HD, nb1 + i*HD, nullptr, ng + i*HD, nbt + i*HD,
        x, nullptr, nullptr, nullptr, nullptr, rowptr, ea_s, nullptr,
        x, n, nullptr, nullptr, nullptr, nullptr, Wf0, Wf1, oF0, oF1, NC,
        nullptr, nullptr);
    else if (F == 1)
      mlp_kernel<M_NODE, 1, 0><<<grd(n), 256, 0, stream>>>(
        c_nW0 + (size_t)i*256*HD, c_nW0 + (size_t)i*256*HD + KS, c_nW1 + (size_t)i*HD*HD,
        nb0 + i*HD, nb1 + i*HD, nullptr, ng + i*HD, nbt + i*HD,
        x, nullptr, nullptr, nullptr, nullptr, rowptr, ea_s, nullptr,
        x, n, nullptr, nullptr, nullptr, nullptr, Wf0, nullptr, oF0, nullptr, NC,
        nullptr, nullptr);
    else
      mlp_kernel<M_NODE, 0, 0><<<grd(n), 256, 0, stream>>>(
        c_nW0 + (size_t)i*256*HD, c_nW0 + (size_t)i*256*HD + KS, c_nW1 + (size_t)i*HD*HD,
        nb0 + i*HD, nb1 + i*HD, nullptr, ng + i*HD, nbt + i*HD,
        x, nullptr, nullptr, nullptr, nullptr, rowptr, ea_s, nullptr,
        x, n, nullptr, nullptr, nullptr, nullptr, nullptr, nullptr, nullptr, nullptr, 0,
        nullptr, nullptr);
  };

  // ---- pass 1 on xa ----
  lin2_kernel<<<grd(NC), 256, 0, stream>>>(eslice(0,0), eslice(0,1), xa, P, Q, NC);
  edgeP(0);                                                    // gathers + converts ea inline
  node(xa, NC, 0, 2, eslice(1,0), eslice(1,1), P, Q);          // next-iter P,Q
  edge(1);
  node(xa, NC, 1, 1, c_uW0 + KS, nullptr, XU, nullptr);        // XU = xa @ uW0b

  // ---- decoder (fused DEC1+DEC2), fuses pass-2 first P,Q ----
  mlp_kernel<M_DEC12, 2, 0><<<grd(NF), 256, 0, stream>>>(
    c_dW1, c_uW0, c_uW1,
    db1, ub0, ub1, ug, ubt,
    nullptr, XU, nullptr, nullptr, nullptr, nullptr, nullptr, clus,
    xb, NF, dW0, db0, pos_c, pos_f,
    eslice(0,0), eslice(0,1), P, Q, NC,
    nullptr, nullptr);

  // ---- pass 2 on xb ----
  edge(0);
  node(xb, NF, 0, 2, eslice(1,0), eslice(1,1), P, Q);
  edge(1);
  node(xb, NF, 1, 0, nullptr, nullptr, nullptr, nullptr);

  float* out = (float*)d_out;
  outhead_kernel<<<(NF + 3) / 4, 256, 0, stream>>>(xb, oW, ob, out);
  idxcopy_kernel<<<(2 * ECNT + 255) / 256, 256, 0, stream>>>(ei, out + (size_t)NF * OUTD);
}